// Round 27
// baseline (1134.438 us; speedup 1.0000x reference)
//
#include <hip/hip_runtime.h>

// ---------------------------------------------------------------------------
// GCN3D. R9: split-bf16 MFMA GEMMs. R13: prop4s+norm-fold. R14/15/17/23: bf16
// activations everywhere. R17/R20/R21/R22: launch merging, int2 edges.
// R24: LDS-W staging. R26: FULLW one-barrier k-loop for h3/o2 (1125us best).
// R27: (a) chunked FULLW: loop K in 64KB chunks -> t1 (K=256,BN=128) goes
//   dbuf(9 barriers) -> 2 chunks (4 barriers). (b) instats fused into h4
//   epilogue the RIGHT way (R19 failed w/ LDS atomics): per-lane register
//   sums + shfl_xor(16/32) over row-groups + g==0 global atomics. No LDS,
//   no extra barrier; k_instats launch + 51MB pass deleted.
// ---------------------------------------------------------------------------

#define NCLUST 1024

typedef short bf16x8 __attribute__((ext_vector_type(8)));
typedef float f32x4 __attribute__((ext_vector_type(4)));

__device__ __forceinline__ float elu1(float x) { return x > 0.f ? x : expm1f(x); }

__device__ __forceinline__ unsigned f2bf(float f) {
    union { float f; unsigned u; } c; c.f = f;
    unsigned u = c.u;
    return (u + 0x7fffu + ((u >> 16) & 1u)) >> 16;
}
__device__ __forceinline__ float bf2f(unsigned h) {
    union { unsigned u; float f; } c; c.u = h << 16; return c.f;
}

union U8 { unsigned u[4]; bf16x8 v; };

// ---- W pre-pack body ----
__device__ __forceinline__ void wpack_body(const float* W, unsigned* Phi, unsigned* Plo,
                                           int K, int BN, int t) {
    int NT = BN / 16;
    int lane = t & 63;
    int rest = t >> 6;
    int ct = rest % NT;
    int s = rest / NT;
    int col = ct * 16 + (lane & 15);
    int g = lane >> 4;
    int k0 = s * 32;
    float e[8];
#pragma unroll
    for (int j = 0; j < 4; j++) {
        e[j]     = W[(size_t)(k0 + 4 * g + j) * BN + col];
        e[4 + j] = W[(size_t)(k0 + 16 + 4 * g + j) * BN + col];
    }
#pragma unroll
    for (int j = 0; j < 4; j++) {
        unsigned h0 = f2bf(e[2 * j]), h1 = f2bf(e[2 * j + 1]);
        Phi[(size_t)t * 4 + j] = h0 | (h1 << 16);
        unsigned l0 = f2bf(e[2 * j] - bf2f(h0));
        unsigned l1 = f2bf(e[2 * j + 1] - bf2f(h1));
        Plo[(size_t)t * 4 + j] = l0 | (l1 << 16);
    }
}

struct PackDesc { const float* W; unsigned* Ph; unsigned* Pl; int K, BN, tbase; };
struct InitArgs {
    PackDesc d[6]; int tot;
    int4* z1; int nz1; int4* z2; int nz2;
};

__global__ void k_init(InitArgs a) {
    int t = blockIdx.x * 256 + threadIdx.x;
    if (t < a.nz1) a.z1[t] = make_int4(0, 0, 0, 0);
    else if (t - a.nz1 < a.nz2) a.z2[t - a.nz1] = make_int4(0, 0, 0, 0);
    if (t < a.tot) {
        int i = 0;
#pragma unroll
        for (int j = 1; j < 6; j++) if (t >= a.d[j].tbase) i = j;
        wpack_body(a.d[i].W, a.d[i].Ph, a.d[i].Pl, a.d[i].K, a.d[i].BN,
                   t - a.d[i].tbase);
    }
}

// ---------------- CSR build ----------------
__global__ void k_hist(const int* __restrict__ key, int* __restrict__ deg, int E) {
    int e = blockIdx.x * 256 + threadIdx.x;
    if (e < E) atomicAdd(&deg[key[e]], 1);
}

__global__ void k_scan_block(const int* __restrict__ deg, int* __restrict__ rowptr,
                             int* __restrict__ bsum, int n) {
    __shared__ int lds[256];
    int tid = threadIdx.x;
    int base = blockIdx.x * 1024 + tid * 4;
    int v0 = base + 0 < n ? deg[base + 0] : 0;
    int v1 = base + 1 < n ? deg[base + 1] : 0;
    int v2 = base + 2 < n ? deg[base + 2] : 0;
    int v3 = base + 3 < n ? deg[base + 3] : 0;
    int tsum = v0 + v1 + v2 + v3;
    lds[tid] = tsum; __syncthreads();
    for (int off = 1; off < 256; off <<= 1) {
        int t = (tid >= off) ? lds[tid - off] : 0;
        __syncthreads();
        lds[tid] += t;
        __syncthreads();
    }
    int run = lds[tid] - tsum;
    if (base + 0 < n) rowptr[base + 0] = run; run += v0;
    if (base + 1 < n) rowptr[base + 1] = run; run += v1;
    if (base + 2 < n) rowptr[base + 2] = run; run += v2;
    if (base + 3 < n) rowptr[base + 3] = run;
    if (tid == 255) bsum[blockIdx.x] = lds[255];
}

// merged: bsum scan + rowptr finalize + dinv + bc + cluster hist
__global__ void k_nodeinit(int* __restrict__ rowptr, const int* __restrict__ bsum,
                           const int* __restrict__ deg, const int* __restrict__ cluster,
                           const int* __restrict__ inb, float* __restrict__ dinv,
                           int* __restrict__ bc, int* __restrict__ cdeg, int n, int nb) {
    __shared__ int pfx[128];
    int tid = threadIdx.x;
    if (tid < 128) pfx[tid] = (tid < nb) ? bsum[tid] : 0;
    __syncthreads();
    for (int off = 1; off < 128; off <<= 1) {
        int v = 0;
        if (tid < 128 && tid >= off) v = pfx[tid - off];
        __syncthreads();
        if (tid < 128) pfx[tid] += v;
        __syncthreads();
    }
    int i = blockIdx.x * 256 + tid;
    if (i >= n) return;
    int j = i >> 10;
    int base = (j == 0) ? 0 : pfx[j - 1];
    rowptr[i] += base;
    dinv[i] = rsqrtf((float)deg[i] + 1.0f);
    int c = cluster[i] + inb[i] * NCLUST;
    bc[i] = c;
    atomicAdd(&cdeg[c], 1);
}

// merged: edge CSR fill (packed int2) + cluster member fill
__global__ void k_fillc(const int* __restrict__ src, const int* __restrict__ dst,
                        const float* __restrict__ dinv, const int* __restrict__ rowptr,
                        int* __restrict__ fill, int2* __restrict__ csr_ev, int E,
                        const int* __restrict__ bc, const int* __restrict__ crowptr,
                        int* __restrict__ cfill, int* __restrict__ cnodes, int n) {
    int e = blockIdx.x * 256 + threadIdx.x;
    if (e < E) {
        int d = dst[e];
        int pos = rowptr[d] + atomicAdd(&fill[d], 1);
        int s = src[e];
        csr_ev[pos] = make_int2(s, __float_as_int(dinv[s]));
    }
    if (e < n) {
        int c = bc[e];
        int pos = crowptr[c] + atomicAdd(&cfill[c], 1);
        cnodes[pos] = e;
    }
}

// ------ GCN propagation, bf16 input; OB=0 f32 out, OB=1 bf16 out ------
template <int F, int OB>
__global__ __launch_bounds__(256) void k_prop4sb(
        const unsigned short* __restrict__ hbf, const float* __restrict__ dinv,
        const int* __restrict__ rowptr, const int* __restrict__ deg,
        const int2* __restrict__ csr_ev,
        const float* __restrict__ bias, float* __restrict__ outf,
        unsigned short* __restrict__ outb, int n, int flags) {
    constexpr int FS = F / 4;
    constexpr int ES = 64 / FS;
    const int node = (blockIdx.x * 256 + threadIdx.x) >> 6;
    if (node >= n) return;
    const int l = threadIdx.x & 63;
    const int fs = l & (FS - 1);
    const int ep = l / FS;
    const int fi = fs * 4;
    const int start = rowptr[node];
    const int cnt = deg[node];
    float ax = 0.f, ay = 0.f, az = 0.f, aw = 0.f;
    for (int j = ep; j < cnt; j += ES) {
        const int2 ev = csr_ev[start + j];
        int s = ev.x;
        float w = __int_as_float(ev.y);
        const ushort4 v = *reinterpret_cast<const ushort4*>(&hbf[(size_t)s * F + fi]);
        ax += w * bf2f(v.x); ay += w * bf2f(v.y);
        az += w * bf2f(v.z); aw += w * bf2f(v.w);
    }
#pragma unroll
    for (int off = FS; off < 64; off <<= 1) {
        ax += __shfl_xor(ax, off);
        ay += __shfl_xor(ay, off);
        az += __shfl_xor(az, off);
        aw += __shfl_xor(aw, off);
    }
    if (ep == 0) {
        float di = dinv[node];
        const ushort4 sv = *reinterpret_cast<const ushort4*>(&hbf[(size_t)node * F + fi]);
        float4 o;
        o.x = di * ax + di * di * bf2f(sv.x);
        o.y = di * ay + di * di * bf2f(sv.y);
        o.z = di * az + di * di * bf2f(sv.z);
        o.w = di * aw + di * di * bf2f(sv.w);
        if (flags) {
            const float4 b = *reinterpret_cast<const float4*>(&bias[fi]);
            o.x = elu1(o.x + b.x); o.y = elu1(o.y + b.y);
            o.z = elu1(o.z + b.z); o.w = elu1(o.w + b.w);
        }
        if constexpr (OB) {
            ushort4 ob;
            ob.x = (unsigned short)f2bf(o.x); ob.y = (unsigned short)f2bf(o.y);
            ob.z = (unsigned short)f2bf(o.z); ob.w = (unsigned short)f2bf(o.w);
            *reinterpret_cast<ushort4*>(&outb[(size_t)node * F + fi]) = ob;
        } else {
            *reinterpret_cast<float4*>(&outf[(size_t)node * F + fi]) = o;
        }
    }
}

// prop3 on x + fused fc<64> -> bf16 out (N x 64)
__global__ void k_prop3f1(const float* __restrict__ h, const float* __restrict__ dinv,
                          const int* __restrict__ rowptr, const int* __restrict__ deg,
                          const int2* __restrict__ csr_ev,
                          const float* __restrict__ WG1, const float* __restrict__ bG1,
                          unsigned short* __restrict__ outb, int n) {
    int node = blockIdx.x * 256 + threadIdx.x;
    if (node >= n) return;
    int start = rowptr[node], cnt = deg[node];
    float a0 = 0.f, a1 = 0.f, a2 = 0.f;
    for (int j = 0; j < cnt; j++) {
        const int2 ev = csr_ev[start + j];
        int s = ev.x;
        float w = __int_as_float(ev.y);
        a0 += w * h[(size_t)s * 3 + 0];
        a1 += w * h[(size_t)s * 3 + 1];
        a2 += w * h[(size_t)s * 3 + 2];
    }
    float di = dinv[node];
    float p0 = di * a0 + di * di * h[(size_t)node * 3 + 0];
    float p1 = di * a1 + di * di * h[(size_t)node * 3 + 1];
    float p2 = di * a2 + di * di * h[(size_t)node * 3 + 2];
    unsigned short* op = outb + (size_t)node * 64;
#pragma unroll 4
    for (int c = 0; c < 64; c += 4) {
        ushort4 ob;
        ob.x = (unsigned short)f2bf(elu1(p0 * WG1[c + 0] + p1 * WG1[64 + c + 0] + p2 * WG1[128 + c + 0] + bG1[c + 0]));
        ob.y = (unsigned short)f2bf(elu1(p0 * WG1[c + 1] + p1 * WG1[64 + c + 1] + p2 * WG1[128 + c + 1] + bG1[c + 1]));
        ob.z = (unsigned short)f2bf(elu1(p0 * WG1[c + 2] + p1 * WG1[64 + c + 2] + p2 * WG1[128 + c + 2] + bG1[c + 2]));
        ob.w = (unsigned short)f2bf(elu1(p0 * WG1[c + 3] + p1 * WG1[64 + c + 3] + p2 * WG1[128 + c + 3] + bG1[c + 3]));
        *reinterpret_cast<ushort4*>(op + c) = ob;
    }
}

// prop3 on t3 (+bO3, elu) + fused final fc3
__global__ void k_prop3out(const float* __restrict__ h, const float* __restrict__ dinv,
                           const int* __restrict__ rowptr, const int* __restrict__ deg,
                           const int2* __restrict__ csr_ev,
                           const float* __restrict__ bO3, const float* __restrict__ WfO3,
                           const float* __restrict__ bfO3, float* __restrict__ out, int n) {
    int node = blockIdx.x * 256 + threadIdx.x;
    if (node >= n) return;
    int start = rowptr[node], cnt = deg[node];
    float a0 = 0.f, a1 = 0.f, a2 = 0.f;
    for (int j = 0; j < cnt; j++) {
        const int2 ev = csr_ev[start + j];
        int s = ev.x;
        float w = __int_as_float(ev.y);
        a0 += w * h[(size_t)s * 3 + 0];
        a1 += w * h[(size_t)s * 3 + 1];
        a2 += w * h[(size_t)s * 3 + 2];
    }
    float di = dinv[node];
    float o0 = elu1(di * a0 + di * di * h[(size_t)node * 3 + 0] + bO3[0]);
    float o1 = elu1(di * a1 + di * di * h[(size_t)node * 3 + 1] + bO3[1]);
    float o2 = elu1(di * a2 + di * di * h[(size_t)node * 3 + 2] + bO3[2]);
#pragma unroll
    for (int c = 0; c < 3; c++) {
        out[(size_t)node * 3 + c] =
            elu1(o0 * WfO3[c] + o1 * WfO3[3 + c] + o2 * WfO3[6 + c] + bfO3[c]);
    }
}

// ---- merged: infinal + rstd-scaled WO1 pack + corr (17 blocks x 256) ----
__global__ void k_normprep(const float* __restrict__ W, const float* __restrict__ insum,
                           const float* __restrict__ insumsq, unsigned* __restrict__ Phi,
                           unsigned* __restrict__ Plo, float* __restrict__ corr,
                           float* __restrict__ mu, float* __restrict__ rstd, int n) {
    const float fn = (float)n;
    const int bid = blockIdx.x, tid = threadIdx.x;
    if (bid == 16) {
        float m = insum[tid] / fn;
        float var = insumsq[tid] / fn - m * m;
        mu[tid] = m;
        rstd[tid] = rsqrtf(var + 1e-5f);
        return;
    }
    {
        int t = bid * 256 + tid;
        int lane = t & 63, rest = t >> 6;
        int ct = rest % 8, s = rest / 8;
        int col = ct * 16 + (lane & 15);
        int g = lane >> 4;
        int k0 = s * 32;
        float e[8];
#pragma unroll
        for (int j = 0; j < 4; j++) {
            int ka = k0 + 4 * g + j;
            int kb = k0 + 16 + 4 * g + j;
            float ma = insum[ka] / fn;
            float sa = rsqrtf(insumsq[ka] / fn - ma * ma + 1e-5f);
            float mb = insum[kb] / fn;
            float sb = rsqrtf(insumsq[kb] / fn - mb * mb + 1e-5f);
            e[j]     = W[(size_t)ka * 128 + col] * sa;
            e[4 + j] = W[(size_t)kb * 128 + col] * sb;
        }
#pragma unroll
        for (int j = 0; j < 4; j++) {
            unsigned h0 = f2bf(e[2 * j]), h1 = f2bf(e[2 * j + 1]);
            Phi[(size_t)t * 4 + j] = h0 | (h1 << 16);
            unsigned l0 = f2bf(e[2 * j] - bf2f(h0));
            unsigned l1 = f2bf(e[2 * j + 1] - bf2f(h1));
            Plo[(size_t)t * 4 + j] = l0 | (l1 << 16);
        }
    }
    if (tid < 128) {
        int k0 = bid * 16;
        float s = 0.f;
        for (int k = k0; k < k0 + 16; k++) {
            float m = insum[k] / fn;
            float r = rsqrtf(insumsq[k] / fn - m * m + 1e-5f);
            s += m * r * W[(size_t)k * 128 + tid];
        }
        atomicAdd(&corr[tid], s);
    }
}

// ---- split-bf16 MFMA GEMM (bf16-A only). Three W paths:
//   FULLW>0 (ksteps-worth of W per 64KB chunk): loop chunks {stage chunk,
//     barrier, barrier-free compute, barrier}. K=FULLW => 1 chunk/2 barriers.
//   else BN>=128: double-buffered global_load_lds W, barrier per kstep.
//   else: register W.
// Optional fused second GEMM (W3: BN x 3) via 16-lane shfl -> C3 (BN<=32).
// Optional fused column stats (ssum/ssumsq): per-lane sums over the lane's
// columns, shfl_xor(16/32) over row-groups, g==0 global atomics. No LDS.
template <int BN, int WAVES, int FULLW>
__global__ __launch_bounds__(WAVES * 64) void k_gmfma(
        const unsigned short* __restrict__ Abf,
        const unsigned* __restrict__ Phi, const unsigned* __restrict__ Plo,
        const float* __restrict__ bias, const float* __restrict__ sub,
        const float* __restrict__ add, const int* __restrict__ addidx,
        float* __restrict__ C, unsigned short* __restrict__ Cbf,
        const float* __restrict__ W3, float* __restrict__ C3,
        float* __restrict__ ssum, float* __restrict__ ssumsq,
        int N, int K, int flags) {
    constexpr int NT = BN / 16;
    constexpr int WCOL = (BN == 256) ? 4 : (BN == 128 ? 2 : 1);
    constexpr int WROW = WAVES / WCOL;
    constexpr int NTW = NT / WCOL;
    constexpr int BR = 32 * WROW;
    constexpr bool LDSW = (BN >= 128);
    constexpr int LDSU = (FULLW > 0) ? 2 * NT * (FULLW / 32) * 256
                                     : (LDSW ? 2 * 2 * NT * 256 : 1);
    __shared__ unsigned lds_w[LDSU];
    const int t = threadIdx.x;
    const int w = t >> 6, l = t & 63;
    const int wr = w / WCOL, wc = w % WCOL;
    const int l15 = l & 15, g = l >> 4;
    const int row0 = blockIdx.x * BR + wr * 32;
    const int ctbase = wc * NTW;
    int ar0 = row0 + l15;      ar0 = ar0 < N ? ar0 : N - 1;
    int ar1 = row0 + 16 + l15; ar1 = ar1 < N ? ar1 : N - 1;
    const unsigned short* ab0 = Abf + (size_t)ar0 * K;
    const unsigned short* ab1 = Abf + (size_t)ar1 * K;

    f32x4 acc[2][NTW];
#pragma unroll
    for (int f = 0; f < 2; f++)
#pragma unroll
        for (int ct = 0; ct < NTW; ct++) acc[f][ct] = (f32x4){0.f, 0.f, 0.f, 0.f};

    auto loadA = [&](int s, U8* ahi) {
        const int k0 = s * 32;
#pragma unroll
        for (int f = 0; f < 2; f++) {
            const unsigned short* ab = f ? ab1 : ab0;
            const uint2 hA = *reinterpret_cast<const uint2*>(ab + k0 + 4 * g);
            const uint2 hB = *reinterpret_cast<const uint2*>(ab + k0 + 16 + 4 * g);
            ahi[f].u[0] = hA.x; ahi[f].u[1] = hA.y;
            ahi[f].u[2] = hB.x; ahi[f].u[3] = hB.y;
        }
    };
    auto domfma = [&](U8* wh, U8* wl, U8* ahi) {
#pragma unroll
        for (int ct = 0; ct < NTW; ct++) {
            acc[0][ct] = __builtin_amdgcn_mfma_f32_16x16x32_bf16(ahi[0].v, wh[ct].v, acc[0][ct], 0, 0, 0);
            acc[0][ct] = __builtin_amdgcn_mfma_f32_16x16x32_bf16(ahi[0].v, wl[ct].v, acc[0][ct], 0, 0, 0);
            acc[1][ct] = __builtin_amdgcn_mfma_f32_16x16x32_bf16(ahi[1].v, wh[ct].v, acc[1][ct], 0, 0, 0);
            acc[1][ct] = __builtin_amdgcn_mfma_f32_16x16x32_bf16(ahi[1].v, wl[ct].v, acc[1][ct], 0, 0, 0);
        }
    };

    const int nk = K / 32;

    if constexpr (FULLW > 0) {
        constexpr int NKT = FULLW / 32;     // ksteps per chunk (chunk <= 64KB)
        const int nchunk = K / FULLW;
        U8 wh[NTW], wl[NTW], ahiA[2];
        for (int c = 0; c < nchunk; c++) {
            // stage chunk c: NKT ksteps x 2*NT 1KB tiles (i = s*2NT + j)
            for (int i = w; i < 2 * NT * NKT; i += WAVES) {
                int s = i / (2 * NT);
                int j = i - s * 2 * NT;
                int gs = c * NKT + s;
                const unsigned* gsrc = (j < NT)
                    ? Phi + (size_t)(gs * NT + j) * 256 + l * 4
                    : Plo + (size_t)(gs * NT + (j - NT)) * 256 + l * 4;
                __builtin_amdgcn_global_load_lds(
                    (const __attribute__((address_space(1))) unsigned*)gsrc,
                    (__attribute__((address_space(3))) unsigned*)(lds_w + (size_t)i * 256),
                    16, 0, 0);
            }
            __syncthreads();                // chunk staged + visible
#pragma unroll
            for (int s = 0; s < NKT; s++) {
                loadA(c * NKT + s, ahiA);
                const unsigned* base = lds_w + (size_t)s * (2 * NT * 256);
#pragma unroll
                for (int ct = 0; ct < NTW; ct++) {
                    wh[ct] = *reinterpret_cast<const U8*>(base + (ctbase + ct) * 256 + l * 4);
                    wl[ct] = *reinterpret_cast<const U8*>(base + (NT + ctbase + ct) * 256 + l * 4);
                }
                domfma(wh, wl, ahiA);
            }
            __syncthreads();   // reads done before restage / stores (in-place)
        }
    } else if constexpr (LDSW) {
        auto stage = [&](int s, int b) {
            unsigned* base = lds_w + (size_t)b * (2 * NT * 256);
            for (int i = w; i < 2 * NT; i += WAVES) {
                const unsigned* gsrc = (i < NT)
                    ? Phi + (size_t)(s * NT + i) * 256 + l * 4
                    : Plo + (size_t)(s * NT + (i - NT)) * 256 + l * 4;
                __builtin_amdgcn_global_load_lds(
                    (const __attribute__((address_space(1))) unsigned*)gsrc,
                    (__attribute__((address_space(3))) unsigned*)(base + i * 256),
                    16, 0, 0);
            }
        };
        auto loadWlds = [&](int b, U8* wh, U8* wl) {
            const unsigned* base = lds_w + (size_t)b * (2 * NT * 256);
#pragma unroll
            for (int ct = 0; ct < NTW; ct++) {
                wh[ct] = *reinterpret_cast<const U8*>(base + (ctbase + ct) * 256 + l * 4);
                wl[ct] = *reinterpret_cast<const U8*>(base + (NT + ctbase + ct) * 256 + l * 4);
            }
        };

        U8 wh[NTW], wl[NTW], ahiA[2], ahiB[2];
        stage(0, 0);
        loadA(0, ahiA);
        __syncthreads();                    // W(0) staged + visible
        int s = 0;
        while (true) {
            const bool hasB = (s + 1 < nk);
            if (hasB) { stage(s + 1, (s + 1) & 1); loadA(s + 1, ahiB); }
            loadWlds(s & 1, wh, wl);
            domfma(wh, wl, ahiA);
            __syncthreads();                // drain stage(s+1); protect buf reuse
            if (!hasB) break;
            s++;
            const bool hasA2 = (s + 1 < nk);
            if (hasA2) { stage(s + 1, (s + 1) & 1); loadA(s + 1, ahiA); }
            loadWlds(s & 1, wh, wl);
            domfma(wh, wl, ahiB);
            __syncthreads();
            if (!hasA2) break;
            s++;
        }
        // loop's trailing barrier = all A reads done before stores (in-place safe)
    } else {
        auto loadW = [&](int s, U8* wh, U8* wl) {
            const unsigned* pb = Phi + ((size_t)(s * NT + ctbase) * 64 + l) * 4;
            const unsigned* pl = Plo + ((size_t)(s * NT + ctbase) * 64 + l) * 4;
#pragma unroll
            for (int ct = 0; ct < NTW; ct++) {
                wh[ct] = *reinterpret_cast<const U8*>(pb + (size_t)ct * 256);
                wl[ct] = *reinterpret_cast<const U8*>(pl + (size_t)ct * 256);
            }
        };
        U8 whA[NTW], wlA[NTW], ahiA[2];
        U8 whB[NTW], wlB[NTW], ahiB[2];
        loadW(0, whA, wlA);
        loadA(0, ahiA);
        int s = 0;
        while (true) {
            const bool hasB = (s + 1 < nk);
            if (hasB) { loadW(s + 1, whB, wlB); loadA(s + 1, ahiB); }
            domfma(whA, wlA, ahiA);
            if (!hasB) break;
            const bool hasA2 = (s + 2 < nk);
            if (hasA2) { loadW(s + 2, whA, wlA); loadA(s + 2, ahiA); }
            domfma(whB, wlB, ahiB);
            if (!hasA2) break;
            s += 2;
        }
        __syncthreads();   // all A reads done before any store (in-place safe)
    }

    float sloc[NTW], qloc[NTW];
    if (ssum != nullptr) {
#pragma unroll
        for (int ct = 0; ct < NTW; ct++) { sloc[ct] = 0.f; qloc[ct] = 0.f; }
    }
#pragma unroll
    for (int f = 0; f < 2; f++) {
#pragma unroll
        for (int r = 0; r < 4; r++) {
            int row = row0 + 16 * f + 4 * g + r;
            if (row >= N) continue;   // uniform across l15 group (shfl-safe)
            int gi = (add != nullptr) ? addidx[row] : 0;
            float t0 = 0.f, t1 = 0.f, t2 = 0.f;
#pragma unroll
            for (int ct = 0; ct < NTW; ct++) {
                int col = (ctbase + ct) * 16 + l15;
                float o = acc[f][ct][r];
                if (add != nullptr) o += add[(size_t)gi * BN + col];
                if (sub != nullptr) o -= sub[col];
                if (flags) o = elu1(o + bias[col]);
                if (C != nullptr) C[(size_t)row * BN + col] = o;
                if (Cbf != nullptr) {
                    unsigned hb = f2bf(o);
                    Cbf[(size_t)row * BN + col] = (unsigned short)hb;
                    if (ssum != nullptr) {
                        float ov = bf2f(hb);
                        sloc[ct] += ov; qloc[ct] += ov * ov;
                    }
                }
                if (W3 != nullptr) {
                    t0 += o * W3[col * 3 + 0];
                    t1 += o * W3[col * 3 + 1];
                    t2 += o * W3[col * 3 + 2];
                }
            }
            if (W3 != nullptr) {
#pragma unroll
                for (int m = 1; m < 16; m <<= 1) {
                    t0 += __shfl_xor(t0, m);
                    t1 += __shfl_xor(t1, m);
                    t2 += __shfl_xor(t2, m);
                }
                if (l15 == 0) {
                    C3[(size_t)row * 3 + 0] = t0;
                    C3[(size_t)row * 3 + 1] = t1;
                    C3[(size_t)row * 3 + 2] = t2;
                }
            }
        }
    }
    if (ssum != nullptr) {
        // reduce over the 4 row-groups (g) via lane-xor 16/32; g==0 commits.
#pragma unroll
        for (int ct = 0; ct < NTW; ct++) {
            float s = sloc[ct], q = qloc[ct];
            s += __shfl_xor(s, 16); q += __shfl_xor(q, 16);
            s += __shfl_xor(s, 32); q += __shfl_xor(q, 32);
            if (g == 0) {
                int col = (ctbase + ct) * 16 + l15;
                atomicAdd(&ssum[col], s);
                atomicAdd(&ssumsq[col], q);
            }
        }
    }
}

// ---------------- simple fc (small shapes) ----------------
template <int M, int RPT>
__global__ __launch_bounds__(256) void k_fc(
        const float* __restrict__ A, const float* __restrict__ W,
        const float* __restrict__ bias, const float* __restrict__ add,
        const int* __restrict__ addidx, float* __restrict__ C,
        int N, int K, int flags) {
    constexpr int TX = M / 4;
    constexpr int TY = 256 / TX;
    constexpr int RB = TY * RPT;
    int tx = threadIdx.x % TX;
    int ty = threadIdx.x / TX;
    int row0 = blockIdx.x * RB + ty * RPT;
    float4 acc[RPT];
#pragma unroll
    for (int r = 0; r < RPT; r++) acc[r] = make_float4(0.f, 0.f, 0.f, 0.f);
    for (int k = 0; k < K; k++) {
        float4 w = *reinterpret_cast<const float4*>(&W[(size_t)k * M + tx * 4]);
#pragma unroll
        for (int r = 0; r < RPT; r++) {
            int row = row0 + r;
            row = row < N ? row : N - 1;
            float a = A[(size_t)row * K + k];
            acc[r].x += a * w.x; acc[r].y += a * w.y;
            acc[r].z += a * w.z; acc[r].w += a * w.w;
        }
    }
    if (add != nullptr) {
#pragma unroll
        for (int r = 0; r < RPT; r++) {
            int row = row0 + r;
            if (row < N) {
                int g = addidx[row];
                const float4 v = *reinterpret_cast<const float4*>(&add[(size_t)g * M + tx * 4]);
                acc[r].x += v.x; acc[r].y += v.y; acc[r].z += v.z; acc[r].w += v.w;
            }
        }
    }
    __syncthreads();
    float4 b = make_float4(0.f, 0.f, 0.f, 0.f);
    if (flags) b = *reinterpret_cast<const float4*>(&bias[tx * 4]);
#pragma unroll
    for (int r = 0; r < RPT; r++) {
        int row = row0 + r;
        if (row >= N) break;
        float4 o = acc[r];
        o.x += b.x; o.y += b.y; o.z += b.z; o.w += b.w;
        if (flags) { o.x = elu1(o.x); o.y = elu1(o.y); o.z = elu1(o.z); o.w = elu1(o.w); }
        *reinterpret_cast<float4*>(&C[(size_t)row * M + tx * 4]) = o;
    }
}

// fused: lx = elu(lA @ WfL2 + bfL2) -> lB;  compO = lx @ WO1[256:] -> lA
__global__ __launch_bounds__(256) void k_fcl2(
        const float* __restrict__ A, const float* __restrict__ W1,
        const float* __restrict__ b1, const float* __restrict__ W2,
        float* __restrict__ lxout, float* __restrict__ compO) {
    __shared__ float lx[32][64];
    const int tid = threadIdx.x;
    const int tx = tid % 16, ty = tid / 16;
    const int row0b = blockIdx.x * 32;
    float4 acc[2];
    acc[0] = make_float4(0.f, 0.f, 0.f, 0.f);
    acc[1] = make_float4(0.f, 0.f, 0.f, 0.f);
    for (int k = 0; k < 64; k++) {
        float4 w = *reinterpret_cast<const float4*>(&W1[(size_t)k * 64 + tx * 4]);
#pragma unroll
        for (int r = 0; r < 2; r++) {
            float a = A[(size_t)(row0b + ty * 2 + r) * 64 + k];
            acc[r].x += a * w.x; acc[r].y += a * w.y;
            acc[r].z += a * w.z; acc[r].w += a * w.w;
        }
    }
    float4 b = *reinterpret_cast<const float4*>(&b1[tx * 4]);
#pragma unroll
    for (int r = 0; r < 2; r++) {
        int lr = ty * 2 + r;
        float4 o;
        o.x = elu1(acc[r].x + b.x); o.y = elu1(acc[r].y + b.y);
        o.z = elu1(acc[r].z + b.z); o.w = elu1(acc[r].w + b.w);
        *reinterpret_cast<float4*>(&lxout[(size_t)(row0b + lr) * 64 + tx * 4]) = o;
        lx[lr][tx * 4 + 0] = o.x; lx[lr][tx * 4 + 1] = o.y;
        lx[lr][tx * 4 + 2] = o.z; lx[lr][tx * 4 + 3] = o.w;
    }
    __syncthreads();
    for (int o = tid; o < 32 * 128; o += 256) {
        int r = o >> 7, c = o & 127;
        float s = 0.f;
        for (int k = 0; k < 64; k++) s += lx[r][k] * W2[(size_t)k * 128 + c];
        compO[(size_t)(row0b + r) * 128 + c] = s;
    }
}

// ---- merged: cluster poolavg + pooledges ----
__global__ __launch_bounds__(256) void k_poolmerge(
        const unsigned short* __restrict__ xh, const int* __restrict__ crowptr,
        const int* __restrict__ cdeg, const int* __restrict__ cnodes,
        const float* __restrict__ mu, const float* __restrict__ rstd,
        float* __restrict__ px,
        const int* __restrict__ src, const int* __restrict__ dst,
        const int* __restrict__ bc, unsigned char* __restrict__ bmT, int E) {
    int bid = blockIdx.x;
    if (bid < NCLUST) {
        int cl = bid;
        int c  = threadIdx.x;
        int start = crowptr[cl];
        int cnt = cdeg[cl];
        float acc = 0.f;
        int j = 0;
        for (; j + 3 < cnt; j += 4) {       // 4 independent gathers (ILP)
            int n0 = cnodes[start + j + 0];
            int n1 = cnodes[start + j + 1];
            int n2 = cnodes[start + j + 2];
            int n3 = cnodes[start + j + 3];
            float v0 = bf2f(xh[(size_t)n0 * 256 + c]);
            float v1 = bf2f(xh[(size_t)n1 * 256 + c]);
            float v2 = bf2f(xh[(size_t)n2 * 256 + c]);
            float v3 = bf2f(xh[(size_t)n3 * 256 + c]);
            acc += (v0 + v1) + (v2 + v3);
        }
        for (; j < cnt; j++) {
            int node = cnodes[start + j];
            acc += bf2f(xh[(size_t)node * 256 + c]);
        }
        float res = acc / fmaxf((float)cnt, 1.0f);
        res = (cnt > 0) ? (res - mu[c]) * rstd[c] : 0.f;
        px[(size_t)cl * 256 + c] = res;
    } else {
        int e = (bid - NCLUST) * 256 + threadIdx.x;
        if (e < E) {
            int ps = bc[src[e]];
            int pd = bc[dst[e]];
            bmT[(size_t)pd * NCLUST + ps] = 1;
        }
    }
}

__global__ __launch_bounds__(256) void k_pooldeg(
        const unsigned char* __restrict__ bmT, float* __restrict__ dinvp) {
    int d = blockIdx.x;
    int t = threadIdx.x;
    const unsigned int v = reinterpret_cast<const unsigned int*>(bmT + (size_t)d * NCLUST)[t];
    int s = (v & 0xff) + ((v >> 8) & 0xff) + ((v >> 16) & 0xff) + ((v >> 24) & 0xff);
    if (t == (d >> 2)) s -= (v >> ((d & 3) * 8)) & 0xff;
    __shared__ int red[256];
    red[t] = s; __syncthreads();
    for (int o = 128; o > 0; o >>= 1) {
        if (t < o) red[t] += red[t + o];
        __syncthreads();
    }
    if (t == 0) dinvp[d] = rsqrtf((float)red[0] + 1.0f);
}

template <int F>
__global__ __launch_bounds__(1024) void k_proppool2(
        const float* __restrict__ h, const float* __restrict__ dinvp,
        const unsigned char* __restrict__ bmT, const float* __restrict__ bias,
        float* __restrict__ out) {
    constexpr int SG = 1024 / F;
    const int d = blockIdx.x;
    const int t = threadIdx.x;
    const int f = t & (F - 1);
    const int sg = t / F;
    const unsigned char* bmrow = bmT + (size_t)d * NCLUST;
    float acc = 0.f;
#pragma unroll 4
    for (int s = sg; s < NCLUST; s += SG) {
        float m = (s != d) ? (float)bmrow[s] : 0.f;
        acc += m * dinvp[s] * h[(size_t)s * F + f];
    }
    __shared__ float red[1024];
    red[t] = acc; __syncthreads();
#pragma unroll
    for (int o = SG / 2; o > 0; o >>= 1) {
        if (sg < o) red[t] += red[t + o * F];
        __syncthreads();
    }
    if (sg == 0) {
        float di = dinvp[d];
        float r = di * red[f] + di * di * h[(size_t)d * F + f] + bias[f];
        out[(size_t)d * F + f] = elu1(r);
    }
}

// ---------------------------------------------------------------------------
extern "C" void kernel_launch(void* const* d_in, const int* in_sizes, int n_in,
                              void* d_out, int out_size, void* d_ws, size_t ws_size,
                              hipStream_t stream) {
    const float* x       = (const float*)d_in[0];
    const int*   adj     = (const int*)d_in[1];
    const int*   inb     = (const int*)d_in[3];
    const int*   cluster = (const int*)d_in[4];
    const float* WG1  = (const float*)d_in[5];   const float* bG1  = (const float*)d_in[6];
    const float* WfG1 = (const float*)d_in[7];   const float* bfG1 = (const float*)d_in[8];
    const float* WG2  = (const float*)d_in[9];   const float* bG2  = (const float*)d_in[10];
    const float* WfG2 = (const float*)d_in[11];  const float* bfG2 = (const float*)d_in[12];
    const float* WL1  = (const float*)d_in[13];  const float* bL1  = (const float*)d_in[14];
    const float* WfL1 = (const float*)d_in[15];  const float* bfL1 = (const float*)d_in[16];
    const float* WL2  = (const float*)d_in[17];  const float* bL2  = (const float*)d_in[18];
    const float* WfL2 = (const float*)d_in[19];  const float* bfL2 = (const float*)d_in[20];
    const float* WO1  = (const float*)d_in[21];  const float* bO1  = (const float*)d_in[22];
    const float* WfO1 = (const float*)d_in[23];  const float* bfO1 = (const float*)d_in[24];
    const float* WO2  = (const float*)d_in[25];  const float* bO2  = (const float*)d_in[26];
    const float* WfO2 = (const float*)d_in[27];  const float* bfO2 = (const float*)d_in[28];
    const float* WO3  = (const float*)d_in[29];  const float* bO3  = (const float*)d_in[30];
    const float* WfO3 = (const float*)d_in[31];  const float* bfO3 = (const float*)d_in[32];
    float* out = (float*)d_out;

    const int n = in_sizes[0] / 3;       // 100000
    const int E = in_sizes[1] / 2;       // 1600000
    const int* src = adj;
    const int* dst = adj + E;

    // ---- workspace carve ----
    char* ws = (char*)d_ws;
    size_t off = 0;
    auto alloc = [&](size_t bytes) -> void* {
        void* p = ws + off;
        off = (off + bytes + 255) & ~(size_t)255;
        return p;
    };
    int*   deg     = (int*)alloc((size_t)n * 4);     // zero span 1 start
    int*   fill    = (int*)alloc((size_t)n * 4);
    int*   cdeg    = (int*)alloc(NCLUST * 4);
    int*   cfill   = (int*)alloc(NCLUST * 4);
    int*   rowptr  = (int*)alloc((size_t)n * 4);     // zero span 1 end (exclusive)
    int*   crowptr = (int*)alloc(NCLUST * 4);
    int*   cnodes  = (int*)alloc((size_t)n * 4);
    int*   bcarr   = (int*)alloc((size_t)n * 4);
    float* dinv    = (float*)alloc((size_t)n * 4);
    int*   bsum    = (int*)alloc(512);
    int2*  csr_ev  = (int2*)alloc((size_t)E * 8);
    float* X       = (float*)alloc((size_t)n * 256 * 4);
    unsigned short* Xh = (unsigned short*)alloc((size_t)n * 256 * 2);
    float* B       = (float*)alloc((size_t)n * 128 * 4);
    unsigned short* Bh = (unsigned short*)alloc((size_t)n * 128 * 2);
    float* insum   = (float*)alloc(256 * 4);         // zero span 2 start
    float* insumsq = (float*)alloc(256 * 4);
    float* px      = (float*)alloc((size_t)NCLUST * 256 * 4);
    unsigned char* bmT = (unsigned char*)alloc((size_t)NCLUST * NCLUST);
    float* corr    = (float*)alloc(128 * 4);
    float* mu      = (float*)alloc(256 * 4);         // zero span 2 end (exclusive)
    float* rstd    = (float*)alloc(256 * 4);
    float* dinvp   = (float*)alloc(NCLUST * 4);
    float* lA      = (float*)alloc((size_t)NCLUST * 128 * 4);
    float* lB      = (float*)alloc((size_t)NCLUST * 128 * 4);
    unsigned* pfG1h = (unsigned*)alloc(2048 * 4);   unsigned* pfG1l = (unsigned*)alloc(2048 * 4);
    unsigned* pG2h  = (unsigned*)alloc(8192 * 4);   unsigned* pG2l  = (unsigned*)alloc(8192 * 4);
    unsigned* pfG2h = (unsigned*)alloc(32768 * 4);  unsigned* pfG2l = (unsigned*)alloc(32768 * 4);
    unsigned* pO1h  = (unsigned*)alloc(16384 * 4);  unsigned* pO1l  = (unsigned*)alloc(16384 * 4);
    unsigned* pfO1h = (unsigned*)alloc(8192 * 4);   unsigned* pfO1l = (unsigned*)alloc(8192 * 4);
    unsigned* pO2h  = (unsigned*)alloc(2048 * 4);   unsigned* pO2l  = (unsigned*)alloc(2048 * 4);
    unsigned* pfO2h = (unsigned*)alloc(512 * 4);    unsigned* pfO2l = (unsigned*)alloc(512 * 4);
    (void)ws_size; (void)n_in; (void)out_size;

    unsigned short* Bh1 = Bh;                        // h1/h2 (n x 64 bf16)
    unsigned short* Bh2 = Bh + (size_t)n * 64;       // p64 (n x 64 bf16)

    auto cdiv = [](int a, int b) { return (a + b - 1) / b; };
    const int EB = cdiv(E, 256);
    const int PB = cdiv(n, 4);

    // ---- init: zero scratch + pack all static weights (ONE launch) ----
    int nz1 = (int)(((char*)rowptr - (char*)deg) / 16);
    int nz2 = (int)(((char*)mu - (char*)insum) / 16);
    InitArgs ia;
    ia.d[0] = {WfG1, pfG1h, pfG1l, 64, 64, 0};
    ia.d[1] = {WG2,  pG2h,  pG2l,  64, 256, 512};
    ia.d[2] = {WfG2, pfG2h, pfG2l, 256, 256, 2560};
    ia.d[3] = {WfO1, pfO1h, pfO1l, 128, 128, 10752};
    ia.d[4] = {WO2,  pO2h,  pO2l,  128, 32, 12800};
    ia.d[5] = {WfO2, pfO2h, pfO2l, 32, 32, 13312};
    ia.tot = 13440;
    ia.z1 = (int4*)deg; ia.nz1 = nz1;
    ia.z2 = (int4*)insum; ia.nz2 = nz2;
    int initN = (nz1 + nz2 > ia.tot) ? (nz1 + nz2) : ia.tot;
    k_init<<<cdiv(initN, 256), 256, 0, stream>>>(ia);

    // ---- CSR build ----
    k_hist<<<EB, 256, 0, stream>>>(dst, deg, E);
    int nb = cdiv(n, 1024);
    k_scan_block<<<nb, 256, 0, stream>>>(deg, rowptr, bsum, n);
    k_nodeinit<<<cdiv(n, 256), 256, 0, stream>>>(rowptr, bsum, deg, cluster, inb,
                                                 dinv, bcarr, cdeg, n, nb);
    k_scan_block<<<1, 256, 0, stream>>>(cdeg, crowptr, bsum, NCLUST);
    k_fillc<<<EB, 256, 0, stream>>>(src, dst, dinv, rowptr, fill, csr_ev, E,
                                    bcarr, crowptr, cfill, cnodes, n);

    // ---- global GCN stack (all bf16 activations) ----
    // p3 + fused fc<64>: h1 -> bf16 Bh1
    k_prop3f1<<<cdiv(n, 256), 256, 0, stream>>>(x, dinv, rowptr, deg, csr_ev,
                                                WG1, bG1, Bh1, n);
    // h2 = elu(h1 @ WfG1 + bfG1)  (Bh1 in-place, register-W)  [8-wave]
    k_gmfma<64, 8, 0><<<cdiv(n, 256), 512, 0, stream>>>(Bh1, pfG1h, pfG1l, bfG1,
                                                        nullptr, nullptr, nullptr,
                                                        nullptr, Bh1, nullptr, nullptr,
                                                        nullptr, nullptr, n, 64, 1);
    // p64 = S h2  (bf16 gather -> bf16 Bh2)
    k_prop4sb<64, 1><<<PB, 256, 0, stream>>>(Bh1, dinv, rowptr, deg, csr_ev,
                                             nullptr, nullptr, Bh2, n, 0);
    // h3 = elu(p64 @ WG2 + bG2) -> bf16 (Xh)  [FULLW: 1 chunk, 2 barriers]
    k_gmfma<256, 8, 64><<<cdiv(n, 64), 512, 0, stream>>>(Bh2, pG2h, pG2l, bG2,
                                                         nullptr, nullptr, nullptr,
                                                         nullptr, Xh, nullptr, nullptr,
                                                         nullptr, nullptr, n, 64, 1);
    // h4 = elu(h3 @ WfG2 + bfG2)  (Xh in-place)  [LDS-W dbuf] + FUSED instats
    k_gmfma<256, 8, 0><<<cdiv(n, 64), 512, 0, stream>>>(Xh, pfG2h, pfG2l, bfG2,
                                                        nullptr, nullptr, nullptr,
                                                        nullptr, Xh, nullptr, nullptr,
                                                        insum, insumsq, n, 256, 1);

    // ---- norm finalize/pack/corr (stats fused into h4) ----
    k_normprep<<<17, 256, 0, stream>>>(WO1, insum, insumsq, pO1h, pO1l, corr, mu, rstd, n);

    // ---- cluster pooling (poolavg + pooledges merged) ----
    k_poolmerge<<<NCLUST + EB, 256, 0, stream>>>(Xh, crowptr, cdeg, cnodes, mu, rstd, px,
                                                 src, dst, bcarr, bmT, E);
    k_pooldeg<<<NCLUST, 256, 0, stream>>>(bmT, dinvp);

    // ---- local (pooled) GCN stack ----
    k_fc<128, 2><<<cdiv(NCLUST, 16), 256, 0, stream>>>(px, WL1, nullptr, nullptr, nullptr,
                                                       lA, NCLUST, 256, 0);
    k_proppool2<128><<<NCLUST, 1024, 0, stream>>>(lA, dinvp, bmT, bL1, lB);
    k_fc<128, 2><<<cdiv(NCLUST, 16), 256, 0, stream>>>(lB, WfL1, bfL1, nullptr, nullptr,
                                                       lA, NCLUST, 128, 1);
    k_fc<64, 2><<<cdiv(NCLUST, 32), 256, 0, stream>>>(lA, WL2, nullptr, nullptr, nullptr,
                                                      lB, NCLUST, 128, 0);
    k_proppool2<64><<<NCLUST, 1024, 0, stream>>>(lB, dinvp, bmT, bL2, lA);
    // fused: lx = elu(lA @ WfL2 + bfL2) -> lB; compO = lx @ WO1[256:] -> lA
    k_fcl2<<<NCLUST / 32, 256, 0, stream>>>(lA, WfL2, bfL2, WO1 + (size_t)256 * 128,
                                            lB, lA);

    // ---- output GCN stack ----
    // t1 = Xh @ (rstd*WO1) - corr + compO[bc] -> bf16 (Bh)  [FULLW: 2 chunks]
    k_gmfma<128, 8, 128><<<cdiv(n, 128), 512, 0, stream>>>(Xh, pO1h, pO1l, nullptr,
                                                           corr, lA, bcarr, nullptr, Bh,
                                                           nullptr, nullptr,
                                                           nullptr, nullptr, n, 256, 0);
    k_prop4sb<128, 1><<<PB, 256, 0, stream>>>(Bh, dinv, rowptr, deg, csr_ev,
                                              bO1, nullptr, Xh, n, 1);
    // o2 = elu(o1 @ WfO1 + bfO1)  (Xh in-place)  [FULLW: 1 chunk]
    k_gmfma<128, 8, 128><<<cdiv(n, 128), 512, 0, stream>>>(Xh, pfO1h, pfO1l, bfO1,
                                                           nullptr, nullptr, nullptr,
                                                           nullptr, Xh, nullptr, nullptr,
                                                           nullptr, nullptr, n, 128, 1);
    // t2 = o2 @ WO2  -> bf16 (Bh, N x 32)  [register-W, 8-wave]
    k_gmfma<32, 8, 0><<<cdiv(n, 256), 512, 0, stream>>>(Xh, pO2h, pO2l, nullptr,
                                                        nullptr, nullptr, nullptr,
                                                        nullptr, Bh, nullptr, nullptr,
                                                        nullptr, nullptr, n, 128, 0);
    k_prop4sb<32, 1><<<PB, 256, 0, stream>>>(Bh, dinv, rowptr, deg, csr_ev,
                                             bO2, nullptr, Xh, n, 1);
    // o4 = elu(o3 @ WfO2 + bfO2); t3 = o4 @ WO3 fused -> B (N x 3 f32)
    k_gmfma<32, 8, 0><<<cdiv(n, 256), 512, 0, stream>>>(Xh, pfO2h, pfO2l, bfO2,
                                                        nullptr, nullptr, nullptr,
                                                        nullptr, nullptr, WO3, B,
                                                        nullptr, nullptr, n, 32, 1);
    // o5 = elu(S t3 + bO3); out = elu(o5 @ WfO3 + bfO3)  (fused)
    k_prop3out<<<cdiv(n, 256), 256, 0, stream>>>(B, dinv, rowptr, deg, csr_ev,
                                                 bO3, WfO3, bfO3, out, n);
}

// Round 28
// 1124.445 us; speedup vs baseline: 1.0089x; 1.0089x over previous
//
#include <hip/hip_runtime.h>

// ---------------------------------------------------------------------------
// GCN3D. R9: split-bf16 MFMA GEMMs. R13: prop4s+norm-fold. R14/15/17/23: bf16
// activations everywhere. R17/R20/R21/R22: launch merging, int2 edges.
// R24: LDS-W staging. R26: FULLW one-barrier k-loop (1125us best). R27:
//   chunked FULLW for t1 (kept) BUT instats-in-h4 via global atomics FAILED
//   AGAIN (+37us, WRITE_SIZE +6.3MB: 800K atomics x 64B write-allocate into
//   512B of accumulators). Column-stat fusion is structurally bad -- closed.
// R28: revert to standalone k_instats (51MB stream, ~20us); h4 stats=nullptr.
// ---------------------------------------------------------------------------

#define NCLUST 1024

typedef short bf16x8 __attribute__((ext_vector_type(8)));
typedef float f32x4 __attribute__((ext_vector_type(4)));

__device__ __forceinline__ float elu1(float x) { return x > 0.f ? x : expm1f(x); }

__device__ __forceinline__ unsigned f2bf(float f) {
    union { float f; unsigned u; } c; c.f = f;
    unsigned u = c.u;
    return (u + 0x7fffu + ((u >> 16) & 1u)) >> 16;
}
__device__ __forceinline__ float bf2f(unsigned h) {
    union { unsigned u; float f; } c; c.u = h << 16; return c.f;
}

union U8 { unsigned u[4]; bf16x8 v; };

// ---- W pre-pack body ----
__device__ __forceinline__ void wpack_body(const float* W, unsigned* Phi, unsigned* Plo,
                                           int K, int BN, int t) {
    int NT = BN / 16;
    int lane = t & 63;
    int rest = t >> 6;
    int ct = rest % NT;
    int s = rest / NT;
    int col = ct * 16 + (lane & 15);
    int g = lane >> 4;
    int k0 = s * 32;
    float e[8];
#pragma unroll
    for (int j = 0; j < 4; j++) {
        e[j]     = W[(size_t)(k0 + 4 * g + j) * BN + col];
        e[4 + j] = W[(size_t)(k0 + 16 + 4 * g + j) * BN + col];
    }
#pragma unroll
    for (int j = 0; j < 4; j++) {
        unsigned h0 = f2bf(e[2 * j]), h1 = f2bf(e[2 * j + 1]);
        Phi[(size_t)t * 4 + j] = h0 | (h1 << 16);
        unsigned l0 = f2bf(e[2 * j] - bf2f(h0));
        unsigned l1 = f2bf(e[2 * j + 1] - bf2f(h1));
        Plo[(size_t)t * 4 + j] = l0 | (l1 << 16);
    }
}

struct PackDesc { const float* W; unsigned* Ph; unsigned* Pl; int K, BN, tbase; };
struct InitArgs {
    PackDesc d[6]; int tot;
    int4* z1; int nz1; int4* z2; int nz2;
};

__global__ void k_init(InitArgs a) {
    int t = blockIdx.x * 256 + threadIdx.x;
    if (t < a.nz1) a.z1[t] = make_int4(0, 0, 0, 0);
    else if (t - a.nz1 < a.nz2) a.z2[t - a.nz1] = make_int4(0, 0, 0, 0);
    if (t < a.tot) {
        int i = 0;
#pragma unroll
        for (int j = 1; j < 6; j++) if (t >= a.d[j].tbase) i = j;
        wpack_body(a.d[i].W, a.d[i].Ph, a.d[i].Pl, a.d[i].K, a.d[i].BN,
                   t - a.d[i].tbase);
    }
}

// ---------------- CSR build ----------------
__global__ void k_hist(const int* __restrict__ key, int* __restrict__ deg, int E) {
    int e = blockIdx.x * 256 + threadIdx.x;
    if (e < E) atomicAdd(&deg[key[e]], 1);
}

__global__ void k_scan_block(const int* __restrict__ deg, int* __restrict__ rowptr,
                             int* __restrict__ bsum, int n) {
    __shared__ int lds[256];
    int tid = threadIdx.x;
    int base = blockIdx.x * 1024 + tid * 4;
    int v0 = base + 0 < n ? deg[base + 0] : 0;
    int v1 = base + 1 < n ? deg[base + 1] : 0;
    int v2 = base + 2 < n ? deg[base + 2] : 0;
    int v3 = base + 3 < n ? deg[base + 3] : 0;
    int tsum = v0 + v1 + v2 + v3;
    lds[tid] = tsum; __syncthreads();
    for (int off = 1; off < 256; off <<= 1) {
        int t = (tid >= off) ? lds[tid - off] : 0;
        __syncthreads();
        lds[tid] += t;
        __syncthreads();
    }
    int run = lds[tid] - tsum;
    if (base + 0 < n) rowptr[base + 0] = run; run += v0;
    if (base + 1 < n) rowptr[base + 1] = run; run += v1;
    if (base + 2 < n) rowptr[base + 2] = run; run += v2;
    if (base + 3 < n) rowptr[base + 3] = run;
    if (tid == 255) bsum[blockIdx.x] = lds[255];
}

// merged: bsum scan + rowptr finalize + dinv + bc + cluster hist
__global__ void k_nodeinit(int* __restrict__ rowptr, const int* __restrict__ bsum,
                           const int* __restrict__ deg, const int* __restrict__ cluster,
                           const int* __restrict__ inb, float* __restrict__ dinv,
                           int* __restrict__ bc, int* __restrict__ cdeg, int n, int nb) {
    __shared__ int pfx[128];
    int tid = threadIdx.x;
    if (tid < 128) pfx[tid] = (tid < nb) ? bsum[tid] : 0;
    __syncthreads();
    for (int off = 1; off < 128; off <<= 1) {
        int v = 0;
        if (tid < 128 && tid >= off) v = pfx[tid - off];
        __syncthreads();
        if (tid < 128) pfx[tid] += v;
        __syncthreads();
    }
    int i = blockIdx.x * 256 + tid;
    if (i >= n) return;
    int j = i >> 10;
    int base = (j == 0) ? 0 : pfx[j - 1];
    rowptr[i] += base;
    dinv[i] = rsqrtf((float)deg[i] + 1.0f);
    int c = cluster[i] + inb[i] * NCLUST;
    bc[i] = c;
    atomicAdd(&cdeg[c], 1);
}

// merged: edge CSR fill (packed int2) + cluster member fill
__global__ void k_fillc(const int* __restrict__ src, const int* __restrict__ dst,
                        const float* __restrict__ dinv, const int* __restrict__ rowptr,
                        int* __restrict__ fill, int2* __restrict__ csr_ev, int E,
                        const int* __restrict__ bc, const int* __restrict__ crowptr,
                        int* __restrict__ cfill, int* __restrict__ cnodes, int n) {
    int e = blockIdx.x * 256 + threadIdx.x;
    if (e < E) {
        int d = dst[e];
        int pos = rowptr[d] + atomicAdd(&fill[d], 1);
        int s = src[e];
        csr_ev[pos] = make_int2(s, __float_as_int(dinv[s]));
    }
    if (e < n) {
        int c = bc[e];
        int pos = crowptr[c] + atomicAdd(&cfill[c], 1);
        cnodes[pos] = e;
    }
}

// ------ GCN propagation, bf16 input; OB=0 f32 out, OB=1 bf16 out ------
template <int F, int OB>
__global__ __launch_bounds__(256) void k_prop4sb(
        const unsigned short* __restrict__ hbf, const float* __restrict__ dinv,
        const int* __restrict__ rowptr, const int* __restrict__ deg,
        const int2* __restrict__ csr_ev,
        const float* __restrict__ bias, float* __restrict__ outf,
        unsigned short* __restrict__ outb, int n, int flags) {
    constexpr int FS = F / 4;
    constexpr int ES = 64 / FS;
    const int node = (blockIdx.x * 256 + threadIdx.x) >> 6;
    if (node >= n) return;
    const int l = threadIdx.x & 63;
    const int fs = l & (FS - 1);
    const int ep = l / FS;
    const int fi = fs * 4;
    const int start = rowptr[node];
    const int cnt = deg[node];
    float ax = 0.f, ay = 0.f, az = 0.f, aw = 0.f;
    for (int j = ep; j < cnt; j += ES) {
        const int2 ev = csr_ev[start + j];
        int s = ev.x;
        float w = __int_as_float(ev.y);
        const ushort4 v = *reinterpret_cast<const ushort4*>(&hbf[(size_t)s * F + fi]);
        ax += w * bf2f(v.x); ay += w * bf2f(v.y);
        az += w * bf2f(v.z); aw += w * bf2f(v.w);
    }
#pragma unroll
    for (int off = FS; off < 64; off <<= 1) {
        ax += __shfl_xor(ax, off);
        ay += __shfl_xor(ay, off);
        az += __shfl_xor(az, off);
        aw += __shfl_xor(aw, off);
    }
    if (ep == 0) {
        float di = dinv[node];
        const ushort4 sv = *reinterpret_cast<const ushort4*>(&hbf[(size_t)node * F + fi]);
        float4 o;
        o.x = di * ax + di * di * bf2f(sv.x);
        o.y = di * ay + di * di * bf2f(sv.y);
        o.z = di * az + di * di * bf2f(sv.z);
        o.w = di * aw + di * di * bf2f(sv.w);
        if (flags) {
            const float4 b = *reinterpret_cast<const float4*>(&bias[fi]);
            o.x = elu1(o.x + b.x); o.y = elu1(o.y + b.y);
            o.z = elu1(o.z + b.z); o.w = elu1(o.w + b.w);
        }
        if constexpr (OB) {
            ushort4 ob;
            ob.x = (unsigned short)f2bf(o.x); ob.y = (unsigned short)f2bf(o.y);
            ob.z = (unsigned short)f2bf(o.z); ob.w = (unsigned short)f2bf(o.w);
            *reinterpret_cast<ushort4*>(&outb[(size_t)node * F + fi]) = ob;
        } else {
            *reinterpret_cast<float4*>(&outf[(size_t)node * F + fi]) = o;
        }
    }
}

// prop3 on x + fused fc<64> -> bf16 out (N x 64)
__global__ void k_prop3f1(const float* __restrict__ h, const float* __restrict__ dinv,
                          const int* __restrict__ rowptr, const int* __restrict__ deg,
                          const int2* __restrict__ csr_ev,
                          const float* __restrict__ WG1, const float* __restrict__ bG1,
                          unsigned short* __restrict__ outb, int n) {
    int node = blockIdx.x * 256 + threadIdx.x;
    if (node >= n) return;
    int start = rowptr[node], cnt = deg[node];
    float a0 = 0.f, a1 = 0.f, a2 = 0.f;
    for (int j = 0; j < cnt; j++) {
        const int2 ev = csr_ev[start + j];
        int s = ev.x;
        float w = __int_as_float(ev.y);
        a0 += w * h[(size_t)s * 3 + 0];
        a1 += w * h[(size_t)s * 3 + 1];
        a2 += w * h[(size_t)s * 3 + 2];
    }
    float di = dinv[node];
    float p0 = di * a0 + di * di * h[(size_t)node * 3 + 0];
    float p1 = di * a1 + di * di * h[(size_t)node * 3 + 1];
    float p2 = di * a2 + di * di * h[(size_t)node * 3 + 2];
    unsigned short* op = outb + (size_t)node * 64;
#pragma unroll 4
    for (int c = 0; c < 64; c += 4) {
        ushort4 ob;
        ob.x = (unsigned short)f2bf(elu1(p0 * WG1[c + 0] + p1 * WG1[64 + c + 0] + p2 * WG1[128 + c + 0] + bG1[c + 0]));
        ob.y = (unsigned short)f2bf(elu1(p0 * WG1[c + 1] + p1 * WG1[64 + c + 1] + p2 * WG1[128 + c + 1] + bG1[c + 1]));
        ob.z = (unsigned short)f2bf(elu1(p0 * WG1[c + 2] + p1 * WG1[64 + c + 2] + p2 * WG1[128 + c + 2] + bG1[c + 2]));
        ob.w = (unsigned short)f2bf(elu1(p0 * WG1[c + 3] + p1 * WG1[64 + c + 3] + p2 * WG1[128 + c + 3] + bG1[c + 3]));
        *reinterpret_cast<ushort4*>(op + c) = ob;
    }
}

// prop3 on t3 (+bO3, elu) + fused final fc3
__global__ void k_prop3out(const float* __restrict__ h, const float* __restrict__ dinv,
                           const int* __restrict__ rowptr, const int* __restrict__ deg,
                           const int2* __restrict__ csr_ev,
                           const float* __restrict__ bO3, const float* __restrict__ WfO3,
                           const float* __restrict__ bfO3, float* __restrict__ out, int n) {
    int node = blockIdx.x * 256 + threadIdx.x;
    if (node >= n) return;
    int start = rowptr[node], cnt = deg[node];
    float a0 = 0.f, a1 = 0.f, a2 = 0.f;
    for (int j = 0; j < cnt; j++) {
        const int2 ev = csr_ev[start + j];
        int s = ev.x;
        float w = __int_as_float(ev.y);
        a0 += w * h[(size_t)s * 3 + 0];
        a1 += w * h[(size_t)s * 3 + 1];
        a2 += w * h[(size_t)s * 3 + 2];
    }
    float di = dinv[node];
    float o0 = elu1(di * a0 + di * di * h[(size_t)node * 3 + 0] + bO3[0]);
    float o1 = elu1(di * a1 + di * di * h[(size_t)node * 3 + 1] + bO3[1]);
    float o2 = elu1(di * a2 + di * di * h[(size_t)node * 3 + 2] + bO3[2]);
#pragma unroll
    for (int c = 0; c < 3; c++) {
        out[(size_t)node * 3 + c] =
            elu1(o0 * WfO3[c] + o1 * WfO3[3 + c] + o2 * WfO3[6 + c] + bfO3[c]);
    }
}

// ---- merged: infinal + rstd-scaled WO1 pack + corr (17 blocks x 256) ----
__global__ void k_normprep(const float* __restrict__ W, const float* __restrict__ insum,
                           const float* __restrict__ insumsq, unsigned* __restrict__ Phi,
                           unsigned* __restrict__ Plo, float* __restrict__ corr,
                           float* __restrict__ mu, float* __restrict__ rstd, int n) {
    const float fn = (float)n;
    const int bid = blockIdx.x, tid = threadIdx.x;
    if (bid == 16) {
        float m = insum[tid] / fn;
        float var = insumsq[tid] / fn - m * m;
        mu[tid] = m;
        rstd[tid] = rsqrtf(var + 1e-5f);
        return;
    }
    {
        int t = bid * 256 + tid;
        int lane = t & 63, rest = t >> 6;
        int ct = rest % 8, s = rest / 8;
        int col = ct * 16 + (lane & 15);
        int g = lane >> 4;
        int k0 = s * 32;
        float e[8];
#pragma unroll
        for (int j = 0; j < 4; j++) {
            int ka = k0 + 4 * g + j;
            int kb = k0 + 16 + 4 * g + j;
            float ma = insum[ka] / fn;
            float sa = rsqrtf(insumsq[ka] / fn - ma * ma + 1e-5f);
            float mb = insum[kb] / fn;
            float sb = rsqrtf(insumsq[kb] / fn - mb * mb + 1e-5f);
            e[j]     = W[(size_t)ka * 128 + col] * sa;
            e[4 + j] = W[(size_t)kb * 128 + col] * sb;
        }
#pragma unroll
        for (int j = 0; j < 4; j++) {
            unsigned h0 = f2bf(e[2 * j]), h1 = f2bf(e[2 * j + 1]);
            Phi[(size_t)t * 4 + j] = h0 | (h1 << 16);
            unsigned l0 = f2bf(e[2 * j] - bf2f(h0));
            unsigned l1 = f2bf(e[2 * j + 1] - bf2f(h1));
            Plo[(size_t)t * 4 + j] = l0 | (l1 << 16);
        }
    }
    if (tid < 128) {
        int k0 = bid * 16;
        float s = 0.f;
        for (int k = k0; k < k0 + 16; k++) {
            float m = insum[k] / fn;
            float r = rsqrtf(insumsq[k] / fn - m * m + 1e-5f);
            s += m * r * W[(size_t)k * 128 + tid];
        }
        atomicAdd(&corr[tid], s);
    }
}

// ---- split-bf16 MFMA GEMM (bf16-A only). Three W paths:
//   FULLW>0 (ksteps-worth of W per 64KB chunk): loop chunks {stage chunk,
//     barrier, barrier-free compute, barrier}. K=FULLW => 1 chunk/2 barriers.
//   else BN>=128: double-buffered global_load_lds W, barrier per kstep.
//   else: register W.
// Optional fused second GEMM (W3: BN x 3) via 16-lane shfl -> C3 (BN<=32).
template <int BN, int WAVES, int FULLW>
__global__ __launch_bounds__(WAVES * 64) void k_gmfma(
        const unsigned short* __restrict__ Abf,
        const unsigned* __restrict__ Phi, const unsigned* __restrict__ Plo,
        const float* __restrict__ bias, const float* __restrict__ sub,
        const float* __restrict__ add, const int* __restrict__ addidx,
        float* __restrict__ C, unsigned short* __restrict__ Cbf,
        const float* __restrict__ W3, float* __restrict__ C3,
        int N, int K, int flags) {
    constexpr int NT = BN / 16;
    constexpr int WCOL = (BN == 256) ? 4 : (BN == 128 ? 2 : 1);
    constexpr int WROW = WAVES / WCOL;
    constexpr int NTW = NT / WCOL;
    constexpr int BR = 32 * WROW;
    constexpr bool LDSW = (BN >= 128);
    constexpr int LDSU = (FULLW > 0) ? 2 * NT * (FULLW / 32) * 256
                                     : (LDSW ? 2 * 2 * NT * 256 : 1);
    __shared__ unsigned lds_w[LDSU];
    const int t = threadIdx.x;
    const int w = t >> 6, l = t & 63;
    const int wr = w / WCOL, wc = w % WCOL;
    const int l15 = l & 15, g = l >> 4;
    const int row0 = blockIdx.x * BR + wr * 32;
    const int ctbase = wc * NTW;
    int ar0 = row0 + l15;      ar0 = ar0 < N ? ar0 : N - 1;
    int ar1 = row0 + 16 + l15; ar1 = ar1 < N ? ar1 : N - 1;
    const unsigned short* ab0 = Abf + (size_t)ar0 * K;
    const unsigned short* ab1 = Abf + (size_t)ar1 * K;

    f32x4 acc[2][NTW];
#pragma unroll
    for (int f = 0; f < 2; f++)
#pragma unroll
        for (int ct = 0; ct < NTW; ct++) acc[f][ct] = (f32x4){0.f, 0.f, 0.f, 0.f};

    auto loadA = [&](int s, U8* ahi) {
        const int k0 = s * 32;
#pragma unroll
        for (int f = 0; f < 2; f++) {
            const unsigned short* ab = f ? ab1 : ab0;
            const uint2 hA = *reinterpret_cast<const uint2*>(ab + k0 + 4 * g);
            const uint2 hB = *reinterpret_cast<const uint2*>(ab + k0 + 16 + 4 * g);
            ahi[f].u[0] = hA.x; ahi[f].u[1] = hA.y;
            ahi[f].u[2] = hB.x; ahi[f].u[3] = hB.y;
        }
    };
    auto domfma = [&](U8* wh, U8* wl, U8* ahi) {
#pragma unroll
        for (int ct = 0; ct < NTW; ct++) {
            acc[0][ct] = __builtin_amdgcn_mfma_f32_16x16x32_bf16(ahi[0].v, wh[ct].v, acc[0][ct], 0, 0, 0);
            acc[0][ct] = __builtin_amdgcn_mfma_f32_16x16x32_bf16(ahi[0].v, wl[ct].v, acc[0][ct], 0, 0, 0);
            acc[1][ct] = __builtin_amdgcn_mfma_f32_16x16x32_bf16(ahi[1].v, wh[ct].v, acc[1][ct], 0, 0, 0);
            acc[1][ct] = __builtin_amdgcn_mfma_f32_16x16x32_bf16(ahi[1].v, wl[ct].v, acc[1][ct], 0, 0, 0);
        }
    };

    const int nk = K / 32;

    if constexpr (FULLW > 0) {
        constexpr int NKT = FULLW / 32;     // ksteps per chunk (chunk <= 64KB)
        const int nchunk = K / FULLW;
        U8 wh[NTW], wl[NTW], ahiA[2];
        for (int c = 0; c < nchunk; c++) {
            // stage chunk c: NKT ksteps x 2*NT 1KB tiles (i = s*2NT + j)
            for (int i = w; i < 2 * NT * NKT; i += WAVES) {
                int s = i / (2 * NT);
                int j = i - s * 2 * NT;
                int gs = c * NKT + s;
                const unsigned* gsrc = (j < NT)
                    ? Phi + (size_t)(gs * NT + j) * 256 + l * 4
                    : Plo + (size_t)(gs * NT + (j - NT)) * 256 + l * 4;
                __builtin_amdgcn_global_load_lds(
                    (const __attribute__((address_space(1))) unsigned*)gsrc,
                    (__attribute__((address_space(3))) unsigned*)(lds_w + (size_t)i * 256),
                    16, 0, 0);
            }
            __syncthreads();                // chunk staged + visible
#pragma unroll
            for (int s = 0; s < NKT; s++) {
                loadA(c * NKT + s, ahiA);
                const unsigned* base = lds_w + (size_t)s * (2 * NT * 256);
#pragma unroll
                for (int ct = 0; ct < NTW; ct++) {
                    wh[ct] = *reinterpret_cast<const U8*>(base + (ctbase + ct) * 256 + l * 4);
                    wl[ct] = *reinterpret_cast<const U8*>(base + (NT + ctbase + ct) * 256 + l * 4);
                }
                domfma(wh, wl, ahiA);
            }
            __syncthreads();   // reads done before restage / stores (in-place)
        }
    } else if constexpr (LDSW) {
        auto stage = [&](int s, int b) {
            unsigned* base = lds_w + (size_t)b * (2 * NT * 256);
            for (int i = w; i < 2 * NT; i += WAVES) {
                const unsigned* gsrc = (i < NT)
                    ? Phi + (size_t)(s * NT + i) * 256 + l * 4
                    : Plo + (size_t)(s * NT + (i - NT)) * 256 + l * 4;
                __builtin_amdgcn_global_load_lds(
                    (const __attribute__((address_space(1))) unsigned*)gsrc,
                    (__attribute__((address_space(3))) unsigned*)(base + i * 256),
                    16, 0, 0);
            }
        };
        auto loadWlds = [&](int b, U8* wh, U8* wl) {
            const unsigned* base = lds_w + (size_t)b * (2 * NT * 256);
#pragma unroll
            for (int ct = 0; ct < NTW; ct++) {
                wh[ct] = *reinterpret_cast<const U8*>(base + (ctbase + ct) * 256 + l * 4);
                wl[ct] = *reinterpret_cast<const U8*>(base + (NT + ctbase + ct) * 256 + l * 4);
            }
        };

        U8 wh[NTW], wl[NTW], ahiA[2], ahiB[2];
        stage(0, 0);
        loadA(0, ahiA);
        __syncthreads();                    // W(0) staged + visible
        int s = 0;
        while (true) {
            const bool hasB = (s + 1 < nk);
            if (hasB) { stage(s + 1, (s + 1) & 1); loadA(s + 1, ahiB); }
            loadWlds(s & 1, wh, wl);
            domfma(wh, wl, ahiA);
            __syncthreads();                // drain stage(s+1); protect buf reuse
            if (!hasB) break;
            s++;
            const bool hasA2 = (s + 1 < nk);
            if (hasA2) { stage(s + 1, (s + 1) & 1); loadA(s + 1, ahiA); }
            loadWlds(s & 1, wh, wl);
            domfma(wh, wl, ahiB);
            __syncthreads();
            if (!hasA2) break;
            s++;
        }
        // loop's trailing barrier = all A reads done before stores (in-place safe)
    } else {
        auto loadW = [&](int s, U8* wh, U8* wl) {
            const unsigned* pb = Phi + ((size_t)(s * NT + ctbase) * 64 + l) * 4;
            const unsigned* pl = Plo + ((size_t)(s * NT + ctbase) * 64 + l) * 4;
#pragma unroll
            for (int ct = 0; ct < NTW; ct++) {
                wh[ct] = *reinterpret_cast<const U8*>(pb + (size_t)ct * 256);
                wl[ct] = *reinterpret_cast<const U8*>(pl + (size_t)ct * 256);
            }
        };
        U8 whA[NTW], wlA[NTW], ahiA[2];
        U8 whB[NTW], wlB[NTW], ahiB[2];
        loadW(0, whA, wlA);
        loadA(0, ahiA);
        int s = 0;
        while (true) {
            const bool hasB = (s + 1 < nk);
            if (hasB) { loadW(s + 1, whB, wlB); loadA(s + 1, ahiB); }
            domfma(whA, wlA, ahiA);
            if (!hasB) break;
            const bool hasA2 = (s + 2 < nk);
            if (hasA2) { loadW(s + 2, whA, wlA); loadA(s + 2, ahiA); }
            domfma(whB, wlB, ahiB);
            if (!hasA2) break;
            s += 2;
        }
        __syncthreads();   // all A reads done before any store (in-place safe)
    }

#pragma unroll
    for (int f = 0; f < 2; f++) {
#pragma unroll
        for (int r = 0; r < 4; r++) {
            int row = row0 + 16 * f + 4 * g + r;
            if (row >= N) continue;   // uniform across l15 group (shfl-safe)
            int gi = (add != nullptr) ? addidx[row] : 0;
            float t0 = 0.f, t1 = 0.f, t2 = 0.f;
#pragma unroll
            for (int ct = 0; ct < NTW; ct++) {
                int col = (ctbase + ct) * 16 + l15;
                float o = acc[f][ct][r];
                if (add != nullptr) o += add[(size_t)gi * BN + col];
                if (sub != nullptr) o -= sub[col];
                if (flags) o = elu1(o + bias[col]);
                if (C != nullptr) C[(size_t)row * BN + col] = o;
                if (Cbf != nullptr) Cbf[(size_t)row * BN + col] = (unsigned short)f2bf(o);
                if (W3 != nullptr) {
                    t0 += o * W3[col * 3 + 0];
                    t1 += o * W3[col * 3 + 1];
                    t2 += o * W3[col * 3 + 2];
                }
            }
            if (W3 != nullptr) {
#pragma unroll
                for (int m = 1; m < 16; m <<= 1) {
                    t0 += __shfl_xor(t0, m);
                    t1 += __shfl_xor(t1, m);
                    t2 += __shfl_xor(t2, m);
                }
                if (l15 == 0) {
                    C3[(size_t)row * 3 + 0] = t0;
                    C3[(size_t)row * 3 + 1] = t1;
                    C3[(size_t)row * 3 + 2] = t2;
                }
            }
        }
    }
}

// ---------------- simple fc (small shapes) ----------------
template <int M, int RPT>
__global__ __launch_bounds__(256) void k_fc(
        const float* __restrict__ A, const float* __restrict__ W,
        const float* __restrict__ bias, const float* __restrict__ add,
        const int* __restrict__ addidx, float* __restrict__ C,
        int N, int K, int flags) {
    constexpr int TX = M / 4;
    constexpr int TY = 256 / TX;
    constexpr int RB = TY * RPT;
    int tx = threadIdx.x % TX;
    int ty = threadIdx.x / TX;
    int row0 = blockIdx.x * RB + ty * RPT;
    float4 acc[RPT];
#pragma unroll
    for (int r = 0; r < RPT; r++) acc[r] = make_float4(0.f, 0.f, 0.f, 0.f);
    for (int k = 0; k < K; k++) {
        float4 w = *reinterpret_cast<const float4*>(&W[(size_t)k * M + tx * 4]);
#pragma unroll
        for (int r = 0; r < RPT; r++) {
            int row = row0 + r;
            row = row < N ? row : N - 1;
            float a = A[(size_t)row * K + k];
            acc[r].x += a * w.x; acc[r].y += a * w.y;
            acc[r].z += a * w.z; acc[r].w += a * w.w;
        }
    }
    if (add != nullptr) {
#pragma unroll
        for (int r = 0; r < RPT; r++) {
            int row = row0 + r;
            if (row < N) {
                int g = addidx[row];
                const float4 v = *reinterpret_cast<const float4*>(&add[(size_t)g * M + tx * 4]);
                acc[r].x += v.x; acc[r].y += v.y; acc[r].z += v.z; acc[r].w += v.w;
            }
        }
    }
    __syncthreads();
    float4 b = make_float4(0.f, 0.f, 0.f, 0.f);
    if (flags) b = *reinterpret_cast<const float4*>(&bias[tx * 4]);
#pragma unroll
    for (int r = 0; r < RPT; r++) {
        int row = row0 + r;
        if (row >= N) break;
        float4 o = acc[r];
        o.x += b.x; o.y += b.y; o.z += b.z; o.w += b.w;
        if (flags) { o.x = elu1(o.x); o.y = elu1(o.y); o.z = elu1(o.z); o.w = elu1(o.w); }
        *reinterpret_cast<float4*>(&C[(size_t)row * M + tx * 4]) = o;
    }
}

// fused: lx = elu(lA @ WfL2 + bfL2) -> lB;  compO = lx @ WO1[256:] -> lA
__global__ __launch_bounds__(256) void k_fcl2(
        const float* __restrict__ A, const float* __restrict__ W1,
        const float* __restrict__ b1, const float* __restrict__ W2,
        float* __restrict__ lxout, float* __restrict__ compO) {
    __shared__ float lx[32][64];
    const int tid = threadIdx.x;
    const int tx = tid % 16, ty = tid / 16;
    const int row0b = blockIdx.x * 32;
    float4 acc[2];
    acc[0] = make_float4(0.f, 0.f, 0.f, 0.f);
    acc[1] = make_float4(0.f, 0.f, 0.f, 0.f);
    for (int k = 0; k < 64; k++) {
        float4 w = *reinterpret_cast<const float4*>(&W1[(size_t)k * 64 + tx * 4]);
#pragma unroll
        for (int r = 0; r < 2; r++) {
            float a = A[(size_t)(row0b + ty * 2 + r) * 64 + k];
            acc[r].x += a * w.x; acc[r].y += a * w.y;
            acc[r].z += a * w.z; acc[r].w += a * w.w;
        }
    }
    float4 b = *reinterpret_cast<const float4*>(&b1[tx * 4]);
#pragma unroll
    for (int r = 0; r < 2; r++) {
        int lr = ty * 2 + r;
        float4 o;
        o.x = elu1(acc[r].x + b.x); o.y = elu1(acc[r].y + b.y);
        o.z = elu1(acc[r].z + b.z); o.w = elu1(acc[r].w + b.w);
        *reinterpret_cast<float4*>(&lxout[(size_t)(row0b + lr) * 64 + tx * 4]) = o;
        lx[lr][tx * 4 + 0] = o.x; lx[lr][tx * 4 + 1] = o.y;
        lx[lr][tx * 4 + 2] = o.z; lx[lr][tx * 4 + 3] = o.w;
    }
    __syncthreads();
    for (int o = tid; o < 32 * 128; o += 256) {
        int r = o >> 7, c = o & 127;
        float s = 0.f;
        for (int k = 0; k < 64; k++) s += lx[r][k] * W2[(size_t)k * 128 + c];
        compO[(size_t)(row0b + r) * 128 + c] = s;
    }
}

// ---------------- instance norm stats (bf16 input) ----------------
__global__ void k_instats(const unsigned short* __restrict__ h, float* __restrict__ sum,
                          float* __restrict__ sumsq, int n) {
    int c = threadIdx.x;
    int r0 = blockIdx.x * 128;
    int r1 = r0 + 128 < n ? r0 + 128 : n;
    float s = 0.f, q = 0.f;
#pragma unroll 4
    for (int r = r0; r < r1; r++) {
        float v = bf2f(h[(size_t)r * 256 + c]);
        s += v; q += v * v;
    }
    atomicAdd(&sum[c], s);
    atomicAdd(&sumsq[c], q);
}

// ---- merged: cluster poolavg + pooledges ----
__global__ __launch_bounds__(256) void k_poolmerge(
        const unsigned short* __restrict__ xh, const int* __restrict__ crowptr,
        const int* __restrict__ cdeg, const int* __restrict__ cnodes,
        const float* __restrict__ mu, const float* __restrict__ rstd,
        float* __restrict__ px,
        const int* __restrict__ src, const int* __restrict__ dst,
        const int* __restrict__ bc, unsigned char* __restrict__ bmT, int E) {
    int bid = blockIdx.x;
    if (bid < NCLUST) {
        int cl = bid;
        int c  = threadIdx.x;
        int start = crowptr[cl];
        int cnt = cdeg[cl];
        float acc = 0.f;
        int j = 0;
        for (; j + 3 < cnt; j += 4) {       // 4 independent gathers (ILP)
            int n0 = cnodes[start + j + 0];
            int n1 = cnodes[start + j + 1];
            int n2 = cnodes[start + j + 2];
            int n3 = cnodes[start + j + 3];
            float v0 = bf2f(xh[(size_t)n0 * 256 + c]);
            float v1 = bf2f(xh[(size_t)n1 * 256 + c]);
            float v2 = bf2f(xh[(size_t)n2 * 256 + c]);
            float v3 = bf2f(xh[(size_t)n3 * 256 + c]);
            acc += (v0 + v1) + (v2 + v3);
        }
        for (; j < cnt; j++) {
            int node = cnodes[start + j];
            acc += bf2f(xh[(size_t)node * 256 + c]);
        }
        float res = acc / fmaxf((float)cnt, 1.0f);
        res = (cnt > 0) ? (res - mu[c]) * rstd[c] : 0.f;
        px[(size_t)cl * 256 + c] = res;
    } else {
        int e = (bid - NCLUST) * 256 + threadIdx.x;
        if (e < E) {
            int ps = bc[src[e]];
            int pd = bc[dst[e]];
            bmT[(size_t)pd * NCLUST + ps] = 1;
        }
    }
}

__global__ __launch_bounds__(256) void k_pooldeg(
        const unsigned char* __restrict__ bmT, float* __restrict__ dinvp) {
    int d = blockIdx.x;
    int t = threadIdx.x;
    const unsigned int v = reinterpret_cast<const unsigned int*>(bmT + (size_t)d * NCLUST)[t];
    int s = (v & 0xff) + ((v >> 8) & 0xff) + ((v >> 16) & 0xff) + ((v >> 24) & 0xff);
    if (t == (d >> 2)) s -= (v >> ((d & 3) * 8)) & 0xff;
    __shared__ int red[256];
    red[t] = s; __syncthreads();
    for (int o = 128; o > 0; o >>= 1) {
        if (t < o) red[t] += red[t + o];
        __syncthreads();
    }
    if (t == 0) dinvp[d] = rsqrtf((float)red[0] + 1.0f);
}

template <int F>
__global__ __launch_bounds__(1024) void k_proppool2(
        const float* __restrict__ h, const float* __restrict__ dinvp,
        const unsigned char* __restrict__ bmT, const float* __restrict__ bias,
        float* __restrict__ out) {
    constexpr int SG = 1024 / F;
    const int d = blockIdx.x;
    const int t = threadIdx.x;
    const int f = t & (F - 1);
    const int sg = t / F;
    const unsigned char* bmrow = bmT + (size_t)d * NCLUST;
    float acc = 0.f;
#pragma unroll 4
    for (int s = sg; s < NCLUST; s += SG) {
        float m = (s != d) ? (float)bmrow[s] : 0.f;
        acc += m * dinvp[s] * h[(size_t)s * F + f];
    }
    __shared__ float red[1024];
    red[t] = acc; __syncthreads();
#pragma unroll
    for (int o = SG / 2; o > 0; o >>= 1) {
        if (sg < o) red[t] += red[t + o * F];
        __syncthreads();
    }
    if (sg == 0) {
        float di = dinvp[d];
        float r = di * red[f] + di * di * h[(size_t)d * F + f] + bias[f];
        out[(size_t)d * F + f] = elu1(r);
    }
}

// ---------------------------------------------------------------------------
extern "C" void kernel_launch(void* const* d_in, const int* in_sizes, int n_in,
                              void* d_out, int out_size, void* d_ws, size_t ws_size,
                              hipStream_t stream) {
    const float* x       = (const float*)d_in[0];
    const int*   adj     = (const int*)d_in[1];
    const int*   inb     = (const int*)d_in[3];
    const int*   cluster = (const int*)d_in[4];
    const float* WG1  = (const float*)d_in[5];   const float* bG1  = (const float*)d_in[6];
    const float* WfG1 = (const float*)d_in[7];   const float* bfG1 = (const float*)d_in[8];
    const float* WG2  = (const float*)d_in[9];   const float* bG2  = (const float*)d_in[10];
    const float* WfG2 = (const float*)d_in[11];  const float* bfG2 = (const float*)d_in[12];
    const float* WL1  = (const float*)d_in[13];  const float* bL1  = (const float*)d_in[14];
    const float* WfL1 = (const float*)d_in[15];  const float* bfL1 = (const float*)d_in[16];
    const float* WL2  = (const float*)d_in[17];  const float* bL2  = (const float*)d_in[18];
    const float* WfL2 = (const float*)d_in[19];  const float* bfL2 = (const float*)d_in[20];
    const float* WO1  = (const float*)d_in[21];  const float* bO1  = (const float*)d_in[22];
    const float* WfO1 = (const float*)d_in[23];  const float* bfO1 = (const float*)d_in[24];
    const float* WO2  = (const float*)d_in[25];  const float* bO2  = (const float*)d_in[26];
    const float* WfO2 = (const float*)d_in[27];  const float* bfO2 = (const float*)d_in[28];
    const float* WO3  = (const float*)d_in[29];  const float* bO3  = (const float*)d_in[30];
    const float* WfO3 = (const float*)d_in[31];  const float* bfO3 = (const float*)d_in[32];
    float* out = (float*)d_out;

    const int n = in_sizes[0] / 3;       // 100000
    const int E = in_sizes[1] / 2;       // 1600000
    const int* src = adj;
    const int* dst = adj + E;

    // ---- workspace carve ----
    char* ws = (char*)d_ws;
    size_t off = 0;
    auto alloc = [&](size_t bytes) -> void* {
        void* p = ws + off;
        off = (off + bytes + 255) & ~(size_t)255;
        return p;
    };
    int*   deg     = (int*)alloc((size_t)n * 4);     // zero span 1 start
    int*   fill    = (int*)alloc((size_t)n * 4);
    int*   cdeg    = (int*)alloc(NCLUST * 4);
    int*   cfill   = (int*)alloc(NCLUST * 4);
    int*   rowptr  = (int*)alloc((size_t)n * 4);     // zero span 1 end (exclusive)
    int*   crowptr = (int*)alloc(NCLUST * 4);
    int*   cnodes  = (int*)alloc((size_t)n * 4);
    int*   bcarr   = (int*)alloc((size_t)n * 4);
    float* dinv    = (float*)alloc((size_t)n * 4);
    int*   bsum    = (int*)alloc(512);
    int2*  csr_ev  = (int2*)alloc((size_t)E * 8);
    float* X       = (float*)alloc((size_t)n * 256 * 4);
    unsigned short* Xh = (unsigned short*)alloc((size_t)n * 256 * 2);
    float* B       = (float*)alloc((size_t)n * 128 * 4);
    unsigned short* Bh = (unsigned short*)alloc((size_t)n * 128 * 2);
    float* insum   = (float*)alloc(256 * 4);         // zero span 2 start
    float* insumsq = (float*)alloc(256 * 4);
    float* px      = (float*)alloc((size_t)NCLUST * 256 * 4);
    unsigned char* bmT = (unsigned char*)alloc((size_t)NCLUST * NCLUST);
    float* corr    = (float*)alloc(128 * 4);
    float* mu      = (float*)alloc(256 * 4);         // zero span 2 end (exclusive)
    float* rstd    = (float*)alloc(256 * 4);
    float* dinvp   = (float*)alloc(NCLUST * 4);
    float* lA      = (float*)alloc((size_t)NCLUST * 128 * 4);
    float* lB      = (float*)alloc((size_t)NCLUST * 128 * 4);
    unsigned* pfG1h = (unsigned*)alloc(2048 * 4);   unsigned* pfG1l = (unsigned*)alloc(2048 * 4);
    unsigned* pG2h  = (unsigned*)alloc(8192 * 4);   unsigned* pG2l  = (unsigned*)alloc(8192 * 4);
    unsigned* pfG2h = (unsigned*)alloc(32768 * 4);  unsigned* pfG2l = (unsigned*)alloc(32768 * 4);
    unsigned* pO1h  = (unsigned*)alloc(16384 * 4);  unsigned* pO1l  = (unsigned*)alloc(16384 * 4);
    unsigned* pfO1h = (unsigned*)alloc(8192 * 4);   unsigned* pfO1l = (unsigned*)alloc(8192 * 4);
    unsigned* pO2h  = (unsigned*)alloc(2048 * 4);   unsigned* pO2l  = (unsigned*)alloc(2048 * 4);
    unsigned* pfO2h = (unsigned*)alloc(512 * 4);    unsigned* pfO2l = (unsigned*)alloc(512 * 4);
    (void)ws_size; (void)n_in; (void)out_size;

    unsigned short* Bh1 = Bh;                        // h1/h2 (n x 64 bf16)
    unsigned short* Bh2 = Bh + (size_t)n * 64;       // p64 (n x 64 bf16)

    auto cdiv = [](int a, int b) { return (a + b - 1) / b; };
    const int EB = cdiv(E, 256);
    const int PB = cdiv(n, 4);

    // ---- init: zero scratch + pack all static weights (ONE launch) ----
    int nz1 = (int)(((char*)rowptr - (char*)deg) / 16);
    int nz2 = (int)(((char*)mu - (char*)insum) / 16);
    InitArgs ia;
    ia.d[0] = {WfG1, pfG1h, pfG1l, 64, 64, 0};
    ia.d[1] = {WG2,  pG2h,  pG2l,  64, 256, 512};
    ia.d[2] = {WfG2, pfG2h, pfG2l, 256, 256, 2560};
    ia.d[3] = {WfO1, pfO1h, pfO1l, 128, 128, 10752};
    ia.d[4] = {WO2,  pO2h,  pO2l,  128, 32, 12800};
    ia.d[5] = {WfO2, pfO2h, pfO2l, 32, 32, 13312};
    ia.tot = 13440;
    ia.z1 = (int4*)deg; ia.nz1 = nz1;
    ia.z2 = (int4*)insum; ia.nz2 = nz2;
    int initN = (nz1 + nz2 > ia.tot) ? (nz1 + nz2) : ia.tot;
    k_init<<<cdiv(initN, 256), 256, 0, stream>>>(ia);

    // ---- CSR build ----
    k_hist<<<EB, 256, 0, stream>>>(dst, deg, E);
    int nb = cdiv(n, 1024);
    k_scan_block<<<nb, 256, 0, stream>>>(deg, rowptr, bsum, n);
    k_nodeinit<<<cdiv(n, 256), 256, 0, stream>>>(rowptr, bsum, deg, cluster, inb,
                                                 dinv, bcarr, cdeg, n, nb);
    k_scan_block<<<1, 256, 0, stream>>>(cdeg, crowptr, bsum, NCLUST);
    k_fillc<<<EB, 256, 0, stream>>>(src, dst, dinv, rowptr, fill, csr_ev, E,
                                    bcarr, crowptr, cfill, cnodes, n);

    // ---- global GCN stack (all bf16 activations) ----
    // p3 + fused fc<64>: h1 -> bf16 Bh1
    k_prop3f1<<<cdiv(n, 256), 256, 0, stream>>>(x, dinv, rowptr, deg, csr_ev,
                                                WG1, bG1, Bh1, n);
    // h2 = elu(h1 @ WfG1 + bfG1)  (Bh1 in-place, register-W)  [8-wave]
    k_gmfma<64, 8, 0><<<cdiv(n, 256), 512, 0, stream>>>(Bh1, pfG1h, pfG1l, bfG1,
                                                        nullptr, nullptr, nullptr,
                                                        nullptr, Bh1, nullptr, nullptr,
                                                        n, 64, 1);
    // p64 = S h2  (bf16 gather -> bf16 Bh2)
    k_prop4sb<64, 1><<<PB, 256, 0, stream>>>(Bh1, dinv, rowptr, deg, csr_ev,
                                             nullptr, nullptr, Bh2, n, 0);
    // h3 = elu(p64 @ WG2 + bG2) -> bf16 (Xh)  [FULLW: 1 chunk, 2 barriers]
    k_gmfma<256, 8, 64><<<cdiv(n, 64), 512, 0, stream>>>(Bh2, pG2h, pG2l, bG2,
                                                         nullptr, nullptr, nullptr,
                                                         nullptr, Xh, nullptr, nullptr,
                                                         n, 64, 1);
    // h4 = elu(h3 @ WfG2 + bfG2)  (Xh in-place)  [LDS-W dbuf, 8-wave]
    k_gmfma<256, 8, 0><<<cdiv(n, 64), 512, 0, stream>>>(Xh, pfG2h, pfG2l, bfG2,
                                                        nullptr, nullptr, nullptr,
                                                        nullptr, Xh, nullptr, nullptr,
                                                        n, 256, 1);

    // ---- instance norm stats + merged finalize/pack/corr ----
    k_instats<<<cdiv(n, 128), 256, 0, stream>>>(Xh, insum, insumsq, n);
    k_normprep<<<17, 256, 0, stream>>>(WO1, insum, insumsq, pO1h, pO1l, corr, mu, rstd, n);

    // ---- cluster pooling (poolavg + pooledges merged) ----
    k_poolmerge<<<NCLUST + EB, 256, 0, stream>>>(Xh, crowptr, cdeg, cnodes, mu, rstd, px,
                                                 src, dst, bcarr, bmT, E);
    k_pooldeg<<<NCLUST, 256, 0, stream>>>(bmT, dinvp);

    // ---- local (pooled) GCN stack ----
    k_fc<128, 2><<<cdiv(NCLUST, 16), 256, 0, stream>>>(px, WL1, nullptr, nullptr, nullptr,
                                                       lA, NCLUST, 256, 0);
    k_proppool2<128><<<NCLUST, 1024, 0, stream>>>(lA, dinvp, bmT, bL1, lB);
    k_fc<128, 2><<<cdiv(NCLUST, 16), 256, 0, stream>>>(lB, WfL1, bfL1, nullptr, nullptr,
                                                       lA, NCLUST, 128, 1);
    k_fc<64, 2><<<cdiv(NCLUST, 32), 256, 0, stream>>>(lA, WL2, nullptr, nullptr, nullptr,
                                                      lB, NCLUST, 128, 0);
    k_proppool2<64><<<NCLUST, 1024, 0, stream>>>(lB, dinvp, bmT, bL2, lA);
    // fused: lx = elu(lA @ WfL2 + bfL2) -> lB; compO = lx @ WO1[256:] -> lA
    k_fcl2<<<NCLUST / 32, 256, 0, stream>>>(lA, WfL2, bfL2, WO1 + (size_t)256 * 128,
                                            lB, lA);

    // ---- output GCN stack ----
    // t1 = Xh @ (rstd*WO1) - corr + compO[bc] -> bf16 (Bh)  [FULLW: 2 chunks]
    k_gmfma<128, 8, 128><<<cdiv(n, 128), 512, 0, stream>>>(Xh, pO1h, pO1l, nullptr,
                                                           corr, lA, bcarr, nullptr, Bh,
                                                           nullptr, nullptr, n, 256, 0);
    k_prop4sb<128, 1><<<PB, 256, 0, stream>>>(Bh, dinv, rowptr, deg, csr_ev,
                                              bO1, nullptr, Xh, n, 1);
    // o2 = elu(o1 @ WfO1 + bfO1)  (Xh in-place)  [FULLW: 1 chunk]
    k_gmfma<128, 8, 128><<<cdiv(n, 128), 512, 0, stream>>>(Xh, pfO1h, pfO1l, bfO1,
                                                           nullptr, nullptr, nullptr,
                                                           nullptr, Xh, nullptr, nullptr,
                                                           n, 128, 1);
    // t2 = o2 @ WO2  -> bf16 (Bh, N x 32)  [register-W, 8-wave]
    k_gmfma<32, 8, 0><<<cdiv(n, 256), 512, 0, stream>>>(Xh, pO2h, pO2l, nullptr,
                                                        nullptr, nullptr, nullptr,
                                                        nullptr, Bh, nullptr, nullptr,
                                                        n, 128, 0);
    k_prop4sb<32, 1><<<PB, 256, 0, stream>>>(Bh, dinv, rowptr, deg, csr_ev,
                                             bO2, nullptr, Xh, n, 1);
    // o4 = elu(o3 @ WfO2 + bfO2); t3 = o4 @ WO3 fused -> B (N x 3 f32)
    k_gmfma<32, 8, 0><<<cdiv(n, 256), 512, 0, stream>>>(Xh, pfO2h, pfO2l, bfO2,
                                                        nullptr, nullptr, nullptr,
                                                        nullptr, nullptr, WO3, B,
                                                        n, 32, 1);
    // o5 = elu(S t3 + bO3); out = elu(o5 @ WfO3 + bfO3)  (fused)
    k_prop3out<<<cdiv(n, 256), 256, 0, stream>>>(B, dinv, rowptr, deg, csr_ev,
                                                 bO3, WfO3, bfO3, out, n);
}

// Round 29
// 1114.686 us; speedup vs baseline: 1.0177x; 1.0088x over previous
//
#include <hip/hip_runtime.h>

// ---------------------------------------------------------------------------
// GCN3D. R9: split-bf16 MFMA GEMMs. R13: prop4s+norm-fold. R14/15/17/23: bf16
// activations everywhere. R17/R20/R21/R22: launch merging, int2 edges.
// R24: LDS-W staging. R26: FULLW one-barrier k-loop. R27/R28: chunked FULLW
//   for t1; instats fusion closed (2 failure modes), standalone (1124us).
// R29: h4's floor is LDS-capped residency (64KB dbuf -> 2 blocks/CU, 1.4
//   effective; barriers have nothing to hide under). Switch h4 to FULLW=32
//   single-kstep chunks: 32KB LDS -> 4 blocks/CU (100% wave occupancy);
//   16 barriers/block but 3 other resident blocks to overlap each drain.
//   Minimal A/B: only h4's template args change.
// ---------------------------------------------------------------------------

#define NCLUST 1024

typedef short bf16x8 __attribute__((ext_vector_type(8)));
typedef float f32x4 __attribute__((ext_vector_type(4)));

__device__ __forceinline__ float elu1(float x) { return x > 0.f ? x : expm1f(x); }

__device__ __forceinline__ unsigned f2bf(float f) {
    union { float f; unsigned u; } c; c.f = f;
    unsigned u = c.u;
    return (u + 0x7fffu + ((u >> 16) & 1u)) >> 16;
}
__device__ __forceinline__ float bf2f(unsigned h) {
    union { unsigned u; float f; } c; c.u = h << 16; return c.f;
}

union U8 { unsigned u[4]; bf16x8 v; };

// ---- W pre-pack body ----
__device__ __forceinline__ void wpack_body(const float* W, unsigned* Phi, unsigned* Plo,
                                           int K, int BN, int t) {
    int NT = BN / 16;
    int lane = t & 63;
    int rest = t >> 6;
    int ct = rest % NT;
    int s = rest / NT;
    int col = ct * 16 + (lane & 15);
    int g = lane >> 4;
    int k0 = s * 32;
    float e[8];
#pragma unroll
    for (int j = 0; j < 4; j++) {
        e[j]     = W[(size_t)(k0 + 4 * g + j) * BN + col];
        e[4 + j] = W[(size_t)(k0 + 16 + 4 * g + j) * BN + col];
    }
#pragma unroll
    for (int j = 0; j < 4; j++) {
        unsigned h0 = f2bf(e[2 * j]), h1 = f2bf(e[2 * j + 1]);
        Phi[(size_t)t * 4 + j] = h0 | (h1 << 16);
        unsigned l0 = f2bf(e[2 * j] - bf2f(h0));
        unsigned l1 = f2bf(e[2 * j + 1] - bf2f(h1));
        Plo[(size_t)t * 4 + j] = l0 | (l1 << 16);
    }
}

struct PackDesc { const float* W; unsigned* Ph; unsigned* Pl; int K, BN, tbase; };
struct InitArgs {
    PackDesc d[6]; int tot;
    int4* z1; int nz1; int4* z2; int nz2;
};

__global__ void k_init(InitArgs a) {
    int t = blockIdx.x * 256 + threadIdx.x;
    if (t < a.nz1) a.z1[t] = make_int4(0, 0, 0, 0);
    else if (t - a.nz1 < a.nz2) a.z2[t - a.nz1] = make_int4(0, 0, 0, 0);
    if (t < a.tot) {
        int i = 0;
#pragma unroll
        for (int j = 1; j < 6; j++) if (t >= a.d[j].tbase) i = j;
        wpack_body(a.d[i].W, a.d[i].Ph, a.d[i].Pl, a.d[i].K, a.d[i].BN,
                   t - a.d[i].tbase);
    }
}

// ---------------- CSR build ----------------
__global__ void k_hist(const int* __restrict__ key, int* __restrict__ deg, int E) {
    int e = blockIdx.x * 256 + threadIdx.x;
    if (e < E) atomicAdd(&deg[key[e]], 1);
}

__global__ void k_scan_block(const int* __restrict__ deg, int* __restrict__ rowptr,
                             int* __restrict__ bsum, int n) {
    __shared__ int lds[256];
    int tid = threadIdx.x;
    int base = blockIdx.x * 1024 + tid * 4;
    int v0 = base + 0 < n ? deg[base + 0] : 0;
    int v1 = base + 1 < n ? deg[base + 1] : 0;
    int v2 = base + 2 < n ? deg[base + 2] : 0;
    int v3 = base + 3 < n ? deg[base + 3] : 0;
    int tsum = v0 + v1 + v2 + v3;
    lds[tid] = tsum; __syncthreads();
    for (int off = 1; off < 256; off <<= 1) {
        int t = (tid >= off) ? lds[tid - off] : 0;
        __syncthreads();
        lds[tid] += t;
        __syncthreads();
    }
    int run = lds[tid] - tsum;
    if (base + 0 < n) rowptr[base + 0] = run; run += v0;
    if (base + 1 < n) rowptr[base + 1] = run; run += v1;
    if (base + 2 < n) rowptr[base + 2] = run; run += v2;
    if (base + 3 < n) rowptr[base + 3] = run;
    if (tid == 255) bsum[blockIdx.x] = lds[255];
}

// merged: bsum scan + rowptr finalize + dinv + bc + cluster hist
__global__ void k_nodeinit(int* __restrict__ rowptr, const int* __restrict__ bsum,
                           const int* __restrict__ deg, const int* __restrict__ cluster,
                           const int* __restrict__ inb, float* __restrict__ dinv,
                           int* __restrict__ bc, int* __restrict__ cdeg, int n, int nb) {
    __shared__ int pfx[128];
    int tid = threadIdx.x;
    if (tid < 128) pfx[tid] = (tid < nb) ? bsum[tid] : 0;
    __syncthreads();
    for (int off = 1; off < 128; off <<= 1) {
        int v = 0;
        if (tid < 128 && tid >= off) v = pfx[tid - off];
        __syncthreads();
        if (tid < 128) pfx[tid] += v;
        __syncthreads();
    }
    int i = blockIdx.x * 256 + tid;
    if (i >= n) return;
    int j = i >> 10;
    int base = (j == 0) ? 0 : pfx[j - 1];
    rowptr[i] += base;
    dinv[i] = rsqrtf((float)deg[i] + 1.0f);
    int c = cluster[i] + inb[i] * NCLUST;
    bc[i] = c;
    atomicAdd(&cdeg[c], 1);
}

// merged: edge CSR fill (packed int2) + cluster member fill
__global__ void k_fillc(const int* __restrict__ src, const int* __restrict__ dst,
                        const float* __restrict__ dinv, const int* __restrict__ rowptr,
                        int* __restrict__ fill, int2* __restrict__ csr_ev, int E,
                        const int* __restrict__ bc, const int* __restrict__ crowptr,
                        int* __restrict__ cfill, int* __restrict__ cnodes, int n) {
    int e = blockIdx.x * 256 + threadIdx.x;
    if (e < E) {
        int d = dst[e];
        int pos = rowptr[d] + atomicAdd(&fill[d], 1);
        int s = src[e];
        csr_ev[pos] = make_int2(s, __float_as_int(dinv[s]));
    }
    if (e < n) {
        int c = bc[e];
        int pos = crowptr[c] + atomicAdd(&cfill[c], 1);
        cnodes[pos] = e;
    }
}

// ------ GCN propagation, bf16 input; OB=0 f32 out, OB=1 bf16 out ------
template <int F, int OB>
__global__ __launch_bounds__(256) void k_prop4sb(
        const unsigned short* __restrict__ hbf, const float* __restrict__ dinv,
        const int* __restrict__ rowptr, const int* __restrict__ deg,
        const int2* __restrict__ csr_ev,
        const float* __restrict__ bias, float* __restrict__ outf,
        unsigned short* __restrict__ outb, int n, int flags) {
    constexpr int FS = F / 4;
    constexpr int ES = 64 / FS;
    const int node = (blockIdx.x * 256 + threadIdx.x) >> 6;
    if (node >= n) return;
    const int l = threadIdx.x & 63;
    const int fs = l & (FS - 1);
    const int ep = l / FS;
    const int fi = fs * 4;
    const int start = rowptr[node];
    const int cnt = deg[node];
    float ax = 0.f, ay = 0.f, az = 0.f, aw = 0.f;
    for (int j = ep; j < cnt; j += ES) {
        const int2 ev = csr_ev[start + j];
        int s = ev.x;
        float w = __int_as_float(ev.y);
        const ushort4 v = *reinterpret_cast<const ushort4*>(&hbf[(size_t)s * F + fi]);
        ax += w * bf2f(v.x); ay += w * bf2f(v.y);
        az += w * bf2f(v.z); aw += w * bf2f(v.w);
    }
#pragma unroll
    for (int off = FS; off < 64; off <<= 1) {
        ax += __shfl_xor(ax, off);
        ay += __shfl_xor(ay, off);
        az += __shfl_xor(az, off);
        aw += __shfl_xor(aw, off);
    }
    if (ep == 0) {
        float di = dinv[node];
        const ushort4 sv = *reinterpret_cast<const ushort4*>(&hbf[(size_t)node * F + fi]);
        float4 o;
        o.x = di * ax + di * di * bf2f(sv.x);
        o.y = di * ay + di * di * bf2f(sv.y);
        o.z = di * az + di * di * bf2f(sv.z);
        o.w = di * aw + di * di * bf2f(sv.w);
        if (flags) {
            const float4 b = *reinterpret_cast<const float4*>(&bias[fi]);
            o.x = elu1(o.x + b.x); o.y = elu1(o.y + b.y);
            o.z = elu1(o.z + b.z); o.w = elu1(o.w + b.w);
        }
        if constexpr (OB) {
            ushort4 ob;
            ob.x = (unsigned short)f2bf(o.x); ob.y = (unsigned short)f2bf(o.y);
            ob.z = (unsigned short)f2bf(o.z); ob.w = (unsigned short)f2bf(o.w);
            *reinterpret_cast<ushort4*>(&outb[(size_t)node * F + fi]) = ob;
        } else {
            *reinterpret_cast<float4*>(&outf[(size_t)node * F + fi]) = o;
        }
    }
}

// prop3 on x + fused fc<64> -> bf16 out (N x 64)
__global__ void k_prop3f1(const float* __restrict__ h, const float* __restrict__ dinv,
                          const int* __restrict__ rowptr, const int* __restrict__ deg,
                          const int2* __restrict__ csr_ev,
                          const float* __restrict__ WG1, const float* __restrict__ bG1,
                          unsigned short* __restrict__ outb, int n) {
    int node = blockIdx.x * 256 + threadIdx.x;
    if (node >= n) return;
    int start = rowptr[node], cnt = deg[node];
    float a0 = 0.f, a1 = 0.f, a2 = 0.f;
    for (int j = 0; j < cnt; j++) {
        const int2 ev = csr_ev[start + j];
        int s = ev.x;
        float w = __int_as_float(ev.y);
        a0 += w * h[(size_t)s * 3 + 0];
        a1 += w * h[(size_t)s * 3 + 1];
        a2 += w * h[(size_t)s * 3 + 2];
    }
    float di = dinv[node];
    float p0 = di * a0 + di * di * h[(size_t)node * 3 + 0];
    float p1 = di * a1 + di * di * h[(size_t)node * 3 + 1];
    float p2 = di * a2 + di * di * h[(size_t)node * 3 + 2];
    unsigned short* op = outb + (size_t)node * 64;
#pragma unroll 4
    for (int c = 0; c < 64; c += 4) {
        ushort4 ob;
        ob.x = (unsigned short)f2bf(elu1(p0 * WG1[c + 0] + p1 * WG1[64 + c + 0] + p2 * WG1[128 + c + 0] + bG1[c + 0]));
        ob.y = (unsigned short)f2bf(elu1(p0 * WG1[c + 1] + p1 * WG1[64 + c + 1] + p2 * WG1[128 + c + 1] + bG1[c + 1]));
        ob.z = (unsigned short)f2bf(elu1(p0 * WG1[c + 2] + p1 * WG1[64 + c + 2] + p2 * WG1[128 + c + 2] + bG1[c + 2]));
        ob.w = (unsigned short)f2bf(elu1(p0 * WG1[c + 3] + p1 * WG1[64 + c + 3] + p2 * WG1[128 + c + 3] + bG1[c + 3]));
        *reinterpret_cast<ushort4*>(op + c) = ob;
    }
}

// prop3 on t3 (+bO3, elu) + fused final fc3
__global__ void k_prop3out(const float* __restrict__ h, const float* __restrict__ dinv,
                           const int* __restrict__ rowptr, const int* __restrict__ deg,
                           const int2* __restrict__ csr_ev,
                           const float* __restrict__ bO3, const float* __restrict__ WfO3,
                           const float* __restrict__ bfO3, float* __restrict__ out, int n) {
    int node = blockIdx.x * 256 + threadIdx.x;
    if (node >= n) return;
    int start = rowptr[node], cnt = deg[node];
    float a0 = 0.f, a1 = 0.f, a2 = 0.f;
    for (int j = 0; j < cnt; j++) {
        const int2 ev = csr_ev[start + j];
        int s = ev.x;
        float w = __int_as_float(ev.y);
        a0 += w * h[(size_t)s * 3 + 0];
        a1 += w * h[(size_t)s * 3 + 1];
        a2 += w * h[(size_t)s * 3 + 2];
    }
    float di = dinv[node];
    float o0 = elu1(di * a0 + di * di * h[(size_t)node * 3 + 0] + bO3[0]);
    float o1 = elu1(di * a1 + di * di * h[(size_t)node * 3 + 1] + bO3[1]);
    float o2 = elu1(di * a2 + di * di * h[(size_t)node * 3 + 2] + bO3[2]);
#pragma unroll
    for (int c = 0; c < 3; c++) {
        out[(size_t)node * 3 + c] =
            elu1(o0 * WfO3[c] + o1 * WfO3[3 + c] + o2 * WfO3[6 + c] + bfO3[c]);
    }
}

// ---- merged: infinal + rstd-scaled WO1 pack + corr (17 blocks x 256) ----
__global__ void k_normprep(const float* __restrict__ W, const float* __restrict__ insum,
                           const float* __restrict__ insumsq, unsigned* __restrict__ Phi,
                           unsigned* __restrict__ Plo, float* __restrict__ corr,
                           float* __restrict__ mu, float* __restrict__ rstd, int n) {
    const float fn = (float)n;
    const int bid = blockIdx.x, tid = threadIdx.x;
    if (bid == 16) {
        float m = insum[tid] / fn;
        float var = insumsq[tid] / fn - m * m;
        mu[tid] = m;
        rstd[tid] = rsqrtf(var + 1e-5f);
        return;
    }
    {
        int t = bid * 256 + tid;
        int lane = t & 63, rest = t >> 6;
        int ct = rest % 8, s = rest / 8;
        int col = ct * 16 + (lane & 15);
        int g = lane >> 4;
        int k0 = s * 32;
        float e[8];
#pragma unroll
        for (int j = 0; j < 4; j++) {
            int ka = k0 + 4 * g + j;
            int kb = k0 + 16 + 4 * g + j;
            float ma = insum[ka] / fn;
            float sa = rsqrtf(insumsq[ka] / fn - ma * ma + 1e-5f);
            float mb = insum[kb] / fn;
            float sb = rsqrtf(insumsq[kb] / fn - mb * mb + 1e-5f);
            e[j]     = W[(size_t)ka * 128 + col] * sa;
            e[4 + j] = W[(size_t)kb * 128 + col] * sb;
        }
#pragma unroll
        for (int j = 0; j < 4; j++) {
            unsigned h0 = f2bf(e[2 * j]), h1 = f2bf(e[2 * j + 1]);
            Phi[(size_t)t * 4 + j] = h0 | (h1 << 16);
            unsigned l0 = f2bf(e[2 * j] - bf2f(h0));
            unsigned l1 = f2bf(e[2 * j + 1] - bf2f(h1));
            Plo[(size_t)t * 4 + j] = l0 | (l1 << 16);
        }
    }
    if (tid < 128) {
        int k0 = bid * 16;
        float s = 0.f;
        for (int k = k0; k < k0 + 16; k++) {
            float m = insum[k] / fn;
            float r = rsqrtf(insumsq[k] / fn - m * m + 1e-5f);
            s += m * r * W[(size_t)k * 128 + tid];
        }
        atomicAdd(&corr[tid], s);
    }
}

// ---- split-bf16 MFMA GEMM (bf16-A only). Three W paths:
//   FULLW>0 (ksteps-worth of W per chunk, chunk <= 64KB): loop chunks
//     {stage chunk, barrier, barrier-free compute, barrier}. Small chunks
//     (e.g. FULLW=32 -> 32KB) raise blocks/CU for cross-block overlap.
//   else BN>=128: double-buffered global_load_lds W, barrier per kstep.
//   else: register W.
// Optional fused second GEMM (W3: BN x 3) via 16-lane shfl -> C3 (BN<=32).
template <int BN, int WAVES, int FULLW>
__global__ __launch_bounds__(WAVES * 64) void k_gmfma(
        const unsigned short* __restrict__ Abf,
        const unsigned* __restrict__ Phi, const unsigned* __restrict__ Plo,
        const float* __restrict__ bias, const float* __restrict__ sub,
        const float* __restrict__ add, const int* __restrict__ addidx,
        float* __restrict__ C, unsigned short* __restrict__ Cbf,
        const float* __restrict__ W3, float* __restrict__ C3,
        int N, int K, int flags) {
    constexpr int NT = BN / 16;
    constexpr int WCOL = (BN == 256) ? 4 : (BN == 128 ? 2 : 1);
    constexpr int WROW = WAVES / WCOL;
    constexpr int NTW = NT / WCOL;
    constexpr int BR = 32 * WROW;
    constexpr bool LDSW = (BN >= 128);
    constexpr int LDSU = (FULLW > 0) ? 2 * NT * (FULLW / 32) * 256
                                     : (LDSW ? 2 * 2 * NT * 256 : 1);
    __shared__ unsigned lds_w[LDSU];
    const int t = threadIdx.x;
    const int w = t >> 6, l = t & 63;
    const int wr = w / WCOL, wc = w % WCOL;
    const int l15 = l & 15, g = l >> 4;
    const int row0 = blockIdx.x * BR + wr * 32;
    const int ctbase = wc * NTW;
    int ar0 = row0 + l15;      ar0 = ar0 < N ? ar0 : N - 1;
    int ar1 = row0 + 16 + l15; ar1 = ar1 < N ? ar1 : N - 1;
    const unsigned short* ab0 = Abf + (size_t)ar0 * K;
    const unsigned short* ab1 = Abf + (size_t)ar1 * K;

    f32x4 acc[2][NTW];
#pragma unroll
    for (int f = 0; f < 2; f++)
#pragma unroll
        for (int ct = 0; ct < NTW; ct++) acc[f][ct] = (f32x4){0.f, 0.f, 0.f, 0.f};

    auto loadA = [&](int s, U8* ahi) {
        const int k0 = s * 32;
#pragma unroll
        for (int f = 0; f < 2; f++) {
            const unsigned short* ab = f ? ab1 : ab0;
            const uint2 hA = *reinterpret_cast<const uint2*>(ab + k0 + 4 * g);
            const uint2 hB = *reinterpret_cast<const uint2*>(ab + k0 + 16 + 4 * g);
            ahi[f].u[0] = hA.x; ahi[f].u[1] = hA.y;
            ahi[f].u[2] = hB.x; ahi[f].u[3] = hB.y;
        }
    };
    auto domfma = [&](U8* wh, U8* wl, U8* ahi) {
#pragma unroll
        for (int ct = 0; ct < NTW; ct++) {
            acc[0][ct] = __builtin_amdgcn_mfma_f32_16x16x32_bf16(ahi[0].v, wh[ct].v, acc[0][ct], 0, 0, 0);
            acc[0][ct] = __builtin_amdgcn_mfma_f32_16x16x32_bf16(ahi[0].v, wl[ct].v, acc[0][ct], 0, 0, 0);
            acc[1][ct] = __builtin_amdgcn_mfma_f32_16x16x32_bf16(ahi[1].v, wh[ct].v, acc[1][ct], 0, 0, 0);
            acc[1][ct] = __builtin_amdgcn_mfma_f32_16x16x32_bf16(ahi[1].v, wl[ct].v, acc[1][ct], 0, 0, 0);
        }
    };

    const int nk = K / 32;

    if constexpr (FULLW > 0) {
        constexpr int NKT = FULLW / 32;     // ksteps per chunk (chunk <= 64KB)
        const int nchunk = K / FULLW;
        U8 wh[NTW], wl[NTW], ahiA[2];
        for (int c = 0; c < nchunk; c++) {
            // stage chunk c: NKT ksteps x 2*NT 1KB tiles (i = s*2NT + j)
            for (int i = w; i < 2 * NT * NKT; i += WAVES) {
                int s = i / (2 * NT);
                int j = i - s * 2 * NT;
                int gs = c * NKT + s;
                const unsigned* gsrc = (j < NT)
                    ? Phi + (size_t)(gs * NT + j) * 256 + l * 4
                    : Plo + (size_t)(gs * NT + (j - NT)) * 256 + l * 4;
                __builtin_amdgcn_global_load_lds(
                    (const __attribute__((address_space(1))) unsigned*)gsrc,
                    (__attribute__((address_space(3))) unsigned*)(lds_w + (size_t)i * 256),
                    16, 0, 0);
            }
            __syncthreads();                // chunk staged + visible
#pragma unroll
            for (int s = 0; s < NKT; s++) {
                loadA(c * NKT + s, ahiA);
                const unsigned* base = lds_w + (size_t)s * (2 * NT * 256);
#pragma unroll
                for (int ct = 0; ct < NTW; ct++) {
                    wh[ct] = *reinterpret_cast<const U8*>(base + (ctbase + ct) * 256 + l * 4);
                    wl[ct] = *reinterpret_cast<const U8*>(base + (NT + ctbase + ct) * 256 + l * 4);
                }
                domfma(wh, wl, ahiA);
            }
            __syncthreads();   // reads done before restage / stores (in-place)
        }
    } else if constexpr (LDSW) {
        auto stage = [&](int s, int b) {
            unsigned* base = lds_w + (size_t)b * (2 * NT * 256);
            for (int i = w; i < 2 * NT; i += WAVES) {
                const unsigned* gsrc = (i < NT)
                    ? Phi + (size_t)(s * NT + i) * 256 + l * 4
                    : Plo + (size_t)(s * NT + (i - NT)) * 256 + l * 4;
                __builtin_amdgcn_global_load_lds(
                    (const __attribute__((address_space(1))) unsigned*)gsrc,
                    (__attribute__((address_space(3))) unsigned*)(base + i * 256),
                    16, 0, 0);
            }
        };
        auto loadWlds = [&](int b, U8* wh, U8* wl) {
            const unsigned* base = lds_w + (size_t)b * (2 * NT * 256);
#pragma unroll
            for (int ct = 0; ct < NTW; ct++) {
                wh[ct] = *reinterpret_cast<const U8*>(base + (ctbase + ct) * 256 + l * 4);
                wl[ct] = *reinterpret_cast<const U8*>(base + (NT + ctbase + ct) * 256 + l * 4);
            }
        };

        U8 wh[NTW], wl[NTW], ahiA[2], ahiB[2];
        stage(0, 0);
        loadA(0, ahiA);
        __syncthreads();                    // W(0) staged + visible
        int s = 0;
        while (true) {
            const bool hasB = (s + 1 < nk);
            if (hasB) { stage(s + 1, (s + 1) & 1); loadA(s + 1, ahiB); }
            loadWlds(s & 1, wh, wl);
            domfma(wh, wl, ahiA);
            __syncthreads();                // drain stage(s+1); protect buf reuse
            if (!hasB) break;
            s++;
            const bool hasA2 = (s + 1 < nk);
            if (hasA2) { stage(s + 1, (s + 1) & 1); loadA(s + 1, ahiA); }
            loadWlds(s & 1, wh, wl);
            domfma(wh, wl, ahiB);
            __syncthreads();
            if (!hasA2) break;
            s++;
        }
        // loop's trailing barrier = all A reads done before stores (in-place safe)
    } else {
        auto loadW = [&](int s, U8* wh, U8* wl) {
            const unsigned* pb = Phi + ((size_t)(s * NT + ctbase) * 64 + l) * 4;
            const unsigned* pl = Plo + ((size_t)(s * NT + ctbase) * 64 + l) * 4;
#pragma unroll
            for (int ct = 0; ct < NTW; ct++) {
                wh[ct] = *reinterpret_cast<const U8*>(pb + (size_t)ct * 256);
                wl[ct] = *reinterpret_cast<const U8*>(pl + (size_t)ct * 256);
            }
        };
        U8 whA[NTW], wlA[NTW], ahiA[2];
        U8 whB[NTW], wlB[NTW], ahiB[2];
        loadW(0, whA, wlA);
        loadA(0, ahiA);
        int s = 0;
        while (true) {
            const bool hasB = (s + 1 < nk);
            if (hasB) { loadW(s + 1, whB, wlB); loadA(s + 1, ahiB); }
            domfma(whA, wlA, ahiA);
            if (!hasB) break;
            const bool hasA2 = (s + 2 < nk);
            if (hasA2) { loadW(s + 2, whA, wlA); loadA(s + 2, ahiA); }
            domfma(whB, wlB, ahiB);
            if (!hasA2) break;
            s += 2;
        }
        __syncthreads();   // all A reads done before any store (in-place safe)
    }

#pragma unroll
    for (int f = 0; f < 2; f++) {
#pragma unroll
        for (int r = 0; r < 4; r++) {
            int row = row0 + 16 * f + 4 * g + r;
            if (row >= N) continue;   // uniform across l15 group (shfl-safe)
            int gi = (add != nullptr) ? addidx[row] : 0;
            float t0 = 0.f, t1 = 0.f, t2 = 0.f;
#pragma unroll
            for (int ct = 0; ct < NTW; ct++) {
                int col = (ctbase + ct) * 16 + l15;
                float o = acc[f][ct][r];
                if (add != nullptr) o += add[(size_t)gi * BN + col];
                if (sub != nullptr) o -= sub[col];
                if (flags) o = elu1(o + bias[col]);
                if (C != nullptr) C[(size_t)row * BN + col] = o;
                if (Cbf != nullptr) Cbf[(size_t)row * BN + col] = (unsigned short)f2bf(o);
                if (W3 != nullptr) {
                    t0 += o * W3[col * 3 + 0];
                    t1 += o * W3[col * 3 + 1];
                    t2 += o * W3[col * 3 + 2];
                }
            }
            if (W3 != nullptr) {
#pragma unroll
                for (int m = 1; m < 16; m <<= 1) {
                    t0 += __shfl_xor(t0, m);
                    t1 += __shfl_xor(t1, m);
                    t2 += __shfl_xor(t2, m);
                }
                if (l15 == 0) {
                    C3[(size_t)row * 3 + 0] = t0;
                    C3[(size_t)row * 3 + 1] = t1;
                    C3[(size_t)row * 3 + 2] = t2;
                }
            }
        }
    }
}

// ---------------- simple fc (small shapes) ----------------
template <int M, int RPT>
__global__ __launch_bounds__(256) void k_fc(
        const float* __restrict__ A, const float* __restrict__ W,
        const float* __restrict__ bias, const float* __restrict__ add,
        const int* __restrict__ addidx, float* __restrict__ C,
        int N, int K, int flags) {
    constexpr int TX = M / 4;
    constexpr int TY = 256 / TX;
    constexpr int RB = TY * RPT;
    int tx = threadIdx.x % TX;
    int ty = threadIdx.x / TX;
    int row0 = blockIdx.x * RB + ty * RPT;
    float4 acc[RPT];
#pragma unroll
    for (int r = 0; r < RPT; r++) acc[r] = make_float4(0.f, 0.f, 0.f, 0.f);
    for (int k = 0; k < K; k++) {
        float4 w = *reinterpret_cast<const float4*>(&W[(size_t)k * M + tx * 4]);
#pragma unroll
        for (int r = 0; r < RPT; r++) {
            int row = row0 + r;
            row = row < N ? row : N - 1;
            float a = A[(size_t)row * K + k];
            acc[r].x += a * w.x; acc[r].y += a * w.y;
            acc[r].z += a * w.z; acc[r].w += a * w.w;
        }
    }
    if (add != nullptr) {
#pragma unroll
        for (int r = 0; r < RPT; r++) {
            int row = row0 + r;
            if (row < N) {
                int g = addidx[row];
                const float4 v = *reinterpret_cast<const float4*>(&add[(size_t)g * M + tx * 4]);
                acc[r].x += v.x; acc[r].y += v.y; acc[r].z += v.z; acc[r].w += v.w;
            }
        }
    }
    __syncthreads();
    float4 b = make_float4(0.f, 0.f, 0.f, 0.f);
    if (flags) b = *reinterpret_cast<const float4*>(&bias[tx * 4]);
#pragma unroll
    for (int r = 0; r < RPT; r++) {
        int row = row0 + r;
        if (row >= N) break;
        float4 o = acc[r];
        o.x += b.x; o.y += b.y; o.z += b.z; o.w += b.w;
        if (flags) { o.x = elu1(o.x); o.y = elu1(o.y); o.z = elu1(o.z); o.w = elu1(o.w); }
        *reinterpret_cast<float4*>(&C[(size_t)row * M + tx * 4]) = o;
    }
}

// fused: lx = elu(lA @ WfL2 + bfL2) -> lB;  compO = lx @ WO1[256:] -> lA
__global__ __launch_bounds__(256) void k_fcl2(
        const float* __restrict__ A, const float* __restrict__ W1,
        const float* __restrict__ b1, const float* __restrict__ W2,
        float* __restrict__ lxout, float* __restrict__ compO) {
    __shared__ float lx[32][64];
    const int tid = threadIdx.x;
    const int tx = tid % 16, ty = tid / 16;
    const int row0b = blockIdx.x * 32;
    float4 acc[2];
    acc[0] = make_float4(0.f, 0.f, 0.f, 0.f);
    acc[1] = make_float4(0.f, 0.f, 0.f, 0.f);
    for (int k = 0; k < 64; k++) {
        float4 w = *reinterpret_cast<const float4*>(&W1[(size_t)k * 64 + tx * 4]);
#pragma unroll
        for (int r = 0; r < 2; r++) {
            float a = A[(size_t)(row0b + ty * 2 + r) * 64 + k];
            acc[r].x += a * w.x; acc[r].y += a * w.y;
            acc[r].z += a * w.z; acc[r].w += a * w.w;
        }
    }
    float4 b = *reinterpret_cast<const float4*>(&b1[tx * 4]);
#pragma unroll
    for (int r = 0; r < 2; r++) {
        int lr = ty * 2 + r;
        float4 o;
        o.x = elu1(acc[r].x + b.x); o.y = elu1(acc[r].y + b.y);
        o.z = elu1(acc[r].z + b.z); o.w = elu1(acc[r].w + b.w);
        *reinterpret_cast<float4*>(&lxout[(size_t)(row0b + lr) * 64 + tx * 4]) = o;
        lx[lr][tx * 4 + 0] = o.x; lx[lr][tx * 4 + 1] = o.y;
        lx[lr][tx * 4 + 2] = o.z; lx[lr][tx * 4 + 3] = o.w;
    }
    __syncthreads();
    for (int o = tid; o < 32 * 128; o += 256) {
        int r = o >> 7, c = o & 127;
        float s = 0.f;
        for (int k = 0; k < 64; k++) s += lx[r][k] * W2[(size_t)k * 128 + c];
        compO[(size_t)(row0b + r) * 128 + c] = s;
    }
}

// ---------------- instance norm stats (bf16 input) ----------------
__global__ void k_instats(const unsigned short* __restrict__ h, float* __restrict__ sum,
                          float* __restrict__ sumsq, int n) {
    int c = threadIdx.x;
    int r0 = blockIdx.x * 128;
    int r1 = r0 + 128 < n ? r0 + 128 : n;
    float s = 0.f, q = 0.f;
#pragma unroll 4
    for (int r = r0; r < r1; r++) {
        float v = bf2f(h[(size_t)r * 256 + c]);
        s += v; q += v * v;
    }
    atomicAdd(&sum[c], s);
    atomicAdd(&sumsq[c], q);
}

// ---- merged: cluster poolavg + pooledges ----
__global__ __launch_bounds__(256) void k_poolmerge(
        const unsigned short* __restrict__ xh, const int* __restrict__ crowptr,
        const int* __restrict__ cdeg, const int* __restrict__ cnodes,
        const float* __restrict__ mu, const float* __restrict__ rstd,
        float* __restrict__ px,
        const int* __restrict__ src, const int* __restrict__ dst,
        const int* __restrict__ bc, unsigned char* __restrict__ bmT, int E) {
    int bid = blockIdx.x;
    if (bid < NCLUST) {
        int cl = bid;
        int c  = threadIdx.x;
        int start = crowptr[cl];
        int cnt = cdeg[cl];
        float acc = 0.f;
        int j = 0;
        for (; j + 3 < cnt; j += 4) {       // 4 independent gathers (ILP)
            int n0 = cnodes[start + j + 0];
            int n1 = cnodes[start + j + 1];
            int n2 = cnodes[start + j + 2];
            int n3 = cnodes[start + j + 3];
            float v0 = bf2f(xh[(size_t)n0 * 256 + c]);
            float v1 = bf2f(xh[(size_t)n1 * 256 + c]);
            float v2 = bf2f(xh[(size_t)n2 * 256 + c]);
            float v3 = bf2f(xh[(size_t)n3 * 256 + c]);
            acc += (v0 + v1) + (v2 + v3);
        }
        for (; j < cnt; j++) {
            int node = cnodes[start + j];
            acc += bf2f(xh[(size_t)node * 256 + c]);
        }
        float res = acc / fmaxf((float)cnt, 1.0f);
        res = (cnt > 0) ? (res - mu[c]) * rstd[c] : 0.f;
        px[(size_t)cl * 256 + c] = res;
    } else {
        int e = (bid - NCLUST) * 256 + threadIdx.x;
        if (e < E) {
            int ps = bc[src[e]];
            int pd = bc[dst[e]];
            bmT[(size_t)pd * NCLUST + ps] = 1;
        }
    }
}

__global__ __launch_bounds__(256) void k_pooldeg(
        const unsigned char* __restrict__ bmT, float* __restrict__ dinvp) {
    int d = blockIdx.x;
    int t = threadIdx.x;
    const unsigned int v = reinterpret_cast<const unsigned int*>(bmT + (size_t)d * NCLUST)[t];
    int s = (v & 0xff) + ((v >> 8) & 0xff) + ((v >> 16) & 0xff) + ((v >> 24) & 0xff);
    if (t == (d >> 2)) s -= (v >> ((d & 3) * 8)) & 0xff;
    __shared__ int red[256];
    red[t] = s; __syncthreads();
    for (int o = 128; o > 0; o >>= 1) {
        if (t < o) red[t] += red[t + o];
        __syncthreads();
    }
    if (t == 0) dinvp[d] = rsqrtf((float)red[0] + 1.0f);
}

template <int F>
__global__ __launch_bounds__(1024) void k_proppool2(
        const float* __restrict__ h, const float* __restrict__ dinvp,
        const unsigned char* __restrict__ bmT, const float* __restrict__ bias,
        float* __restrict__ out) {
    constexpr int SG = 1024 / F;
    const int d = blockIdx.x;
    const int t = threadIdx.x;
    const int f = t & (F - 1);
    const int sg = t / F;
    const unsigned char* bmrow = bmT + (size_t)d * NCLUST;
    float acc = 0.f;
#pragma unroll 4
    for (int s = sg; s < NCLUST; s += SG) {
        float m = (s != d) ? (float)bmrow[s] : 0.f;
        acc += m * dinvp[s] * h[(size_t)s * F + f];
    }
    __shared__ float red[1024];
    red[t] = acc; __syncthreads();
#pragma unroll
    for (int o = SG / 2; o > 0; o >>= 1) {
        if (sg < o) red[t] += red[t + o * F];
        __syncthreads();
    }
    if (sg == 0) {
        float di = dinvp[d];
        float r = di * red[f] + di * di * h[(size_t)d * F + f] + bias[f];
        out[(size_t)d * F + f] = elu1(r);
    }
}

// ---------------------------------------------------------------------------
extern "C" void kernel_launch(void* const* d_in, const int* in_sizes, int n_in,
                              void* d_out, int out_size, void* d_ws, size_t ws_size,
                              hipStream_t stream) {
    const float* x       = (const float*)d_in[0];
    const int*   adj     = (const int*)d_in[1];
    const int*   inb     = (const int*)d_in[3];
    const int*   cluster = (const int*)d_in[4];
    const float* WG1  = (const float*)d_in[5];   const float* bG1  = (const float*)d_in[6];
    const float* WfG1 = (const float*)d_in[7];   const float* bfG1 = (const float*)d_in[8];
    const float* WG2  = (const float*)d_in[9];   const float* bG2  = (const float*)d_in[10];
    const float* WfG2 = (const float*)d_in[11];  const float* bfG2 = (const float*)d_in[12];
    const float* WL1  = (const float*)d_in[13];  const float* bL1  = (const float*)d_in[14];
    const float* WfL1 = (const float*)d_in[15];  const float* bfL1 = (const float*)d_in[16];
    const float* WL2  = (const float*)d_in[17];  const float* bL2  = (const float*)d_in[18];
    const float* WfL2 = (const float*)d_in[19];  const float* bfL2 = (const float*)d_in[20];
    const float* WO1  = (const float*)d_in[21];  const float* bO1  = (const float*)d_in[22];
    const float* WfO1 = (const float*)d_in[23];  const float* bfO1 = (const float*)d_in[24];
    const float* WO2  = (const float*)d_in[25];  const float* bO2  = (const float*)d_in[26];
    const float* WfO2 = (const float*)d_in[27];  const float* bfO2 = (const float*)d_in[28];
    const float* WO3  = (const float*)d_in[29];  const float* bO3  = (const float*)d_in[30];
    const float* WfO3 = (const float*)d_in[31];  const float* bfO3 = (const float*)d_in[32];
    float* out = (float*)d_out;

    const int n = in_sizes[0] / 3;       // 100000
    const int E = in_sizes[1] / 2;       // 1600000
    const int* src = adj;
    const int* dst = adj + E;

    // ---- workspace carve ----
    char* ws = (char*)d_ws;
    size_t off = 0;
    auto alloc = [&](size_t bytes) -> void* {
        void* p = ws + off;
        off = (off + bytes + 255) & ~(size_t)255;
        return p;
    };
    int*   deg     = (int*)alloc((size_t)n * 4);     // zero span 1 start
    int*   fill    = (int*)alloc((size_t)n * 4);
    int*   cdeg    = (int*)alloc(NCLUST * 4);
    int*   cfill   = (int*)alloc(NCLUST * 4);
    int*   rowptr  = (int*)alloc((size_t)n * 4);     // zero span 1 end (exclusive)
    int*   crowptr = (int*)alloc(NCLUST * 4);
    int*   cnodes  = (int*)alloc((size_t)n * 4);
    int*   bcarr   = (int*)alloc((size_t)n * 4);
    float* dinv    = (float*)alloc((size_t)n * 4);
    int*   bsum    = (int*)alloc(512);
    int2*  csr_ev  = (int2*)alloc((size_t)E * 8);
    float* X       = (float*)alloc((size_t)n * 256 * 4);
    unsigned short* Xh = (unsigned short*)alloc((size_t)n * 256 * 2);
    float* B       = (float*)alloc((size_t)n * 128 * 4);
    unsigned short* Bh = (unsigned short*)alloc((size_t)n * 128 * 2);
    float* insum   = (float*)alloc(256 * 4);         // zero span 2 start
    float* insumsq = (float*)alloc(256 * 4);
    float* px      = (float*)alloc((size_t)NCLUST * 256 * 4);
    unsigned char* bmT = (unsigned char*)alloc((size_t)NCLUST * NCLUST);
    float* corr    = (float*)alloc(128 * 4);
    float* mu      = (float*)alloc(256 * 4);         // zero span 2 end (exclusive)
    float* rstd    = (float*)alloc(256 * 4);
    float* dinvp   = (float*)alloc(NCLUST * 4);
    float* lA      = (float*)alloc((size_t)NCLUST * 128 * 4);
    float* lB      = (float*)alloc((size_t)NCLUST * 128 * 4);
    unsigned* pfG1h = (unsigned*)alloc(2048 * 4);   unsigned* pfG1l = (unsigned*)alloc(2048 * 4);
    unsigned* pG2h  = (unsigned*)alloc(8192 * 4);   unsigned* pG2l  = (unsigned*)alloc(8192 * 4);
    unsigned* pfG2h = (unsigned*)alloc(32768 * 4);  unsigned* pfG2l = (unsigned*)alloc(32768 * 4);
    unsigned* pO1h  = (unsigned*)alloc(16384 * 4);  unsigned* pO1l  = (unsigned*)alloc(16384 * 4);
    unsigned* pfO1h = (unsigned*)alloc(8192 * 4);   unsigned* pfO1l = (unsigned*)alloc(8192 * 4);
    unsigned* pO2h  = (unsigned*)alloc(2048 * 4);   unsigned* pO2l  = (unsigned*)alloc(2048 * 4);
    unsigned* pfO2h = (unsigned*)alloc(512 * 4);    unsigned* pfO2l = (unsigned*)alloc(512 * 4);
    (void)ws_size; (void)n_in; (void)out_size;

    unsigned short* Bh1 = Bh;                        // h1/h2 (n x 64 bf16)
    unsigned short* Bh2 = Bh + (size_t)n * 64;       // p64 (n x 64 bf16)

    auto cdiv = [](int a, int b) { return (a + b - 1) / b; };
    const int EB = cdiv(E, 256);
    const int PB = cdiv(n, 4);

    // ---- init: zero scratch + pack all static weights (ONE launch) ----
    int nz1 = (int)(((char*)rowptr - (char*)deg) / 16);
    int nz2 = (int)(((char*)mu - (char*)insum) / 16);
    InitArgs ia;
    ia.d[0] = {WfG1, pfG1h, pfG1l, 64, 64, 0};
    ia.d[1] = {WG2,  pG2h,  pG2l,  64, 256, 512};
    ia.d[2] = {WfG2, pfG2h, pfG2l, 256, 256, 2560};
    ia.d[3] = {WfO1, pfO1h, pfO1l, 128, 128, 10752};
    ia.d[4] = {WO2,  pO2h,  pO2l,  128, 32, 12800};
    ia.d[5] = {WfO2, pfO2h, pfO2l, 32, 32, 13312};
    ia.tot = 13440;
    ia.z1 = (int4*)deg; ia.nz1 = nz1;
    ia.z2 = (int4*)insum; ia.nz2 = nz2;
    int initN = (nz1 + nz2 > ia.tot) ? (nz1 + nz2) : ia.tot;
    k_init<<<cdiv(initN, 256), 256, 0, stream>>>(ia);

    // ---- CSR build ----
    k_hist<<<EB, 256, 0, stream>>>(dst, deg, E);
    int nb = cdiv(n, 1024);
    k_scan_block<<<nb, 256, 0, stream>>>(deg, rowptr, bsum, n);
    k_nodeinit<<<cdiv(n, 256), 256, 0, stream>>>(rowptr, bsum, deg, cluster, inb,
                                                 dinv, bcarr, cdeg, n, nb);
    k_scan_block<<<1, 256, 0, stream>>>(cdeg, crowptr, bsum, NCLUST);
    k_fillc<<<EB, 256, 0, stream>>>(src, dst, dinv, rowptr, fill, csr_ev, E,
                                    bcarr, crowptr, cfill, cnodes, n);

    // ---- global GCN stack (all bf16 activations) ----
    // p3 + fused fc<64>: h1 -> bf16 Bh1
    k_prop3f1<<<cdiv(n, 256), 256, 0, stream>>>(x, dinv, rowptr, deg, csr_ev,
                                                WG1, bG1, Bh1, n);
    // h2 = elu(h1 @ WfG1 + bfG1)  (Bh1 in-place, register-W)  [8-wave]
    k_gmfma<64, 8, 0><<<cdiv(n, 256), 512, 0, stream>>>(Bh1, pfG1h, pfG1l, bfG1,
                                                        nullptr, nullptr, nullptr,
                                                        nullptr, Bh1, nullptr, nullptr,
                                                        n, 64, 1);
    // p64 = S h2  (bf16 gather -> bf16 Bh2)
    k_prop4sb<64, 1><<<PB, 256, 0, stream>>>(Bh1, dinv, rowptr, deg, csr_ev,
                                             nullptr, nullptr, Bh2, n, 0);
    // h3 = elu(p64 @ WG2 + bG2) -> bf16 (Xh)  [FULLW: 1 chunk, 2 barriers]
    k_gmfma<256, 8, 64><<<cdiv(n, 64), 512, 0, stream>>>(Bh2, pG2h, pG2l, bG2,
                                                         nullptr, nullptr, nullptr,
                                                         nullptr, Xh, nullptr, nullptr,
                                                         n, 64, 1);
    // h4 = elu(h3 @ WfG2 + bfG2)  (Xh in-place)  [FULLW=32: 32KB, 4 blk/CU]
    k_gmfma<256, 8, 32><<<cdiv(n, 64), 512, 0, stream>>>(Xh, pfG2h, pfG2l, bfG2,
                                                         nullptr, nullptr, nullptr,
                                                         nullptr, Xh, nullptr, nullptr,
                                                         n, 256, 1);

    // ---- instance norm stats + merged finalize/pack/corr ----
    k_instats<<<cdiv(n, 128), 256, 0, stream>>>(Xh, insum, insumsq, n);
    k_normprep<<<17, 256, 0, stream>>>(WO1, insum, insumsq, pO1h, pO1l, corr, mu, rstd, n);

    // ---- cluster pooling (poolavg + pooledges merged) ----
    k_poolmerge<<<NCLUST + EB, 256, 0, stream>>>(Xh, crowptr, cdeg, cnodes, mu, rstd, px,
                                                 src, dst, bcarr, bmT, E);
    k_pooldeg<<<NCLUST, 256, 0, stream>>>(bmT, dinvp);

    // ---- local (pooled) GCN stack ----
    k_fc<128, 2><<<cdiv(NCLUST, 16), 256, 0, stream>>>(px, WL1, nullptr, nullptr, nullptr,
                                                       lA, NCLUST, 256, 0);
    k_proppool2<128><<<NCLUST, 1024, 0, stream>>>(lA, dinvp, bmT, bL1, lB);
    k_fc<128, 2><<<cdiv(NCLUST, 16), 256, 0, stream>>>(lB, WfL1, bfL1, nullptr, nullptr,
                                                       lA, NCLUST, 128, 1);
    k_fc<64, 2><<<cdiv(NCLUST, 32), 256, 0, stream>>>(lA, WL2, nullptr, nullptr, nullptr,
                                                      lB, NCLUST, 128, 0);
    k_proppool2<64><<<NCLUST, 1024, 0, stream>>>(lB, dinvp, bmT, bL2, lA);
    // fused: lx = elu(lA @ WfL2 + bfL2) -> lB; compO = lx @ WO1[256:] -> lA
    k_fcl2<<<NCLUST / 32, 256, 0, stream>>>(lA, WfL2, bfL2, WO1 + (size_t)256 * 128,
                                            lB, lA);

    // ---- output GCN stack ----
    // t1 = Xh @ (rstd*WO1) - corr + compO[bc] -> bf16 (Bh)  [FULLW: 2 chunks]
    k_gmfma<128, 8, 128><<<cdiv(n, 128), 512, 0, stream>>>(Xh, pO1h, pO1l, nullptr,
                                                           corr, lA, bcarr, nullptr, Bh,
                                                           nullptr, nullptr, n, 256, 0);
    k_prop4sb<128, 1><<<PB, 256, 0, stream>>>(Bh, dinv, rowptr, deg, csr_ev,
                                              bO1, nullptr, Xh, n, 1);
    // o2 = elu(o1 @ WfO1 + bfO1)  (Xh in-place)  [FULLW: 1 chunk]
    k_gmfma<128, 8, 128><<<cdiv(n, 128), 512, 0, stream>>>(Xh, pfO1h, pfO1l, bfO1,
                                                           nullptr, nullptr, nullptr,
                                                           nullptr, Xh, nullptr, nullptr,
                                                           n, 128, 1);
    // t2 = o2 @ WO2  -> bf16 (Bh, N x 32)  [register-W, 8-wave]
    k_gmfma<32, 8, 0><<<cdiv(n, 256), 512, 0, stream>>>(Xh, pO2h, pO2l, nullptr,
                                                        nullptr, nullptr, nullptr,
                                                        nullptr, Bh, nullptr, nullptr,
                                                        n, 128, 0);
    k_prop4sb<32, 1><<<PB, 256, 0, stream>>>(Bh, dinv, rowptr, deg, csr_ev,
                                             bO2, nullptr, Xh, n, 1);
    // o4 = elu(o3 @ WfO2 + bfO2); t3 = o4 @ WO3 fused -> B (N x 3 f32)
    k_gmfma<32, 8, 0><<<cdiv(n, 256), 512, 0, stream>>>(Xh, pfO2h, pfO2l, bfO2,
                                                        nullptr, nullptr, nullptr,
                                                        nullptr, nullptr, WO3, B,
                                                        n, 32, 1);
    // o5 = elu(S t3 + bO3); out = elu(o5 @ WfO3 + bfO3)  (fused)
    k_prop3out<<<cdiv(n, 256), 256, 0, stream>>>(B, dinv, rowptr, deg, csr_ev,
                                                 bO3, WfO3, bfO3, out, n);
}

// Round 30
// 1051.758 us; speedup vs baseline: 1.0786x; 1.0598x over previous
//
#include <hip/hip_runtime.h>

// ---------------------------------------------------------------------------
// GCN3D. R9: split-bf16 MFMA GEMMs. R13: prop4s+norm-fold. R14/15/17/23: bf16
// activations everywhere. R17/R20/R21/R22: launch merging, int2 edges.
// R24: LDS-W staging. R26/R27: FULLW chunked k-loops. R29: FULLW=32 (32KB,
//   4 blk/CU) fixed h4 -- occupancy was the GEMM constraint (1115us best).
// R30: top kernel now prop4sb<128> (o1 gather, 110us, latency-bound:
//   2.04TB/s, VALU 38%). (a) edge-loop unroll x2: two independent row
//   gathers in flight (poolavg-ILP mechanism). (b) roll 32KB chunks out:
//   h3 FULLW 64->32, t1/o2 FULLW 128->64 (4 blk/CU everywhere).
// ---------------------------------------------------------------------------

#define NCLUST 1024

typedef short bf16x8 __attribute__((ext_vector_type(8)));
typedef float f32x4 __attribute__((ext_vector_type(4)));

__device__ __forceinline__ float elu1(float x) { return x > 0.f ? x : expm1f(x); }

__device__ __forceinline__ unsigned f2bf(float f) {
    union { float f; unsigned u; } c; c.f = f;
    unsigned u = c.u;
    return (u + 0x7fffu + ((u >> 16) & 1u)) >> 16;
}
__device__ __forceinline__ float bf2f(unsigned h) {
    union { unsigned u; float f; } c; c.u = h << 16; return c.f;
}

union U8 { unsigned u[4]; bf16x8 v; };

// ---- W pre-pack body ----
__device__ __forceinline__ void wpack_body(const float* W, unsigned* Phi, unsigned* Plo,
                                           int K, int BN, int t) {
    int NT = BN / 16;
    int lane = t & 63;
    int rest = t >> 6;
    int ct = rest % NT;
    int s = rest / NT;
    int col = ct * 16 + (lane & 15);
    int g = lane >> 4;
    int k0 = s * 32;
    float e[8];
#pragma unroll
    for (int j = 0; j < 4; j++) {
        e[j]     = W[(size_t)(k0 + 4 * g + j) * BN + col];
        e[4 + j] = W[(size_t)(k0 + 16 + 4 * g + j) * BN + col];
    }
#pragma unroll
    for (int j = 0; j < 4; j++) {
        unsigned h0 = f2bf(e[2 * j]), h1 = f2bf(e[2 * j + 1]);
        Phi[(size_t)t * 4 + j] = h0 | (h1 << 16);
        unsigned l0 = f2bf(e[2 * j] - bf2f(h0));
        unsigned l1 = f2bf(e[2 * j + 1] - bf2f(h1));
        Plo[(size_t)t * 4 + j] = l0 | (l1 << 16);
    }
}

struct PackDesc { const float* W; unsigned* Ph; unsigned* Pl; int K, BN, tbase; };
struct InitArgs {
    PackDesc d[6]; int tot;
    int4* z1; int nz1; int4* z2; int nz2;
};

__global__ void k_init(InitArgs a) {
    int t = blockIdx.x * 256 + threadIdx.x;
    if (t < a.nz1) a.z1[t] = make_int4(0, 0, 0, 0);
    else if (t - a.nz1 < a.nz2) a.z2[t - a.nz1] = make_int4(0, 0, 0, 0);
    if (t < a.tot) {
        int i = 0;
#pragma unroll
        for (int j = 1; j < 6; j++) if (t >= a.d[j].tbase) i = j;
        wpack_body(a.d[i].W, a.d[i].Ph, a.d[i].Pl, a.d[i].K, a.d[i].BN,
                   t - a.d[i].tbase);
    }
}

// ---------------- CSR build ----------------
__global__ void k_hist(const int* __restrict__ key, int* __restrict__ deg, int E) {
    int e = blockIdx.x * 256 + threadIdx.x;
    if (e < E) atomicAdd(&deg[key[e]], 1);
}

__global__ void k_scan_block(const int* __restrict__ deg, int* __restrict__ rowptr,
                             int* __restrict__ bsum, int n) {
    __shared__ int lds[256];
    int tid = threadIdx.x;
    int base = blockIdx.x * 1024 + tid * 4;
    int v0 = base + 0 < n ? deg[base + 0] : 0;
    int v1 = base + 1 < n ? deg[base + 1] : 0;
    int v2 = base + 2 < n ? deg[base + 2] : 0;
    int v3 = base + 3 < n ? deg[base + 3] : 0;
    int tsum = v0 + v1 + v2 + v3;
    lds[tid] = tsum; __syncthreads();
    for (int off = 1; off < 256; off <<= 1) {
        int t = (tid >= off) ? lds[tid - off] : 0;
        __syncthreads();
        lds[tid] += t;
        __syncthreads();
    }
    int run = lds[tid] - tsum;
    if (base + 0 < n) rowptr[base + 0] = run; run += v0;
    if (base + 1 < n) rowptr[base + 1] = run; run += v1;
    if (base + 2 < n) rowptr[base + 2] = run; run += v2;
    if (base + 3 < n) rowptr[base + 3] = run;
    if (tid == 255) bsum[blockIdx.x] = lds[255];
}

// merged: bsum scan + rowptr finalize + dinv + bc + cluster hist
__global__ void k_nodeinit(int* __restrict__ rowptr, const int* __restrict__ bsum,
                           const int* __restrict__ deg, const int* __restrict__ cluster,
                           const int* __restrict__ inb, float* __restrict__ dinv,
                           int* __restrict__ bc, int* __restrict__ cdeg, int n, int nb) {
    __shared__ int pfx[128];
    int tid = threadIdx.x;
    if (tid < 128) pfx[tid] = (tid < nb) ? bsum[tid] : 0;
    __syncthreads();
    for (int off = 1; off < 128; off <<= 1) {
        int v = 0;
        if (tid < 128 && tid >= off) v = pfx[tid - off];
        __syncthreads();
        if (tid < 128) pfx[tid] += v;
        __syncthreads();
    }
    int i = blockIdx.x * 256 + tid;
    if (i >= n) return;
    int j = i >> 10;
    int base = (j == 0) ? 0 : pfx[j - 1];
    rowptr[i] += base;
    dinv[i] = rsqrtf((float)deg[i] + 1.0f);
    int c = cluster[i] + inb[i] * NCLUST;
    bc[i] = c;
    atomicAdd(&cdeg[c], 1);
}

// merged: edge CSR fill (packed int2) + cluster member fill
__global__ void k_fillc(const int* __restrict__ src, const int* __restrict__ dst,
                        const float* __restrict__ dinv, const int* __restrict__ rowptr,
                        int* __restrict__ fill, int2* __restrict__ csr_ev, int E,
                        const int* __restrict__ bc, const int* __restrict__ crowptr,
                        int* __restrict__ cfill, int* __restrict__ cnodes, int n) {
    int e = blockIdx.x * 256 + threadIdx.x;
    if (e < E) {
        int d = dst[e];
        int pos = rowptr[d] + atomicAdd(&fill[d], 1);
        int s = src[e];
        csr_ev[pos] = make_int2(s, __float_as_int(dinv[s]));
    }
    if (e < n) {
        int c = bc[e];
        int pos = crowptr[c] + atomicAdd(&cfill[c], 1);
        cnodes[pos] = e;
    }
}

// ------ GCN propagation, bf16 input; OB=0 f32 out, OB=1 bf16 out ------
// Edge loop unrolled x2: two independent row-gathers in flight per iter.
template <int F, int OB>
__global__ __launch_bounds__(256) void k_prop4sb(
        const unsigned short* __restrict__ hbf, const float* __restrict__ dinv,
        const int* __restrict__ rowptr, const int* __restrict__ deg,
        const int2* __restrict__ csr_ev,
        const float* __restrict__ bias, float* __restrict__ outf,
        unsigned short* __restrict__ outb, int n, int flags) {
    constexpr int FS = F / 4;
    constexpr int ES = 64 / FS;
    const int node = (blockIdx.x * 256 + threadIdx.x) >> 6;
    if (node >= n) return;
    const int l = threadIdx.x & 63;
    const int fs = l & (FS - 1);
    const int ep = l / FS;
    const int fi = fs * 4;
    const int start = rowptr[node];
    const int cnt = deg[node];
    float ax = 0.f, ay = 0.f, az = 0.f, aw = 0.f;
    int j = ep;
    for (; j + ES < cnt; j += 2 * ES) {
        const int2 ev0 = csr_ev[start + j];
        const int2 ev1 = csr_ev[start + j + ES];
        float w0 = __int_as_float(ev0.y);
        float w1 = __int_as_float(ev1.y);
        const ushort4 v0 = *reinterpret_cast<const ushort4*>(&hbf[(size_t)ev0.x * F + fi]);
        const ushort4 v1 = *reinterpret_cast<const ushort4*>(&hbf[(size_t)ev1.x * F + fi]);
        ax += w0 * bf2f(v0.x) + w1 * bf2f(v1.x);
        ay += w0 * bf2f(v0.y) + w1 * bf2f(v1.y);
        az += w0 * bf2f(v0.z) + w1 * bf2f(v1.z);
        aw += w0 * bf2f(v0.w) + w1 * bf2f(v1.w);
    }
    if (j < cnt) {
        const int2 ev = csr_ev[start + j];
        float w = __int_as_float(ev.y);
        const ushort4 v = *reinterpret_cast<const ushort4*>(&hbf[(size_t)ev.x * F + fi]);
        ax += w * bf2f(v.x); ay += w * bf2f(v.y);
        az += w * bf2f(v.z); aw += w * bf2f(v.w);
    }
#pragma unroll
    for (int off = FS; off < 64; off <<= 1) {
        ax += __shfl_xor(ax, off);
        ay += __shfl_xor(ay, off);
        az += __shfl_xor(az, off);
        aw += __shfl_xor(aw, off);
    }
    if (ep == 0) {
        float di = dinv[node];
        const ushort4 sv = *reinterpret_cast<const ushort4*>(&hbf[(size_t)node * F + fi]);
        float4 o;
        o.x = di * ax + di * di * bf2f(sv.x);
        o.y = di * ay + di * di * bf2f(sv.y);
        o.z = di * az + di * di * bf2f(sv.z);
        o.w = di * aw + di * di * bf2f(sv.w);
        if (flags) {
            const float4 b = *reinterpret_cast<const float4*>(&bias[fi]);
            o.x = elu1(o.x + b.x); o.y = elu1(o.y + b.y);
            o.z = elu1(o.z + b.z); o.w = elu1(o.w + b.w);
        }
        if constexpr (OB) {
            ushort4 ob;
            ob.x = (unsigned short)f2bf(o.x); ob.y = (unsigned short)f2bf(o.y);
            ob.z = (unsigned short)f2bf(o.z); ob.w = (unsigned short)f2bf(o.w);
            *reinterpret_cast<ushort4*>(&outb[(size_t)node * F + fi]) = ob;
        } else {
            *reinterpret_cast<float4*>(&outf[(size_t)node * F + fi]) = o;
        }
    }
}

// prop3 on x + fused fc<64> -> bf16 out (N x 64)
__global__ void k_prop3f1(const float* __restrict__ h, const float* __restrict__ dinv,
                          const int* __restrict__ rowptr, const int* __restrict__ deg,
                          const int2* __restrict__ csr_ev,
                          const float* __restrict__ WG1, const float* __restrict__ bG1,
                          unsigned short* __restrict__ outb, int n) {
    int node = blockIdx.x * 256 + threadIdx.x;
    if (node >= n) return;
    int start = rowptr[node], cnt = deg[node];
    float a0 = 0.f, a1 = 0.f, a2 = 0.f;
    for (int j = 0; j < cnt; j++) {
        const int2 ev = csr_ev[start + j];
        int s = ev.x;
        float w = __int_as_float(ev.y);
        a0 += w * h[(size_t)s * 3 + 0];
        a1 += w * h[(size_t)s * 3 + 1];
        a2 += w * h[(size_t)s * 3 + 2];
    }
    float di = dinv[node];
    float p0 = di * a0 + di * di * h[(size_t)node * 3 + 0];
    float p1 = di * a1 + di * di * h[(size_t)node * 3 + 1];
    float p2 = di * a2 + di * di * h[(size_t)node * 3 + 2];
    unsigned short* op = outb + (size_t)node * 64;
#pragma unroll 4
    for (int c = 0; c < 64; c += 4) {
        ushort4 ob;
        ob.x = (unsigned short)f2bf(elu1(p0 * WG1[c + 0] + p1 * WG1[64 + c + 0] + p2 * WG1[128 + c + 0] + bG1[c + 0]));
        ob.y = (unsigned short)f2bf(elu1(p0 * WG1[c + 1] + p1 * WG1[64 + c + 1] + p2 * WG1[128 + c + 1] + bG1[c + 1]));
        ob.z = (unsigned short)f2bf(elu1(p0 * WG1[c + 2] + p1 * WG1[64 + c + 2] + p2 * WG1[128 + c + 2] + bG1[c + 2]));
        ob.w = (unsigned short)f2bf(elu1(p0 * WG1[c + 3] + p1 * WG1[64 + c + 3] + p2 * WG1[128 + c + 3] + bG1[c + 3]));
        *reinterpret_cast<ushort4*>(op + c) = ob;
    }
}

// prop3 on t3 (+bO3, elu) + fused final fc3
__global__ void k_prop3out(const float* __restrict__ h, const float* __restrict__ dinv,
                           const int* __restrict__ rowptr, const int* __restrict__ deg,
                           const int2* __restrict__ csr_ev,
                           const float* __restrict__ bO3, const float* __restrict__ WfO3,
                           const float* __restrict__ bfO3, float* __restrict__ out, int n) {
    int node = blockIdx.x * 256 + threadIdx.x;
    if (node >= n) return;
    int start = rowptr[node], cnt = deg[node];
    float a0 = 0.f, a1 = 0.f, a2 = 0.f;
    for (int j = 0; j < cnt; j++) {
        const int2 ev = csr_ev[start + j];
        int s = ev.x;
        float w = __int_as_float(ev.y);
        a0 += w * h[(size_t)s * 3 + 0];
        a1 += w * h[(size_t)s * 3 + 1];
        a2 += w * h[(size_t)s * 3 + 2];
    }
    float di = dinv[node];
    float o0 = elu1(di * a0 + di * di * h[(size_t)node * 3 + 0] + bO3[0]);
    float o1 = elu1(di * a1 + di * di * h[(size_t)node * 3 + 1] + bO3[1]);
    float o2 = elu1(di * a2 + di * di * h[(size_t)node * 3 + 2] + bO3[2]);
#pragma unroll
    for (int c = 0; c < 3; c++) {
        out[(size_t)node * 3 + c] =
            elu1(o0 * WfO3[c] + o1 * WfO3[3 + c] + o2 * WfO3[6 + c] + bfO3[c]);
    }
}

// ---- merged: infinal + rstd-scaled WO1 pack + corr (17 blocks x 256) ----
__global__ void k_normprep(const float* __restrict__ W, const float* __restrict__ insum,
                           const float* __restrict__ insumsq, unsigned* __restrict__ Phi,
                           unsigned* __restrict__ Plo, float* __restrict__ corr,
                           float* __restrict__ mu, float* __restrict__ rstd, int n) {
    const float fn = (float)n;
    const int bid = blockIdx.x, tid = threadIdx.x;
    if (bid == 16) {
        float m = insum[tid] / fn;
        float var = insumsq[tid] / fn - m * m;
        mu[tid] = m;
        rstd[tid] = rsqrtf(var + 1e-5f);
        return;
    }
    {
        int t = bid * 256 + tid;
        int lane = t & 63, rest = t >> 6;
        int ct = rest % 8, s = rest / 8;
        int col = ct * 16 + (lane & 15);
        int g = lane >> 4;
        int k0 = s * 32;
        float e[8];
#pragma unroll
        for (int j = 0; j < 4; j++) {
            int ka = k0 + 4 * g + j;
            int kb = k0 + 16 + 4 * g + j;
            float ma = insum[ka] / fn;
            float sa = rsqrtf(insumsq[ka] / fn - ma * ma + 1e-5f);
            float mb = insum[kb] / fn;
            float sb = rsqrtf(insumsq[kb] / fn - mb * mb + 1e-5f);
            e[j]     = W[(size_t)ka * 128 + col] * sa;
            e[4 + j] = W[(size_t)kb * 128 + col] * sb;
        }
#pragma unroll
        for (int j = 0; j < 4; j++) {
            unsigned h0 = f2bf(e[2 * j]), h1 = f2bf(e[2 * j + 1]);
            Phi[(size_t)t * 4 + j] = h0 | (h1 << 16);
            unsigned l0 = f2bf(e[2 * j] - bf2f(h0));
            unsigned l1 = f2bf(e[2 * j + 1] - bf2f(h1));
            Plo[(size_t)t * 4 + j] = l0 | (l1 << 16);
        }
    }
    if (tid < 128) {
        int k0 = bid * 16;
        float s = 0.f;
        for (int k = k0; k < k0 + 16; k++) {
            float m = insum[k] / fn;
            float r = rsqrtf(insumsq[k] / fn - m * m + 1e-5f);
            s += m * r * W[(size_t)k * 128 + tid];
        }
        atomicAdd(&corr[tid], s);
    }
}

// ---- split-bf16 MFMA GEMM (bf16-A only). Three W paths:
//   FULLW>0 (ksteps-worth of W per chunk, chunk <= 64KB): loop chunks
//     {stage chunk, barrier, barrier-free compute, barrier}. 32KB chunks
//     give 4 blocks/CU (R29: occupancy is the binding constraint).
//   else BN>=128: double-buffered global_load_lds W, barrier per kstep.
//   else: register W.
// Optional fused second GEMM (W3: BN x 3) via 16-lane shfl -> C3 (BN<=32).
template <int BN, int WAVES, int FULLW>
__global__ __launch_bounds__(WAVES * 64) void k_gmfma(
        const unsigned short* __restrict__ Abf,
        const unsigned* __restrict__ Phi, const unsigned* __restrict__ Plo,
        const float* __restrict__ bias, const float* __restrict__ sub,
        const float* __restrict__ add, const int* __restrict__ addidx,
        float* __restrict__ C, unsigned short* __restrict__ Cbf,
        const float* __restrict__ W3, float* __restrict__ C3,
        int N, int K, int flags) {
    constexpr int NT = BN / 16;
    constexpr int WCOL = (BN == 256) ? 4 : (BN == 128 ? 2 : 1);
    constexpr int WROW = WAVES / WCOL;
    constexpr int NTW = NT / WCOL;
    constexpr int BR = 32 * WROW;
    constexpr bool LDSW = (BN >= 128);
    constexpr int LDSU = (FULLW > 0) ? 2 * NT * (FULLW / 32) * 256
                                     : (LDSW ? 2 * 2 * NT * 256 : 1);
    __shared__ unsigned lds_w[LDSU];
    const int t = threadIdx.x;
    const int w = t >> 6, l = t & 63;
    const int wr = w / WCOL, wc = w % WCOL;
    const int l15 = l & 15, g = l >> 4;
    const int row0 = blockIdx.x * BR + wr * 32;
    const int ctbase = wc * NTW;
    int ar0 = row0 + l15;      ar0 = ar0 < N ? ar0 : N - 1;
    int ar1 = row0 + 16 + l15; ar1 = ar1 < N ? ar1 : N - 1;
    const unsigned short* ab0 = Abf + (size_t)ar0 * K;
    const unsigned short* ab1 = Abf + (size_t)ar1 * K;

    f32x4 acc[2][NTW];
#pragma unroll
    for (int f = 0; f < 2; f++)
#pragma unroll
        for (int ct = 0; ct < NTW; ct++) acc[f][ct] = (f32x4){0.f, 0.f, 0.f, 0.f};

    auto loadA = [&](int s, U8* ahi) {
        const int k0 = s * 32;
#pragma unroll
        for (int f = 0; f < 2; f++) {
            const unsigned short* ab = f ? ab1 : ab0;
            const uint2 hA = *reinterpret_cast<const uint2*>(ab + k0 + 4 * g);
            const uint2 hB = *reinterpret_cast<const uint2*>(ab + k0 + 16 + 4 * g);
            ahi[f].u[0] = hA.x; ahi[f].u[1] = hA.y;
            ahi[f].u[2] = hB.x; ahi[f].u[3] = hB.y;
        }
    };
    auto domfma = [&](U8* wh, U8* wl, U8* ahi) {
#pragma unroll
        for (int ct = 0; ct < NTW; ct++) {
            acc[0][ct] = __builtin_amdgcn_mfma_f32_16x16x32_bf16(ahi[0].v, wh[ct].v, acc[0][ct], 0, 0, 0);
            acc[0][ct] = __builtin_amdgcn_mfma_f32_16x16x32_bf16(ahi[0].v, wl[ct].v, acc[0][ct], 0, 0, 0);
            acc[1][ct] = __builtin_amdgcn_mfma_f32_16x16x32_bf16(ahi[1].v, wh[ct].v, acc[1][ct], 0, 0, 0);
            acc[1][ct] = __builtin_amdgcn_mfma_f32_16x16x32_bf16(ahi[1].v, wl[ct].v, acc[1][ct], 0, 0, 0);
        }
    };

    const int nk = K / 32;

    if constexpr (FULLW > 0) {
        constexpr int NKT = FULLW / 32;     // ksteps per chunk
        const int nchunk = K / FULLW;
        U8 wh[NTW], wl[NTW], ahiA[2];
        for (int c = 0; c < nchunk; c++) {
            for (int i = w; i < 2 * NT * NKT; i += WAVES) {
                int s = i / (2 * NT);
                int j = i - s * 2 * NT;
                int gs = c * NKT + s;
                const unsigned* gsrc = (j < NT)
                    ? Phi + (size_t)(gs * NT + j) * 256 + l * 4
                    : Plo + (size_t)(gs * NT + (j - NT)) * 256 + l * 4;
                __builtin_amdgcn_global_load_lds(
                    (const __attribute__((address_space(1))) unsigned*)gsrc,
                    (__attribute__((address_space(3))) unsigned*)(lds_w + (size_t)i * 256),
                    16, 0, 0);
            }
            __syncthreads();                // chunk staged + visible
#pragma unroll
            for (int s = 0; s < NKT; s++) {
                loadA(c * NKT + s, ahiA);
                const unsigned* base = lds_w + (size_t)s * (2 * NT * 256);
#pragma unroll
                for (int ct = 0; ct < NTW; ct++) {
                    wh[ct] = *reinterpret_cast<const U8*>(base + (ctbase + ct) * 256 + l * 4);
                    wl[ct] = *reinterpret_cast<const U8*>(base + (NT + ctbase + ct) * 256 + l * 4);
                }
                domfma(wh, wl, ahiA);
            }
            __syncthreads();   // reads done before restage / stores (in-place)
        }
    } else if constexpr (LDSW) {
        auto stage = [&](int s, int b) {
            unsigned* base = lds_w + (size_t)b * (2 * NT * 256);
            for (int i = w; i < 2 * NT; i += WAVES) {
                const unsigned* gsrc = (i < NT)
                    ? Phi + (size_t)(s * NT + i) * 256 + l * 4
                    : Plo + (size_t)(s * NT + (i - NT)) * 256 + l * 4;
                __builtin_amdgcn_global_load_lds(
                    (const __attribute__((address_space(1))) unsigned*)gsrc,
                    (__attribute__((address_space(3))) unsigned*)(base + i * 256),
                    16, 0, 0);
            }
        };
        auto loadWlds = [&](int b, U8* wh, U8* wl) {
            const unsigned* base = lds_w + (size_t)b * (2 * NT * 256);
#pragma unroll
            for (int ct = 0; ct < NTW; ct++) {
                wh[ct] = *reinterpret_cast<const U8*>(base + (ctbase + ct) * 256 + l * 4);
                wl[ct] = *reinterpret_cast<const U8*>(base + (NT + ctbase + ct) * 256 + l * 4);
            }
        };

        U8 wh[NTW], wl[NTW], ahiA[2], ahiB[2];
        stage(0, 0);
        loadA(0, ahiA);
        __syncthreads();                    // W(0) staged + visible
        int s = 0;
        while (true) {
            const bool hasB = (s + 1 < nk);
            if (hasB) { stage(s + 1, (s + 1) & 1); loadA(s + 1, ahiB); }
            loadWlds(s & 1, wh, wl);
            domfma(wh, wl, ahiA);
            __syncthreads();                // drain stage(s+1); protect buf reuse
            if (!hasB) break;
            s++;
            const bool hasA2 = (s + 1 < nk);
            if (hasA2) { stage(s + 1, (s + 1) & 1); loadA(s + 1, ahiA); }
            loadWlds(s & 1, wh, wl);
            domfma(wh, wl, ahiB);
            __syncthreads();
            if (!hasA2) break;
            s++;
        }
        // loop's trailing barrier = all A reads done before stores (in-place safe)
    } else {
        auto loadW = [&](int s, U8* wh, U8* wl) {
            const unsigned* pb = Phi + ((size_t)(s * NT + ctbase) * 64 + l) * 4;
            const unsigned* pl = Plo + ((size_t)(s * NT + ctbase) * 64 + l) * 4;
#pragma unroll
            for (int ct = 0; ct < NTW; ct++) {
                wh[ct] = *reinterpret_cast<const U8*>(pb + (size_t)ct * 256);
                wl[ct] = *reinterpret_cast<const U8*>(pl + (size_t)ct * 256);
            }
        };
        U8 whA[NTW], wlA[NTW], ahiA[2];
        U8 whB[NTW], wlB[NTW], ahiB[2];
        loadW(0, whA, wlA);
        loadA(0, ahiA);
        int s = 0;
        while (true) {
            const bool hasB = (s + 1 < nk);
            if (hasB) { loadW(s + 1, whB, wlB); loadA(s + 1, ahiB); }
            domfma(whA, wlA, ahiA);
            if (!hasB) break;
            const bool hasA2 = (s + 2 < nk);
            if (hasA2) { loadW(s + 2, whA, wlA); loadA(s + 2, ahiA); }
            domfma(whB, wlB, ahiB);
            if (!hasA2) break;
            s += 2;
        }
        __syncthreads();   // all A reads done before any store (in-place safe)
    }

#pragma unroll
    for (int f = 0; f < 2; f++) {
#pragma unroll
        for (int r = 0; r < 4; r++) {
            int row = row0 + 16 * f + 4 * g + r;
            if (row >= N) continue;   // uniform across l15 group (shfl-safe)
            int gi = (add != nullptr) ? addidx[row] : 0;
            float t0 = 0.f, t1 = 0.f, t2 = 0.f;
#pragma unroll
            for (int ct = 0; ct < NTW; ct++) {
                int col = (ctbase + ct) * 16 + l15;
                float o = acc[f][ct][r];
                if (add != nullptr) o += add[(size_t)gi * BN + col];
                if (sub != nullptr) o -= sub[col];
                if (flags) o = elu1(o + bias[col]);
                if (C != nullptr) C[(size_t)row * BN + col] = o;
                if (Cbf != nullptr) Cbf[(size_t)row * BN + col] = (unsigned short)f2bf(o);
                if (W3 != nullptr) {
                    t0 += o * W3[col * 3 + 0];
                    t1 += o * W3[col * 3 + 1];
                    t2 += o * W3[col * 3 + 2];
                }
            }
            if (W3 != nullptr) {
#pragma unroll
                for (int m = 1; m < 16; m <<= 1) {
                    t0 += __shfl_xor(t0, m);
                    t1 += __shfl_xor(t1, m);
                    t2 += __shfl_xor(t2, m);
                }
                if (l15 == 0) {
                    C3[(size_t)row * 3 + 0] = t0;
                    C3[(size_t)row * 3 + 1] = t1;
                    C3[(size_t)row * 3 + 2] = t2;
                }
            }
        }
    }
}

// ---------------- simple fc (small shapes) ----------------
template <int M, int RPT>
__global__ __launch_bounds__(256) void k_fc(
        const float* __restrict__ A, const float* __restrict__ W,
        const float* __restrict__ bias, const float* __restrict__ add,
        const int* __restrict__ addidx, float* __restrict__ C,
        int N, int K, int flags) {
    constexpr int TX = M / 4;
    constexpr int TY = 256 / TX;
    constexpr int RB = TY * RPT;
    int tx = threadIdx.x % TX;
    int ty = threadIdx.x / TX;
    int row0 = blockIdx.x * RB + ty * RPT;
    float4 acc[RPT];
#pragma unroll
    for (int r = 0; r < RPT; r++) acc[r] = make_float4(0.f, 0.f, 0.f, 0.f);
    for (int k = 0; k < K; k++) {
        float4 w = *reinterpret_cast<const float4*>(&W[(size_t)k * M + tx * 4]);
#pragma unroll
        for (int r = 0; r < RPT; r++) {
            int row = row0 + r;
            row = row < N ? row : N - 1;
            float a = A[(size_t)row * K + k];
            acc[r].x += a * w.x; acc[r].y += a * w.y;
            acc[r].z += a * w.z; acc[r].w += a * w.w;
        }
    }
    if (add != nullptr) {
#pragma unroll
        for (int r = 0; r < RPT; r++) {
            int row = row0 + r;
            if (row < N) {
                int g = addidx[row];
                const float4 v = *reinterpret_cast<const float4*>(&add[(size_t)g * M + tx * 4]);
                acc[r].x += v.x; acc[r].y += v.y; acc[r].z += v.z; acc[r].w += v.w;
            }
        }
    }
    __syncthreads();
    float4 b = make_float4(0.f, 0.f, 0.f, 0.f);
    if (flags) b = *reinterpret_cast<const float4*>(&bias[tx * 4]);
#pragma unroll
    for (int r = 0; r < RPT; r++) {
        int row = row0 + r;
        if (row >= N) break;
        float4 o = acc[r];
        o.x += b.x; o.y += b.y; o.z += b.z; o.w += b.w;
        if (flags) { o.x = elu1(o.x); o.y = elu1(o.y); o.z = elu1(o.z); o.w = elu1(o.w); }
        *reinterpret_cast<float4*>(&C[(size_t)row * M + tx * 4]) = o;
    }
}

// fused: lx = elu(lA @ WfL2 + bfL2) -> lB;  compO = lx @ WO1[256:] -> lA
__global__ __launch_bounds__(256) void k_fcl2(
        const float* __restrict__ A, const float* __restrict__ W1,
        const float* __restrict__ b1, const float* __restrict__ W2,
        float* __restrict__ lxout, float* __restrict__ compO) {
    __shared__ float lx[32][64];
    const int tid = threadIdx.x;
    const int tx = tid % 16, ty = tid / 16;
    const int row0b = blockIdx.x * 32;
    float4 acc[2];
    acc[0] = make_float4(0.f, 0.f, 0.f, 0.f);
    acc[1] = make_float4(0.f, 0.f, 0.f, 0.f);
    for (int k = 0; k < 64; k++) {
        float4 w = *reinterpret_cast<const float4*>(&W1[(size_t)k * 64 + tx * 4]);
#pragma unroll
        for (int r = 0; r < 2; r++) {
            float a = A[(size_t)(row0b + ty * 2 + r) * 64 + k];
            acc[r].x += a * w.x; acc[r].y += a * w.y;
            acc[r].z += a * w.z; acc[r].w += a * w.w;
        }
    }
    float4 b = *reinterpret_cast<const float4*>(&b1[tx * 4]);
#pragma unroll
    for (int r = 0; r < 2; r++) {
        int lr = ty * 2 + r;
        float4 o;
        o.x = elu1(acc[r].x + b.x); o.y = elu1(acc[r].y + b.y);
        o.z = elu1(acc[r].z + b.z); o.w = elu1(acc[r].w + b.w);
        *reinterpret_cast<float4*>(&lxout[(size_t)(row0b + lr) * 64 + tx * 4]) = o;
        lx[lr][tx * 4 + 0] = o.x; lx[lr][tx * 4 + 1] = o.y;
        lx[lr][tx * 4 + 2] = o.z; lx[lr][tx * 4 + 3] = o.w;
    }
    __syncthreads();
    for (int o = tid; o < 32 * 128; o += 256) {
        int r = o >> 7, c = o & 127;
        float s = 0.f;
        for (int k = 0; k < 64; k++) s += lx[r][k] * W2[(size_t)k * 128 + c];
        compO[(size_t)(row0b + r) * 128 + c] = s;
    }
}

// ---------------- instance norm stats (bf16 input) ----------------
__global__ void k_instats(const unsigned short* __restrict__ h, float* __restrict__ sum,
                          float* __restrict__ sumsq, int n) {
    int c = threadIdx.x;
    int r0 = blockIdx.x * 128;
    int r1 = r0 + 128 < n ? r0 + 128 : n;
    float s = 0.f, q = 0.f;
#pragma unroll 4
    for (int r = r0; r < r1; r++) {
        float v = bf2f(h[(size_t)r * 256 + c]);
        s += v; q += v * v;
    }
    atomicAdd(&sum[c], s);
    atomicAdd(&sumsq[c], q);
}

// ---- merged: cluster poolavg + pooledges ----
__global__ __launch_bounds__(256) void k_poolmerge(
        const unsigned short* __restrict__ xh, const int* __restrict__ crowptr,
        const int* __restrict__ cdeg, const int* __restrict__ cnodes,
        const float* __restrict__ mu, const float* __restrict__ rstd,
        float* __restrict__ px,
        const int* __restrict__ src, const int* __restrict__ dst,
        const int* __restrict__ bc, unsigned char* __restrict__ bmT, int E) {
    int bid = blockIdx.x;
    if (bid < NCLUST) {
        int cl = bid;
        int c  = threadIdx.x;
        int start = crowptr[cl];
        int cnt = cdeg[cl];
        float acc = 0.f;
        int j = 0;
        for (; j + 3 < cnt; j += 4) {       // 4 independent gathers (ILP)
            int n0 = cnodes[start + j + 0];
            int n1 = cnodes[start + j + 1];
            int n2 = cnodes[start + j + 2];
            int n3 = cnodes[start + j + 3];
            float v0 = bf2f(xh[(size_t)n0 * 256 + c]);
            float v1 = bf2f(xh[(size_t)n1 * 256 + c]);
            float v2 = bf2f(xh[(size_t)n2 * 256 + c]);
            float v3 = bf2f(xh[(size_t)n3 * 256 + c]);
            acc += (v0 + v1) + (v2 + v3);
        }
        for (; j < cnt; j++) {
            int node = cnodes[start + j];
            acc += bf2f(xh[(size_t)node * 256 + c]);
        }
        float res = acc / fmaxf((float)cnt, 1.0f);
        res = (cnt > 0) ? (res - mu[c]) * rstd[c] : 0.f;
        px[(size_t)cl * 256 + c] = res;
    } else {
        int e = (bid - NCLUST) * 256 + threadIdx.x;
        if (e < E) {
            int ps = bc[src[e]];
            int pd = bc[dst[e]];
            bmT[(size_t)pd * NCLUST + ps] = 1;
        }
    }
}

__global__ __launch_bounds__(256) void k_pooldeg(
        const unsigned char* __restrict__ bmT, float* __restrict__ dinvp) {
    int d = blockIdx.x;
    int t = threadIdx.x;
    const unsigned int v = reinterpret_cast<const unsigned int*>(bmT + (size_t)d * NCLUST)[t];
    int s = (v & 0xff) + ((v >> 8) & 0xff) + ((v >> 16) & 0xff) + ((v >> 24) & 0xff);
    if (t == (d >> 2)) s -= (v >> ((d & 3) * 8)) & 0xff;
    __shared__ int red[256];
    red[t] = s; __syncthreads();
    for (int o = 128; o > 0; o >>= 1) {
        if (t < o) red[t] += red[t + o];
        __syncthreads();
    }
    if (t == 0) dinvp[d] = rsqrtf((float)red[0] + 1.0f);
}

template <int F>
__global__ __launch_bounds__(1024) void k_proppool2(
        const float* __restrict__ h, const float* __restrict__ dinvp,
        const unsigned char* __restrict__ bmT, const float* __restrict__ bias,
        float* __restrict__ out) {
    constexpr int SG = 1024 / F;
    const int d = blockIdx.x;
    const int t = threadIdx.x;
    const int f = t & (F - 1);
    const int sg = t / F;
    const unsigned char* bmrow = bmT + (size_t)d * NCLUST;
    float acc = 0.f;
#pragma unroll 4
    for (int s = sg; s < NCLUST; s += SG) {
        float m = (s != d) ? (float)bmrow[s] : 0.f;
        acc += m * dinvp[s] * h[(size_t)s * F + f];
    }
    __shared__ float red[1024];
    red[t] = acc; __syncthreads();
#pragma unroll
    for (int o = SG / 2; o > 0; o >>= 1) {
        if (sg < o) red[t] += red[t + o * F];
        __syncthreads();
    }
    if (sg == 0) {
        float di = dinvp[d];
        float r = di * red[f] + di * di * h[(size_t)d * F + f] + bias[f];
        out[(size_t)d * F + f] = elu1(r);
    }
}

// ---------------------------------------------------------------------------
extern "C" void kernel_launch(void* const* d_in, const int* in_sizes, int n_in,
                              void* d_out, int out_size, void* d_ws, size_t ws_size,
                              hipStream_t stream) {
    const float* x       = (const float*)d_in[0];
    const int*   adj     = (const int*)d_in[1];
    const int*   inb     = (const int*)d_in[3];
    const int*   cluster = (const int*)d_in[4];
    const float* WG1  = (const float*)d_in[5];   const float* bG1  = (const float*)d_in[6];
    const float* WfG1 = (const float*)d_in[7];   const float* bfG1 = (const float*)d_in[8];
    const float* WG2  = (const float*)d_in[9];   const float* bG2  = (const float*)d_in[10];
    const float* WfG2 = (const float*)d_in[11];  const float* bfG2 = (const float*)d_in[12];
    const float* WL1  = (const float*)d_in[13];  const float* bL1  = (const float*)d_in[14];
    const float* WfL1 = (const float*)d_in[15];  const float* bfL1 = (const float*)d_in[16];
    const float* WL2  = (const float*)d_in[17];  const float* bL2  = (const float*)d_in[18];
    const float* WfL2 = (const float*)d_in[19];  const float* bfL2 = (const float*)d_in[20];
    const float* WO1  = (const float*)d_in[21];  const float* bO1  = (const float*)d_in[22];
    const float* WfO1 = (const float*)d_in[23];  const float* bfO1 = (const float*)d_in[24];
    const float* WO2  = (const float*)d_in[25];  const float* bO2  = (const float*)d_in[26];
    const float* WfO2 = (const float*)d_in[27];  const float* bfO2 = (const float*)d_in[28];
    const float* WO3  = (const float*)d_in[29];  const float* bO3  = (const float*)d_in[30];
    const float* WfO3 = (const float*)d_in[31];  const float* bfO3 = (const float*)d_in[32];
    float* out = (float*)d_out;

    const int n = in_sizes[0] / 3;       // 100000
    const int E = in_sizes[1] / 2;       // 1600000
    const int* src = adj;
    const int* dst = adj + E;

    // ---- workspace carve ----
    char* ws = (char*)d_ws;
    size_t off = 0;
    auto alloc = [&](size_t bytes) -> void* {
        void* p = ws + off;
        off = (off + bytes + 255) & ~(size_t)255;
        return p;
    };
    int*   deg     = (int*)alloc((size_t)n * 4);     // zero span 1 start
    int*   fill    = (int*)alloc((size_t)n * 4);
    int*   cdeg    = (int*)alloc(NCLUST * 4);
    int*   cfill   = (int*)alloc(NCLUST * 4);
    int*   rowptr  = (int*)alloc((size_t)n * 4);     // zero span 1 end (exclusive)
    int*   crowptr = (int*)alloc(NCLUST * 4);
    int*   cnodes  = (int*)alloc((size_t)n * 4);
    int*   bcarr   = (int*)alloc((size_t)n * 4);
    float* dinv    = (float*)alloc((size_t)n * 4);
    int*   bsum    = (int*)alloc(512);
    int2*  csr_ev  = (int2*)alloc((size_t)E * 8);
    float* X       = (float*)alloc((size_t)n * 256 * 4);
    unsigned short* Xh = (unsigned short*)alloc((size_t)n * 256 * 2);
    float* B       = (float*)alloc((size_t)n * 128 * 4);
    unsigned short* Bh = (unsigned short*)alloc((size_t)n * 128 * 2);
    float* insum   = (float*)alloc(256 * 4);         // zero span 2 start
    float* insumsq = (float*)alloc(256 * 4);
    float* px      = (float*)alloc((size_t)NCLUST * 256 * 4);
    unsigned char* bmT = (unsigned char*)alloc((size_t)NCLUST * NCLUST);
    float* corr    = (float*)alloc(128 * 4);
    float* mu      = (float*)alloc(256 * 4);         // zero span 2 end (exclusive)
    float* rstd    = (float*)alloc(256 * 4);
    float* dinvp   = (float*)alloc(NCLUST * 4);
    float* lA      = (float*)alloc((size_t)NCLUST * 128 * 4);
    float* lB      = (float*)alloc((size_t)NCLUST * 128 * 4);
    unsigned* pfG1h = (unsigned*)alloc(2048 * 4);   unsigned* pfG1l = (unsigned*)alloc(2048 * 4);
    unsigned* pG2h  = (unsigned*)alloc(8192 * 4);   unsigned* pG2l  = (unsigned*)alloc(8192 * 4);
    unsigned* pfG2h = (unsigned*)alloc(32768 * 4);  unsigned* pfG2l = (unsigned*)alloc(32768 * 4);
    unsigned* pO1h  = (unsigned*)alloc(16384 * 4);  unsigned* pO1l  = (unsigned*)alloc(16384 * 4);
    unsigned* pfO1h = (unsigned*)alloc(8192 * 4);   unsigned* pfO1l = (unsigned*)alloc(8192 * 4);
    unsigned* pO2h  = (unsigned*)alloc(2048 * 4);   unsigned* pO2l  = (unsigned*)alloc(2048 * 4);
    unsigned* pfO2h = (unsigned*)alloc(512 * 4);    unsigned* pfO2l = (unsigned*)alloc(512 * 4);
    (void)ws_size; (void)n_in; (void)out_size;

    unsigned short* Bh1 = Bh;                        // h1/h2 (n x 64 bf16)
    unsigned short* Bh2 = Bh + (size_t)n * 64;       // p64 (n x 64 bf16)

    auto cdiv = [](int a, int b) { return (a + b - 1) / b; };
    const int EB = cdiv(E, 256);
    const int PB = cdiv(n, 4);

    // ---- init: zero scratch + pack all static weights (ONE launch) ----
    int nz1 = (int)(((char*)rowptr - (char*)deg) / 16);
    int nz2 = (int)(((char*)mu - (char*)insum) / 16);
    InitArgs ia;
    ia.d[0] = {WfG1, pfG1h, pfG1l, 64, 64, 0};
    ia.d[1] = {WG2,  pG2h,  pG2l,  64, 256, 512};
    ia.d[2] = {WfG2, pfG2h, pfG2l, 256, 256, 2560};
    ia.d[3] = {WfO1, pfO1h, pfO1l, 128, 128, 10752};
    ia.d[4] = {WO2,  pO2h,  pO2l,  128, 32, 12800};
    ia.d[5] = {WfO2, pfO2h, pfO2l, 32, 32, 13312};
    ia.tot = 13440;
    ia.z1 = (int4*)deg; ia.nz1 = nz1;
    ia.z2 = (int4*)insum; ia.nz2 = nz2;
    int initN = (nz1 + nz2 > ia.tot) ? (nz1 + nz2) : ia.tot;
    k_init<<<cdiv(initN, 256), 256, 0, stream>>>(ia);

    // ---- CSR build ----
    k_hist<<<EB, 256, 0, stream>>>(dst, deg, E);
    int nb = cdiv(n, 1024);
    k_scan_block<<<nb, 256, 0, stream>>>(deg, rowptr, bsum, n);
    k_nodeinit<<<cdiv(n, 256), 256, 0, stream>>>(rowptr, bsum, deg, cluster, inb,
                                                 dinv, bcarr, cdeg, n, nb);
    k_scan_block<<<1, 256, 0, stream>>>(cdeg, crowptr, bsum, NCLUST);
    k_fillc<<<EB, 256, 0, stream>>>(src, dst, dinv, rowptr, fill, csr_ev, E,
                                    bcarr, crowptr, cfill, cnodes, n);

    // ---- global GCN stack (all bf16 activations) ----
    // p3 + fused fc<64>: h1 -> bf16 Bh1
    k_prop3f1<<<cdiv(n, 256), 256, 0, stream>>>(x, dinv, rowptr, deg, csr_ev,
                                                WG1, bG1, Bh1, n);
    // h2 = elu(h1 @ WfG1 + bfG1)  (Bh1 in-place, register-W)  [8-wave]
    k_gmfma<64, 8, 0><<<cdiv(n, 256), 512, 0, stream>>>(Bh1, pfG1h, pfG1l, bfG1,
                                                        nullptr, nullptr, nullptr,
                                                        nullptr, Bh1, nullptr, nullptr,
                                                        n, 64, 1);
    // p64 = S h2  (bf16 gather -> bf16 Bh2)
    k_prop4sb<64, 1><<<PB, 256, 0, stream>>>(Bh1, dinv, rowptr, deg, csr_ev,
                                             nullptr, nullptr, Bh2, n, 0);
    // h3 = elu(p64 @ WG2 + bG2) -> bf16 (Xh)  [FULLW=32: 32KB, 4 blk/CU]
    k_gmfma<256, 8, 32><<<cdiv(n, 64), 512, 0, stream>>>(Bh2, pG2h, pG2l, bG2,
                                                         nullptr, nullptr, nullptr,
                                                         nullptr, Xh, nullptr, nullptr,
                                                         n, 64, 1);
    // h4 = elu(h3 @ WfG2 + bfG2)  (Xh in-place)  [FULLW=32: 32KB, 4 blk/CU]
    k_gmfma<256, 8, 32><<<cdiv(n, 64), 512, 0, stream>>>(Xh, pfG2h, pfG2l, bfG2,
                                                         nullptr, nullptr, nullptr,
                                                         nullptr, Xh, nullptr, nullptr,
                                                         n, 256, 1);

    // ---- instance norm stats + merged finalize/pack/corr ----
    k_instats<<<cdiv(n, 128), 256, 0, stream>>>(Xh, insum, insumsq, n);
    k_normprep<<<17, 256, 0, stream>>>(WO1, insum, insumsq, pO1h, pO1l, corr, mu, rstd, n);

    // ---- cluster pooling (poolavg + pooledges merged) ----
    k_poolmerge<<<NCLUST + EB, 256, 0, stream>>>(Xh, crowptr, cdeg, cnodes, mu, rstd, px,
                                                 src, dst, bcarr, bmT, E);
    k_pooldeg<<<NCLUST, 256, 0, stream>>>(bmT, dinvp);

    // ---- local (pooled) GCN stack ----
    k_fc<128, 2><<<cdiv(NCLUST, 16), 256, 0, stream>>>(px, WL1, nullptr, nullptr, nullptr,
                                                       lA, NCLUST, 256, 0);
    k_proppool2<128><<<NCLUST, 1024, 0, stream>>>(lA, dinvp, bmT, bL1, lB);
    k_fc<128, 2><<<cdiv(NCLUST, 16), 256, 0, stream>>>(lB, WfL1, bfL1, nullptr, nullptr,
                                                       lA, NCLUST, 128, 1);
    k_fc<64, 2><<<cdiv(NCLUST, 32), 256, 0, stream>>>(lA, WL2, nullptr, nullptr, nullptr,
                                                      lB, NCLUST, 128, 0);
    k_proppool2<64><<<NCLUST, 1024, 0, stream>>>(lB, dinvp, bmT, bL2, lA);
    // fused: lx = elu(lA @ WfL2 + bfL2) -> lB; compO = lx @ WO1[256:] -> lA
    k_fcl2<<<NCLUST / 32, 256, 0, stream>>>(lA, WfL2, bfL2, WO1 + (size_t)256 * 128,
                                            lB, lA);

    // ---- output GCN stack ----
    // t1 = Xh @ (rstd*WO1) - corr + compO[bc] -> bf16 (Bh)  [FULLW=64: 4 chunks]
    k_gmfma<128, 8, 64><<<cdiv(n, 128), 512, 0, stream>>>(Xh, pO1h, pO1l, nullptr,
                                                          corr, lA, bcarr, nullptr, Bh,
                                                          nullptr, nullptr, n, 256, 0);
    k_prop4sb<128, 1><<<PB, 256, 0, stream>>>(Bh, dinv, rowptr, deg, csr_ev,
                                              bO1, nullptr, Xh, n, 1);
    // o2 = elu(o1 @ WfO1 + bfO1)  (Xh in-place)  [FULLW=64: 2 chunks]
    k_gmfma<128, 8, 64><<<cdiv(n, 128), 512, 0, stream>>>(Xh, pfO1h, pfO1l, bfO1,
                                                          nullptr, nullptr, nullptr,
                                                          nullptr, Xh, nullptr, nullptr,
                                                          n, 128, 1);
    // t2 = o2 @ WO2  -> bf16 (Bh, N x 32)  [register-W, 8-wave]
    k_gmfma<32, 8, 0><<<cdiv(n, 256), 512, 0, stream>>>(Xh, pO2h, pO2l, nullptr,
                                                        nullptr, nullptr, nullptr,
                                                        nullptr, Bh, nullptr, nullptr,
                                                        n, 128, 0);
    k_prop4sb<32, 1><<<PB, 256, 0, stream>>>(Bh, dinv, rowptr, deg, csr_ev,
                                             bO2, nullptr, Xh, n, 1);
    // o4 = elu(o3 @ WfO2 + bfO2); t3 = o4 @ WO3 fused -> B (N x 3 f32)
    k_gmfma<32, 8, 0><<<cdiv(n, 256), 512, 0, stream>>>(Xh, pfO2h, pfO2l, bfO2,
                                                        nullptr, nullptr, nullptr,
                                                        nullptr, nullptr, WO3, B,
                                                        n, 32, 1);
    // o5 = elu(S t3 + bO3); out = elu(o5 @ WfO3 + bfO3)  (fused)
    k_prop3out<<<cdiv(n, 256), 256, 0, stream>>>(B, dinv, rowptr, deg, csr_ev,
                                                 bO3, WfO3, bfO3, out, n);
}

// Round 31
// 1046.153 us; speedup vs baseline: 1.0844x; 1.0054x over previous
//
#include <hip/hip_runtime.h>

// ---------------------------------------------------------------------------
// GCN3D. R9: split-bf16 MFMA GEMMs. R13: prop4s+norm-fold. R14/15/17/23: bf16
// activations everywhere. R17/R20/R21/R22: launch merging, int2 edges.
// R24: LDS-W staging. R26/R27: FULLW chunked k-loops. R29/R30: FULLW=32
//   (4 blk/CU) for all big GEMMs + prop gather unroll x2 (1052us best).
// R31: push the two live mechanisms: prop4sb gather unroll x2 -> x4 (4
//   independent row fetches in flight, tail loop); prop3f1/prop3out edge
//   loop unroll x2 (same serial-chain structure, L2-resident rows).
// ---------------------------------------------------------------------------

#define NCLUST 1024

typedef short bf16x8 __attribute__((ext_vector_type(8)));
typedef float f32x4 __attribute__((ext_vector_type(4)));

__device__ __forceinline__ float elu1(float x) { return x > 0.f ? x : expm1f(x); }

__device__ __forceinline__ unsigned f2bf(float f) {
    union { float f; unsigned u; } c; c.f = f;
    unsigned u = c.u;
    return (u + 0x7fffu + ((u >> 16) & 1u)) >> 16;
}
__device__ __forceinline__ float bf2f(unsigned h) {
    union { unsigned u; float f; } c; c.u = h << 16; return c.f;
}

union U8 { unsigned u[4]; bf16x8 v; };

// ---- W pre-pack body ----
__device__ __forceinline__ void wpack_body(const float* W, unsigned* Phi, unsigned* Plo,
                                           int K, int BN, int t) {
    int NT = BN / 16;
    int lane = t & 63;
    int rest = t >> 6;
    int ct = rest % NT;
    int s = rest / NT;
    int col = ct * 16 + (lane & 15);
    int g = lane >> 4;
    int k0 = s * 32;
    float e[8];
#pragma unroll
    for (int j = 0; j < 4; j++) {
        e[j]     = W[(size_t)(k0 + 4 * g + j) * BN + col];
        e[4 + j] = W[(size_t)(k0 + 16 + 4 * g + j) * BN + col];
    }
#pragma unroll
    for (int j = 0; j < 4; j++) {
        unsigned h0 = f2bf(e[2 * j]), h1 = f2bf(e[2 * j + 1]);
        Phi[(size_t)t * 4 + j] = h0 | (h1 << 16);
        unsigned l0 = f2bf(e[2 * j] - bf2f(h0));
        unsigned l1 = f2bf(e[2 * j + 1] - bf2f(h1));
        Plo[(size_t)t * 4 + j] = l0 | (l1 << 16);
    }
}

struct PackDesc { const float* W; unsigned* Ph; unsigned* Pl; int K, BN, tbase; };
struct InitArgs {
    PackDesc d[6]; int tot;
    int4* z1; int nz1; int4* z2; int nz2;
};

__global__ void k_init(InitArgs a) {
    int t = blockIdx.x * 256 + threadIdx.x;
    if (t < a.nz1) a.z1[t] = make_int4(0, 0, 0, 0);
    else if (t - a.nz1 < a.nz2) a.z2[t - a.nz1] = make_int4(0, 0, 0, 0);
    if (t < a.tot) {
        int i = 0;
#pragma unroll
        for (int j = 1; j < 6; j++) if (t >= a.d[j].tbase) i = j;
        wpack_body(a.d[i].W, a.d[i].Ph, a.d[i].Pl, a.d[i].K, a.d[i].BN,
                   t - a.d[i].tbase);
    }
}

// ---------------- CSR build ----------------
__global__ void k_hist(const int* __restrict__ key, int* __restrict__ deg, int E) {
    int e = blockIdx.x * 256 + threadIdx.x;
    if (e < E) atomicAdd(&deg[key[e]], 1);
}

__global__ void k_scan_block(const int* __restrict__ deg, int* __restrict__ rowptr,
                             int* __restrict__ bsum, int n) {
    __shared__ int lds[256];
    int tid = threadIdx.x;
    int base = blockIdx.x * 1024 + tid * 4;
    int v0 = base + 0 < n ? deg[base + 0] : 0;
    int v1 = base + 1 < n ? deg[base + 1] : 0;
    int v2 = base + 2 < n ? deg[base + 2] : 0;
    int v3 = base + 3 < n ? deg[base + 3] : 0;
    int tsum = v0 + v1 + v2 + v3;
    lds[tid] = tsum; __syncthreads();
    for (int off = 1; off < 256; off <<= 1) {
        int t = (tid >= off) ? lds[tid - off] : 0;
        __syncthreads();
        lds[tid] += t;
        __syncthreads();
    }
    int run = lds[tid] - tsum;
    if (base + 0 < n) rowptr[base + 0] = run; run += v0;
    if (base + 1 < n) rowptr[base + 1] = run; run += v1;
    if (base + 2 < n) rowptr[base + 2] = run; run += v2;
    if (base + 3 < n) rowptr[base + 3] = run;
    if (tid == 255) bsum[blockIdx.x] = lds[255];
}

// merged: bsum scan + rowptr finalize + dinv + bc + cluster hist
__global__ void k_nodeinit(int* __restrict__ rowptr, const int* __restrict__ bsum,
                           const int* __restrict__ deg, const int* __restrict__ cluster,
                           const int* __restrict__ inb, float* __restrict__ dinv,
                           int* __restrict__ bc, int* __restrict__ cdeg, int n, int nb) {
    __shared__ int pfx[128];
    int tid = threadIdx.x;
    if (tid < 128) pfx[tid] = (tid < nb) ? bsum[tid] : 0;
    __syncthreads();
    for (int off = 1; off < 128; off <<= 1) {
        int v = 0;
        if (tid < 128 && tid >= off) v = pfx[tid - off];
        __syncthreads();
        if (tid < 128) pfx[tid] += v;
        __syncthreads();
    }
    int i = blockIdx.x * 256 + tid;
    if (i >= n) return;
    int j = i >> 10;
    int base = (j == 0) ? 0 : pfx[j - 1];
    rowptr[i] += base;
    dinv[i] = rsqrtf((float)deg[i] + 1.0f);
    int c = cluster[i] + inb[i] * NCLUST;
    bc[i] = c;
    atomicAdd(&cdeg[c], 1);
}

// merged: edge CSR fill (packed int2) + cluster member fill
__global__ void k_fillc(const int* __restrict__ src, const int* __restrict__ dst,
                        const float* __restrict__ dinv, const int* __restrict__ rowptr,
                        int* __restrict__ fill, int2* __restrict__ csr_ev, int E,
                        const int* __restrict__ bc, const int* __restrict__ crowptr,
                        int* __restrict__ cfill, int* __restrict__ cnodes, int n) {
    int e = blockIdx.x * 256 + threadIdx.x;
    if (e < E) {
        int d = dst[e];
        int pos = rowptr[d] + atomicAdd(&fill[d], 1);
        int s = src[e];
        csr_ev[pos] = make_int2(s, __float_as_int(dinv[s]));
    }
    if (e < n) {
        int c = bc[e];
        int pos = crowptr[c] + atomicAdd(&cfill[c], 1);
        cnodes[pos] = e;
    }
}

// ------ GCN propagation, bf16 input; OB=0 f32 out, OB=1 bf16 out ------
// Edge loop unrolled x4: four independent row-gathers in flight per iter.
template <int F, int OB>
__global__ __launch_bounds__(256) void k_prop4sb(
        const unsigned short* __restrict__ hbf, const float* __restrict__ dinv,
        const int* __restrict__ rowptr, const int* __restrict__ deg,
        const int2* __restrict__ csr_ev,
        const float* __restrict__ bias, float* __restrict__ outf,
        unsigned short* __restrict__ outb, int n, int flags) {
    constexpr int FS = F / 4;
    constexpr int ES = 64 / FS;
    const int node = (blockIdx.x * 256 + threadIdx.x) >> 6;
    if (node >= n) return;
    const int l = threadIdx.x & 63;
    const int fs = l & (FS - 1);
    const int ep = l / FS;
    const int fi = fs * 4;
    const int start = rowptr[node];
    const int cnt = deg[node];
    float ax = 0.f, ay = 0.f, az = 0.f, aw = 0.f;
    int j = ep;
    for (; j + 3 * ES < cnt; j += 4 * ES) {
        const int2 ev0 = csr_ev[start + j];
        const int2 ev1 = csr_ev[start + j + ES];
        const int2 ev2 = csr_ev[start + j + 2 * ES];
        const int2 ev3 = csr_ev[start + j + 3 * ES];
        float w0 = __int_as_float(ev0.y);
        float w1 = __int_as_float(ev1.y);
        float w2 = __int_as_float(ev2.y);
        float w3 = __int_as_float(ev3.y);
        const ushort4 v0 = *reinterpret_cast<const ushort4*>(&hbf[(size_t)ev0.x * F + fi]);
        const ushort4 v1 = *reinterpret_cast<const ushort4*>(&hbf[(size_t)ev1.x * F + fi]);
        const ushort4 v2 = *reinterpret_cast<const ushort4*>(&hbf[(size_t)ev2.x * F + fi]);
        const ushort4 v3 = *reinterpret_cast<const ushort4*>(&hbf[(size_t)ev3.x * F + fi]);
        ax += (w0 * bf2f(v0.x) + w1 * bf2f(v1.x)) + (w2 * bf2f(v2.x) + w3 * bf2f(v3.x));
        ay += (w0 * bf2f(v0.y) + w1 * bf2f(v1.y)) + (w2 * bf2f(v2.y) + w3 * bf2f(v3.y));
        az += (w0 * bf2f(v0.z) + w1 * bf2f(v1.z)) + (w2 * bf2f(v2.z) + w3 * bf2f(v3.z));
        aw += (w0 * bf2f(v0.w) + w1 * bf2f(v1.w)) + (w2 * bf2f(v2.w) + w3 * bf2f(v3.w));
    }
    for (; j < cnt; j += ES) {
        const int2 ev = csr_ev[start + j];
        float w = __int_as_float(ev.y);
        const ushort4 v = *reinterpret_cast<const ushort4*>(&hbf[(size_t)ev.x * F + fi]);
        ax += w * bf2f(v.x); ay += w * bf2f(v.y);
        az += w * bf2f(v.z); aw += w * bf2f(v.w);
    }
#pragma unroll
    for (int off = FS; off < 64; off <<= 1) {
        ax += __shfl_xor(ax, off);
        ay += __shfl_xor(ay, off);
        az += __shfl_xor(az, off);
        aw += __shfl_xor(aw, off);
    }
    if (ep == 0) {
        float di = dinv[node];
        const ushort4 sv = *reinterpret_cast<const ushort4*>(&hbf[(size_t)node * F + fi]);
        float4 o;
        o.x = di * ax + di * di * bf2f(sv.x);
        o.y = di * ay + di * di * bf2f(sv.y);
        o.z = di * az + di * di * bf2f(sv.z);
        o.w = di * aw + di * di * bf2f(sv.w);
        if (flags) {
            const float4 b = *reinterpret_cast<const float4*>(&bias[fi]);
            o.x = elu1(o.x + b.x); o.y = elu1(o.y + b.y);
            o.z = elu1(o.z + b.z); o.w = elu1(o.w + b.w);
        }
        if constexpr (OB) {
            ushort4 ob;
            ob.x = (unsigned short)f2bf(o.x); ob.y = (unsigned short)f2bf(o.y);
            ob.z = (unsigned short)f2bf(o.z); ob.w = (unsigned short)f2bf(o.w);
            *reinterpret_cast<ushort4*>(&outb[(size_t)node * F + fi]) = ob;
        } else {
            *reinterpret_cast<float4*>(&outf[(size_t)node * F + fi]) = o;
        }
    }
}

// prop3 on x + fused fc<64> -> bf16 out (N x 64); edge loop unrolled x2
__global__ void k_prop3f1(const float* __restrict__ h, const float* __restrict__ dinv,
                          const int* __restrict__ rowptr, const int* __restrict__ deg,
                          const int2* __restrict__ csr_ev,
                          const float* __restrict__ WG1, const float* __restrict__ bG1,
                          unsigned short* __restrict__ outb, int n) {
    int node = blockIdx.x * 256 + threadIdx.x;
    if (node >= n) return;
    int start = rowptr[node], cnt = deg[node];
    float a0 = 0.f, a1 = 0.f, a2 = 0.f;
    int j = 0;
    for (; j + 1 < cnt; j += 2) {
        const int2 ev0 = csr_ev[start + j];
        const int2 ev1 = csr_ev[start + j + 1];
        float w0 = __int_as_float(ev0.y);
        float w1 = __int_as_float(ev1.y);
        const float* r0 = h + (size_t)ev0.x * 3;
        const float* r1 = h + (size_t)ev1.x * 3;
        a0 += w0 * r0[0] + w1 * r1[0];
        a1 += w0 * r0[1] + w1 * r1[1];
        a2 += w0 * r0[2] + w1 * r1[2];
    }
    if (j < cnt) {
        const int2 ev = csr_ev[start + j];
        float w = __int_as_float(ev.y);
        const float* r = h + (size_t)ev.x * 3;
        a0 += w * r[0]; a1 += w * r[1]; a2 += w * r[2];
    }
    float di = dinv[node];
    float p0 = di * a0 + di * di * h[(size_t)node * 3 + 0];
    float p1 = di * a1 + di * di * h[(size_t)node * 3 + 1];
    float p2 = di * a2 + di * di * h[(size_t)node * 3 + 2];
    unsigned short* op = outb + (size_t)node * 64;
#pragma unroll 4
    for (int c = 0; c < 64; c += 4) {
        ushort4 ob;
        ob.x = (unsigned short)f2bf(elu1(p0 * WG1[c + 0] + p1 * WG1[64 + c + 0] + p2 * WG1[128 + c + 0] + bG1[c + 0]));
        ob.y = (unsigned short)f2bf(elu1(p0 * WG1[c + 1] + p1 * WG1[64 + c + 1] + p2 * WG1[128 + c + 1] + bG1[c + 1]));
        ob.z = (unsigned short)f2bf(elu1(p0 * WG1[c + 2] + p1 * WG1[64 + c + 2] + p2 * WG1[128 + c + 2] + bG1[c + 2]));
        ob.w = (unsigned short)f2bf(elu1(p0 * WG1[c + 3] + p1 * WG1[64 + c + 3] + p2 * WG1[128 + c + 3] + bG1[c + 3]));
        *reinterpret_cast<ushort4*>(op + c) = ob;
    }
}

// prop3 on t3 (+bO3, elu) + fused final fc3; edge loop unrolled x2
__global__ void k_prop3out(const float* __restrict__ h, const float* __restrict__ dinv,
                           const int* __restrict__ rowptr, const int* __restrict__ deg,
                           const int2* __restrict__ csr_ev,
                           const float* __restrict__ bO3, const float* __restrict__ WfO3,
                           const float* __restrict__ bfO3, float* __restrict__ out, int n) {
    int node = blockIdx.x * 256 + threadIdx.x;
    if (node >= n) return;
    int start = rowptr[node], cnt = deg[node];
    float a0 = 0.f, a1 = 0.f, a2 = 0.f;
    int j = 0;
    for (; j + 1 < cnt; j += 2) {
        const int2 ev0 = csr_ev[start + j];
        const int2 ev1 = csr_ev[start + j + 1];
        float w0 = __int_as_float(ev0.y);
        float w1 = __int_as_float(ev1.y);
        const float* r0 = h + (size_t)ev0.x * 3;
        const float* r1 = h + (size_t)ev1.x * 3;
        a0 += w0 * r0[0] + w1 * r1[0];
        a1 += w0 * r0[1] + w1 * r1[1];
        a2 += w0 * r0[2] + w1 * r1[2];
    }
    if (j < cnt) {
        const int2 ev = csr_ev[start + j];
        float w = __int_as_float(ev.y);
        const float* r = h + (size_t)ev.x * 3;
        a0 += w * r[0]; a1 += w * r[1]; a2 += w * r[2];
    }
    float di = dinv[node];
    float o0 = elu1(di * a0 + di * di * h[(size_t)node * 3 + 0] + bO3[0]);
    float o1 = elu1(di * a1 + di * di * h[(size_t)node * 3 + 1] + bO3[1]);
    float o2 = elu1(di * a2 + di * di * h[(size_t)node * 3 + 2] + bO3[2]);
#pragma unroll
    for (int c = 0; c < 3; c++) {
        out[(size_t)node * 3 + c] =
            elu1(o0 * WfO3[c] + o1 * WfO3[3 + c] + o2 * WfO3[6 + c] + bfO3[c]);
    }
}

// ---- merged: infinal + rstd-scaled WO1 pack + corr (17 blocks x 256) ----
__global__ void k_normprep(const float* __restrict__ W, const float* __restrict__ insum,
                           const float* __restrict__ insumsq, unsigned* __restrict__ Phi,
                           unsigned* __restrict__ Plo, float* __restrict__ corr,
                           float* __restrict__ mu, float* __restrict__ rstd, int n) {
    const float fn = (float)n;
    const int bid = blockIdx.x, tid = threadIdx.x;
    if (bid == 16) {
        float m = insum[tid] / fn;
        float var = insumsq[tid] / fn - m * m;
        mu[tid] = m;
        rstd[tid] = rsqrtf(var + 1e-5f);
        return;
    }
    {
        int t = bid * 256 + tid;
        int lane = t & 63, rest = t >> 6;
        int ct = rest % 8, s = rest / 8;
        int col = ct * 16 + (lane & 15);
        int g = lane >> 4;
        int k0 = s * 32;
        float e[8];
#pragma unroll
        for (int j = 0; j < 4; j++) {
            int ka = k0 + 4 * g + j;
            int kb = k0 + 16 + 4 * g + j;
            float ma = insum[ka] / fn;
            float sa = rsqrtf(insumsq[ka] / fn - ma * ma + 1e-5f);
            float mb = insum[kb] / fn;
            float sb = rsqrtf(insumsq[kb] / fn - mb * mb + 1e-5f);
            e[j]     = W[(size_t)ka * 128 + col] * sa;
            e[4 + j] = W[(size_t)kb * 128 + col] * sb;
        }
#pragma unroll
        for (int j = 0; j < 4; j++) {
            unsigned h0 = f2bf(e[2 * j]), h1 = f2bf(e[2 * j + 1]);
            Phi[(size_t)t * 4 + j] = h0 | (h1 << 16);
            unsigned l0 = f2bf(e[2 * j] - bf2f(h0));
            unsigned l1 = f2bf(e[2 * j + 1] - bf2f(h1));
            Plo[(size_t)t * 4 + j] = l0 | (l1 << 16);
        }
    }
    if (tid < 128) {
        int k0 = bid * 16;
        float s = 0.f;
        for (int k = k0; k < k0 + 16; k++) {
            float m = insum[k] / fn;
            float r = rsqrtf(insumsq[k] / fn - m * m + 1e-5f);
            s += m * r * W[(size_t)k * 128 + tid];
        }
        atomicAdd(&corr[tid], s);
    }
}

// ---- split-bf16 MFMA GEMM (bf16-A only). Three W paths:
//   FULLW>0: loop K in FULLW chunks {stage, barrier, compute, barrier};
//     32KB chunks -> 4 blocks/CU (occupancy is the binding constraint).
//   else BN>=128: double-buffered global_load_lds W, barrier per kstep.
//   else: register W.
// Optional fused second GEMM (W3: BN x 3) via 16-lane shfl -> C3 (BN<=32).
template <int BN, int WAVES, int FULLW>
__global__ __launch_bounds__(WAVES * 64) void k_gmfma(
        const unsigned short* __restrict__ Abf,
        const unsigned* __restrict__ Phi, const unsigned* __restrict__ Plo,
        const float* __restrict__ bias, const float* __restrict__ sub,
        const float* __restrict__ add, const int* __restrict__ addidx,
        float* __restrict__ C, unsigned short* __restrict__ Cbf,
        const float* __restrict__ W3, float* __restrict__ C3,
        int N, int K, int flags) {
    constexpr int NT = BN / 16;
    constexpr int WCOL = (BN == 256) ? 4 : (BN == 128 ? 2 : 1);
    constexpr int WROW = WAVES / WCOL;
    constexpr int NTW = NT / WCOL;
    constexpr int BR = 32 * WROW;
    constexpr bool LDSW = (BN >= 128);
    constexpr int LDSU = (FULLW > 0) ? 2 * NT * (FULLW / 32) * 256
                                     : (LDSW ? 2 * 2 * NT * 256 : 1);
    __shared__ unsigned lds_w[LDSU];
    const int t = threadIdx.x;
    const int w = t >> 6, l = t & 63;
    const int wr = w / WCOL, wc = w % WCOL;
    const int l15 = l & 15, g = l >> 4;
    const int row0 = blockIdx.x * BR + wr * 32;
    const int ctbase = wc * NTW;
    int ar0 = row0 + l15;      ar0 = ar0 < N ? ar0 : N - 1;
    int ar1 = row0 + 16 + l15; ar1 = ar1 < N ? ar1 : N - 1;
    const unsigned short* ab0 = Abf + (size_t)ar0 * K;
    const unsigned short* ab1 = Abf + (size_t)ar1 * K;

    f32x4 acc[2][NTW];
#pragma unroll
    for (int f = 0; f < 2; f++)
#pragma unroll
        for (int ct = 0; ct < NTW; ct++) acc[f][ct] = (f32x4){0.f, 0.f, 0.f, 0.f};

    auto loadA = [&](int s, U8* ahi) {
        const int k0 = s * 32;
#pragma unroll
        for (int f = 0; f < 2; f++) {
            const unsigned short* ab = f ? ab1 : ab0;
            const uint2 hA = *reinterpret_cast<const uint2*>(ab + k0 + 4 * g);
            const uint2 hB = *reinterpret_cast<const uint2*>(ab + k0 + 16 + 4 * g);
            ahi[f].u[0] = hA.x; ahi[f].u[1] = hA.y;
            ahi[f].u[2] = hB.x; ahi[f].u[3] = hB.y;
        }
    };
    auto domfma = [&](U8* wh, U8* wl, U8* ahi) {
#pragma unroll
        for (int ct = 0; ct < NTW; ct++) {
            acc[0][ct] = __builtin_amdgcn_mfma_f32_16x16x32_bf16(ahi[0].v, wh[ct].v, acc[0][ct], 0, 0, 0);
            acc[0][ct] = __builtin_amdgcn_mfma_f32_16x16x32_bf16(ahi[0].v, wl[ct].v, acc[0][ct], 0, 0, 0);
            acc[1][ct] = __builtin_amdgcn_mfma_f32_16x16x32_bf16(ahi[1].v, wh[ct].v, acc[1][ct], 0, 0, 0);
            acc[1][ct] = __builtin_amdgcn_mfma_f32_16x16x32_bf16(ahi[1].v, wl[ct].v, acc[1][ct], 0, 0, 0);
        }
    };

    const int nk = K / 32;

    if constexpr (FULLW > 0) {
        constexpr int NKT = FULLW / 32;     // ksteps per chunk
        const int nchunk = K / FULLW;
        U8 wh[NTW], wl[NTW], ahiA[2];
        for (int c = 0; c < nchunk; c++) {
            for (int i = w; i < 2 * NT * NKT; i += WAVES) {
                int s = i / (2 * NT);
                int j = i - s * 2 * NT;
                int gs = c * NKT + s;
                const unsigned* gsrc = (j < NT)
                    ? Phi + (size_t)(gs * NT + j) * 256 + l * 4
                    : Plo + (size_t)(gs * NT + (j - NT)) * 256 + l * 4;
                __builtin_amdgcn_global_load_lds(
                    (const __attribute__((address_space(1))) unsigned*)gsrc,
                    (__attribute__((address_space(3))) unsigned*)(lds_w + (size_t)i * 256),
                    16, 0, 0);
            }
            __syncthreads();                // chunk staged + visible
#pragma unroll
            for (int s = 0; s < NKT; s++) {
                loadA(c * NKT + s, ahiA);
                const unsigned* base = lds_w + (size_t)s * (2 * NT * 256);
#pragma unroll
                for (int ct = 0; ct < NTW; ct++) {
                    wh[ct] = *reinterpret_cast<const U8*>(base + (ctbase + ct) * 256 + l * 4);
                    wl[ct] = *reinterpret_cast<const U8*>(base + (NT + ctbase + ct) * 256 + l * 4);
                }
                domfma(wh, wl, ahiA);
            }
            __syncthreads();   // reads done before restage / stores (in-place)
        }
    } else if constexpr (LDSW) {
        auto stage = [&](int s, int b) {
            unsigned* base = lds_w + (size_t)b * (2 * NT * 256);
            for (int i = w; i < 2 * NT; i += WAVES) {
                const unsigned* gsrc = (i < NT)
                    ? Phi + (size_t)(s * NT + i) * 256 + l * 4
                    : Plo + (size_t)(s * NT + (i - NT)) * 256 + l * 4;
                __builtin_amdgcn_global_load_lds(
                    (const __attribute__((address_space(1))) unsigned*)gsrc,
                    (__attribute__((address_space(3))) unsigned*)(base + i * 256),
                    16, 0, 0);
            }
        };
        auto loadWlds = [&](int b, U8* wh, U8* wl) {
            const unsigned* base = lds_w + (size_t)b * (2 * NT * 256);
#pragma unroll
            for (int ct = 0; ct < NTW; ct++) {
                wh[ct] = *reinterpret_cast<const U8*>(base + (ctbase + ct) * 256 + l * 4);
                wl[ct] = *reinterpret_cast<const U8*>(base + (NT + ctbase + ct) * 256 + l * 4);
            }
        };

        U8 wh[NTW], wl[NTW], ahiA[2], ahiB[2];
        stage(0, 0);
        loadA(0, ahiA);
        __syncthreads();                    // W(0) staged + visible
        int s = 0;
        while (true) {
            const bool hasB = (s + 1 < nk);
            if (hasB) { stage(s + 1, (s + 1) & 1); loadA(s + 1, ahiB); }
            loadWlds(s & 1, wh, wl);
            domfma(wh, wl, ahiA);
            __syncthreads();                // drain stage(s+1); protect buf reuse
            if (!hasB) break;
            s++;
            const bool hasA2 = (s + 1 < nk);
            if (hasA2) { stage(s + 1, (s + 1) & 1); loadA(s + 1, ahiA); }
            loadWlds(s & 1, wh, wl);
            domfma(wh, wl, ahiB);
            __syncthreads();
            if (!hasA2) break;
            s++;
        }
        // loop's trailing barrier = all A reads done before stores (in-place safe)
    } else {
        auto loadW = [&](int s, U8* wh, U8* wl) {
            const unsigned* pb = Phi + ((size_t)(s * NT + ctbase) * 64 + l) * 4;
            const unsigned* pl = Plo + ((size_t)(s * NT + ctbase) * 64 + l) * 4;
#pragma unroll
            for (int ct = 0; ct < NTW; ct++) {
                wh[ct] = *reinterpret_cast<const U8*>(pb + (size_t)ct * 256);
                wl[ct] = *reinterpret_cast<const U8*>(pl + (size_t)ct * 256);
            }
        };
        U8 whA[NTW], wlA[NTW], ahiA[2];
        U8 whB[NTW], wlB[NTW], ahiB[2];
        loadW(0, whA, wlA);
        loadA(0, ahiA);
        int s = 0;
        while (true) {
            const bool hasB = (s + 1 < nk);
            if (hasB) { loadW(s + 1, whB, wlB); loadA(s + 1, ahiB); }
            domfma(whA, wlA, ahiA);
            if (!hasB) break;
            const bool hasA2 = (s + 2 < nk);
            if (hasA2) { loadW(s + 2, whA, wlA); loadA(s + 2, ahiA); }
            domfma(whB, wlB, ahiB);
            if (!hasA2) break;
            s += 2;
        }
        __syncthreads();   // all A reads done before any store (in-place safe)
    }

#pragma unroll
    for (int f = 0; f < 2; f++) {
#pragma unroll
        for (int r = 0; r < 4; r++) {
            int row = row0 + 16 * f + 4 * g + r;
            if (row >= N) continue;   // uniform across l15 group (shfl-safe)
            int gi = (add != nullptr) ? addidx[row] : 0;
            float t0 = 0.f, t1 = 0.f, t2 = 0.f;
#pragma unroll
            for (int ct = 0; ct < NTW; ct++) {
                int col = (ctbase + ct) * 16 + l15;
                float o = acc[f][ct][r];
                if (add != nullptr) o += add[(size_t)gi * BN + col];
                if (sub != nullptr) o -= sub[col];
                if (flags) o = elu1(o + bias[col]);
                if (C != nullptr) C[(size_t)row * BN + col] = o;
                if (Cbf != nullptr) Cbf[(size_t)row * BN + col] = (unsigned short)f2bf(o);
                if (W3 != nullptr) {
                    t0 += o * W3[col * 3 + 0];
                    t1 += o * W3[col * 3 + 1];
                    t2 += o * W3[col * 3 + 2];
                }
            }
            if (W3 != nullptr) {
#pragma unroll
                for (int m = 1; m < 16; m <<= 1) {
                    t0 += __shfl_xor(t0, m);
                    t1 += __shfl_xor(t1, m);
                    t2 += __shfl_xor(t2, m);
                }
                if (l15 == 0) {
                    C3[(size_t)row * 3 + 0] = t0;
                    C3[(size_t)row * 3 + 1] = t1;
                    C3[(size_t)row * 3 + 2] = t2;
                }
            }
        }
    }
}

// ---------------- simple fc (small shapes) ----------------
template <int M, int RPT>
__global__ __launch_bounds__(256) void k_fc(
        const float* __restrict__ A, const float* __restrict__ W,
        const float* __restrict__ bias, const float* __restrict__ add,
        const int* __restrict__ addidx, float* __restrict__ C,
        int N, int K, int flags) {
    constexpr int TX = M / 4;
    constexpr int TY = 256 / TX;
    constexpr int RB = TY * RPT;
    int tx = threadIdx.x % TX;
    int ty = threadIdx.x / TX;
    int row0 = blockIdx.x * RB + ty * RPT;
    float4 acc[RPT];
#pragma unroll
    for (int r = 0; r < RPT; r++) acc[r] = make_float4(0.f, 0.f, 0.f, 0.f);
    for (int k = 0; k < K; k++) {
        float4 w = *reinterpret_cast<const float4*>(&W[(size_t)k * M + tx * 4]);
#pragma unroll
        for (int r = 0; r < RPT; r++) {
            int row = row0 + r;
            row = row < N ? row : N - 1;
            float a = A[(size_t)row * K + k];
            acc[r].x += a * w.x; acc[r].y += a * w.y;
            acc[r].z += a * w.z; acc[r].w += a * w.w;
        }
    }
    if (add != nullptr) {
#pragma unroll
        for (int r = 0; r < RPT; r++) {
            int row = row0 + r;
            if (row < N) {
                int g = addidx[row];
                const float4 v = *reinterpret_cast<const float4*>(&add[(size_t)g * M + tx * 4]);
                acc[r].x += v.x; acc[r].y += v.y; acc[r].z += v.z; acc[r].w += v.w;
            }
        }
    }
    __syncthreads();
    float4 b = make_float4(0.f, 0.f, 0.f, 0.f);
    if (flags) b = *reinterpret_cast<const float4*>(&bias[tx * 4]);
#pragma unroll
    for (int r = 0; r < RPT; r++) {
        int row = row0 + r;
        if (row >= N) break;
        float4 o = acc[r];
        o.x += b.x; o.y += b.y; o.z += b.z; o.w += b.w;
        if (flags) { o.x = elu1(o.x); o.y = elu1(o.y); o.z = elu1(o.z); o.w = elu1(o.w); }
        *reinterpret_cast<float4*>(&C[(size_t)row * M + tx * 4]) = o;
    }
}

// fused: lx = elu(lA @ WfL2 + bfL2) -> lB;  compO = lx @ WO1[256:] -> lA
__global__ __launch_bounds__(256) void k_fcl2(
        const float* __restrict__ A, const float* __restrict__ W1,
        const float* __restrict__ b1, const float* __restrict__ W2,
        float* __restrict__ lxout, float* __restrict__ compO) {
    __shared__ float lx[32][64];
    const int tid = threadIdx.x;
    const int tx = tid % 16, ty = tid / 16;
    const int row0b = blockIdx.x * 32;
    float4 acc[2];
    acc[0] = make_float4(0.f, 0.f, 0.f, 0.f);
    acc[1] = make_float4(0.f, 0.f, 0.f, 0.f);
    for (int k = 0; k < 64; k++) {
        float4 w = *reinterpret_cast<const float4*>(&W1[(size_t)k * 64 + tx * 4]);
#pragma unroll
        for (int r = 0; r < 2; r++) {
            float a = A[(size_t)(row0b + ty * 2 + r) * 64 + k];
            acc[r].x += a * w.x; acc[r].y += a * w.y;
            acc[r].z += a * w.z; acc[r].w += a * w.w;
        }
    }
    float4 b = *reinterpret_cast<const float4*>(&b1[tx * 4]);
#pragma unroll
    for (int r = 0; r < 2; r++) {
        int lr = ty * 2 + r;
        float4 o;
        o.x = elu1(acc[r].x + b.x); o.y = elu1(acc[r].y + b.y);
        o.z = elu1(acc[r].z + b.z); o.w = elu1(acc[r].w + b.w);
        *reinterpret_cast<float4*>(&lxout[(size_t)(row0b + lr) * 64 + tx * 4]) = o;
        lx[lr][tx * 4 + 0] = o.x; lx[lr][tx * 4 + 1] = o.y;
        lx[lr][tx * 4 + 2] = o.z; lx[lr][tx * 4 + 3] = o.w;
    }
    __syncthreads();
    for (int o = tid; o < 32 * 128; o += 256) {
        int r = o >> 7, c = o & 127;
        float s = 0.f;
        for (int k = 0; k < 64; k++) s += lx[r][k] * W2[(size_t)k * 128 + c];
        compO[(size_t)(row0b + r) * 128 + c] = s;
    }
}

// ---------------- instance norm stats (bf16 input) ----------------
__global__ void k_instats(const unsigned short* __restrict__ h, float* __restrict__ sum,
                          float* __restrict__ sumsq, int n) {
    int c = threadIdx.x;
    int r0 = blockIdx.x * 128;
    int r1 = r0 + 128 < n ? r0 + 128 : n;
    float s = 0.f, q = 0.f;
#pragma unroll 4
    for (int r = r0; r < r1; r++) {
        float v = bf2f(h[(size_t)r * 256 + c]);
        s += v; q += v * v;
    }
    atomicAdd(&sum[c], s);
    atomicAdd(&sumsq[c], q);
}

// ---- merged: cluster poolavg + pooledges ----
__global__ __launch_bounds__(256) void k_poolmerge(
        const unsigned short* __restrict__ xh, const int* __restrict__ crowptr,
        const int* __restrict__ cdeg, const int* __restrict__ cnodes,
        const float* __restrict__ mu, const float* __restrict__ rstd,
        float* __restrict__ px,
        const int* __restrict__ src, const int* __restrict__ dst,
        const int* __restrict__ bc, unsigned char* __restrict__ bmT, int E) {
    int bid = blockIdx.x;
    if (bid < NCLUST) {
        int cl = bid;
        int c  = threadIdx.x;
        int start = crowptr[cl];
        int cnt = cdeg[cl];
        float acc = 0.f;
        int j = 0;
        for (; j + 3 < cnt; j += 4) {       // 4 independent gathers (ILP)
            int n0 = cnodes[start + j + 0];
            int n1 = cnodes[start + j + 1];
            int n2 = cnodes[start + j + 2];
            int n3 = cnodes[start + j + 3];
            float v0 = bf2f(xh[(size_t)n0 * 256 + c]);
            float v1 = bf2f(xh[(size_t)n1 * 256 + c]);
            float v2 = bf2f(xh[(size_t)n2 * 256 + c]);
            float v3 = bf2f(xh[(size_t)n3 * 256 + c]);
            acc += (v0 + v1) + (v2 + v3);
        }
        for (; j < cnt; j++) {
            int node = cnodes[start + j];
            acc += bf2f(xh[(size_t)node * 256 + c]);
        }
        float res = acc / fmaxf((float)cnt, 1.0f);
        res = (cnt > 0) ? (res - mu[c]) * rstd[c] : 0.f;
        px[(size_t)cl * 256 + c] = res;
    } else {
        int e = (bid - NCLUST) * 256 + threadIdx.x;
        if (e < E) {
            int ps = bc[src[e]];
            int pd = bc[dst[e]];
            bmT[(size_t)pd * NCLUST + ps] = 1;
        }
    }
}

__global__ __launch_bounds__(256) void k_pooldeg(
        const unsigned char* __restrict__ bmT, float* __restrict__ dinvp) {
    int d = blockIdx.x;
    int t = threadIdx.x;
    const unsigned int v = reinterpret_cast<const unsigned int*>(bmT + (size_t)d * NCLUST)[t];
    int s = (v & 0xff) + ((v >> 8) & 0xff) + ((v >> 16) & 0xff) + ((v >> 24) & 0xff);
    if (t == (d >> 2)) s -= (v >> ((d & 3) * 8)) & 0xff;
    __shared__ int red[256];
    red[t] = s; __syncthreads();
    for (int o = 128; o > 0; o >>= 1) {
        if (t < o) red[t] += red[t + o];
        __syncthreads();
    }
    if (t == 0) dinvp[d] = rsqrtf((float)red[0] + 1.0f);
}

template <int F>
__global__ __launch_bounds__(1024) void k_proppool2(
        const float* __restrict__ h, const float* __restrict__ dinvp,
        const unsigned char* __restrict__ bmT, const float* __restrict__ bias,
        float* __restrict__ out) {
    constexpr int SG = 1024 / F;
    const int d = blockIdx.x;
    const int t = threadIdx.x;
    const int f = t & (F - 1);
    const int sg = t / F;
    const unsigned char* bmrow = bmT + (size_t)d * NCLUST;
    float acc = 0.f;
#pragma unroll 4
    for (int s = sg; s < NCLUST; s += SG) {
        float m = (s != d) ? (float)bmrow[s] : 0.f;
        acc += m * dinvp[s] * h[(size_t)s * F + f];
    }
    __shared__ float red[1024];
    red[t] = acc; __syncthreads();
#pragma unroll
    for (int o = SG / 2; o > 0; o >>= 1) {
        if (sg < o) red[t] += red[t + o * F];
        __syncthreads();
    }
    if (sg == 0) {
        float di = dinvp[d];
        float r = di * red[f] + di * di * h[(size_t)d * F + f] + bias[f];
        out[(size_t)d * F + f] = elu1(r);
    }
}

// ---------------------------------------------------------------------------
extern "C" void kernel_launch(void* const* d_in, const int* in_sizes, int n_in,
                              void* d_out, int out_size, void* d_ws, size_t ws_size,
                              hipStream_t stream) {
    const float* x       = (const float*)d_in[0];
    const int*   adj     = (const int*)d_in[1];
    const int*   inb     = (const int*)d_in[3];
    const int*   cluster = (const int*)d_in[4];
    const float* WG1  = (const float*)d_in[5];   const float* bG1  = (const float*)d_in[6];
    const float* WfG1 = (const float*)d_in[7];   const float* bfG1 = (const float*)d_in[8];
    const float* WG2  = (const float*)d_in[9];   const float* bG2  = (const float*)d_in[10];
    const float* WfG2 = (const float*)d_in[11];  const float* bfG2 = (const float*)d_in[12];
    const float* WL1  = (const float*)d_in[13];  const float* bL1  = (const float*)d_in[14];
    const float* WfL1 = (const float*)d_in[15];  const float* bfL1 = (const float*)d_in[16];
    const float* WL2  = (const float*)d_in[17];  const float* bL2  = (const float*)d_in[18];
    const float* WfL2 = (const float*)d_in[19];  const float* bfL2 = (const float*)d_in[20];
    const float* WO1  = (const float*)d_in[21];  const float* bO1  = (const float*)d_in[22];
    const float* WfO1 = (const float*)d_in[23];  const float* bfO1 = (const float*)d_in[24];
    const float* WO2  = (const float*)d_in[25];  const float* bO2  = (const float*)d_in[26];
    const float* WfO2 = (const float*)d_in[27];  const float* bfO2 = (const float*)d_in[28];
    const float* WO3  = (const float*)d_in[29];  const float* bO3  = (const float*)d_in[30];
    const float* WfO3 = (const float*)d_in[31];  const float* bfO3 = (const float*)d_in[32];
    float* out = (float*)d_out;

    const int n = in_sizes[0] / 3;       // 100000
    const int E = in_sizes[1] / 2;       // 1600000
    const int* src = adj;
    const int* dst = adj + E;

    // ---- workspace carve ----
    char* ws = (char*)d_ws;
    size_t off = 0;
    auto alloc = [&](size_t bytes) -> void* {
        void* p = ws + off;
        off = (off + bytes + 255) & ~(size_t)255;
        return p;
    };
    int*   deg     = (int*)alloc((size_t)n * 4);     // zero span 1 start
    int*   fill    = (int*)alloc((size_t)n * 4);
    int*   cdeg    = (int*)alloc(NCLUST * 4);
    int*   cfill   = (int*)alloc(NCLUST * 4);
    int*   rowptr  = (int*)alloc((size_t)n * 4);     // zero span 1 end (exclusive)
    int*   crowptr = (int*)alloc(NCLUST * 4);
    int*   cnodes  = (int*)alloc((size_t)n * 4);
    int*   bcarr   = (int*)alloc((size_t)n * 4);
    float* dinv    = (float*)alloc((size_t)n * 4);
    int*   bsum    = (int*)alloc(512);
    int2*  csr_ev  = (int2*)alloc((size_t)E * 8);
    float* X       = (float*)alloc((size_t)n * 256 * 4);
    unsigned short* Xh = (unsigned short*)alloc((size_t)n * 256 * 2);
    float* B       = (float*)alloc((size_t)n * 128 * 4);
    unsigned short* Bh = (unsigned short*)alloc((size_t)n * 128 * 2);
    float* insum   = (float*)alloc(256 * 4);         // zero span 2 start
    float* insumsq = (float*)alloc(256 * 4);
    float* px      = (float*)alloc((size_t)NCLUST * 256 * 4);
    unsigned char* bmT = (unsigned char*)alloc((size_t)NCLUST * NCLUST);
    float* corr    = (float*)alloc(128 * 4);
    float* mu      = (float*)alloc(256 * 4);         // zero span 2 end (exclusive)
    float* rstd    = (float*)alloc(256 * 4);
    float* dinvp   = (float*)alloc(NCLUST * 4);
    float* lA      = (float*)alloc((size_t)NCLUST * 128 * 4);
    float* lB      = (float*)alloc((size_t)NCLUST * 128 * 4);
    unsigned* pfG1h = (unsigned*)alloc(2048 * 4);   unsigned* pfG1l = (unsigned*)alloc(2048 * 4);
    unsigned* pG2h  = (unsigned*)alloc(8192 * 4);   unsigned* pG2l  = (unsigned*)alloc(8192 * 4);
    unsigned* pfG2h = (unsigned*)alloc(32768 * 4);  unsigned* pfG2l = (unsigned*)alloc(32768 * 4);
    unsigned* pO1h  = (unsigned*)alloc(16384 * 4);  unsigned* pO1l  = (unsigned*)alloc(16384 * 4);
    unsigned* pfO1h = (unsigned*)alloc(8192 * 4);   unsigned* pfO1l = (unsigned*)alloc(8192 * 4);
    unsigned* pO2h  = (unsigned*)alloc(2048 * 4);   unsigned* pO2l  = (unsigned*)alloc(2048 * 4);
    unsigned* pfO2h = (unsigned*)alloc(512 * 4);    unsigned* pfO2l = (unsigned*)alloc(512 * 4);
    (void)ws_size; (void)n_in; (void)out_size;

    unsigned short* Bh1 = Bh;                        // h1/h2 (n x 64 bf16)
    unsigned short* Bh2 = Bh + (size_t)n * 64;       // p64 (n x 64 bf16)

    auto cdiv = [](int a, int b) { return (a + b - 1) / b; };
    const int EB = cdiv(E, 256);
    const int PB = cdiv(n, 4);

    // ---- init: zero scratch + pack all static weights (ONE launch) ----
    int nz1 = (int)(((char*)rowptr - (char*)deg) / 16);
    int nz2 = (int)(((char*)mu - (char*)insum) / 16);
    InitArgs ia;
    ia.d[0] = {WfG1, pfG1h, pfG1l, 64, 64, 0};
    ia.d[1] = {WG2,  pG2h,  pG2l,  64, 256, 512};
    ia.d[2] = {WfG2, pfG2h, pfG2l, 256, 256, 2560};
    ia.d[3] = {WfO1, pfO1h, pfO1l, 128, 128, 10752};
    ia.d[4] = {WO2,  pO2h,  pO2l,  128, 32, 12800};
    ia.d[5] = {WfO2, pfO2h, pfO2l, 32, 32, 13312};
    ia.tot = 13440;
    ia.z1 = (int4*)deg; ia.nz1 = nz1;
    ia.z2 = (int4*)insum; ia.nz2 = nz2;
    int initN = (nz1 + nz2 > ia.tot) ? (nz1 + nz2) : ia.tot;
    k_init<<<cdiv(initN, 256), 256, 0, stream>>>(ia);

    // ---- CSR build ----
    k_hist<<<EB, 256, 0, stream>>>(dst, deg, E);
    int nb = cdiv(n, 1024);
    k_scan_block<<<nb, 256, 0, stream>>>(deg, rowptr, bsum, n);
    k_nodeinit<<<cdiv(n, 256), 256, 0, stream>>>(rowptr, bsum, deg, cluster, inb,
                                                 dinv, bcarr, cdeg, n, nb);
    k_scan_block<<<1, 256, 0, stream>>>(cdeg, crowptr, bsum, NCLUST);
    k_fillc<<<EB, 256, 0, stream>>>(src, dst, dinv, rowptr, fill, csr_ev, E,
                                    bcarr, crowptr, cfill, cnodes, n);

    // ---- global GCN stack (all bf16 activations) ----
    // p3 + fused fc<64>: h1 -> bf16 Bh1
    k_prop3f1<<<cdiv(n, 256), 256, 0, stream>>>(x, dinv, rowptr, deg, csr_ev,
                                                WG1, bG1, Bh1, n);
    // h2 = elu(h1 @ WfG1 + bfG1)  (Bh1 in-place, register-W)  [8-wave]
    k_gmfma<64, 8, 0><<<cdiv(n, 256), 512, 0, stream>>>(Bh1, pfG1h, pfG1l, bfG1,
                                                        nullptr, nullptr, nullptr,
                                                        nullptr, Bh1, nullptr, nullptr,
                                                        n, 64, 1);
    // p64 = S h2  (bf16 gather -> bf16 Bh2)
    k_prop4sb<64, 1><<<PB, 256, 0, stream>>>(Bh1, dinv, rowptr, deg, csr_ev,
                                             nullptr, nullptr, Bh2, n, 0);
    // h3 = elu(p64 @ WG2 + bG2) -> bf16 (Xh)  [FULLW=32: 32KB, 4 blk/CU]
    k_gmfma<256, 8, 32><<<cdiv(n, 64), 512, 0, stream>>>(Bh2, pG2h, pG2l, bG2,
                                                         nullptr, nullptr, nullptr,
                                                         nullptr, Xh, nullptr, nullptr,
                                                         n, 64, 1);
    // h4 = elu(h3 @ WfG2 + bfG2)  (Xh in-place)  [FULLW=32: 32KB, 4 blk/CU]
    k_gmfma<256, 8, 32><<<cdiv(n, 64), 512, 0, stream>>>(Xh, pfG2h, pfG2l, bfG2,
                                                         nullptr, nullptr, nullptr,
                                                         nullptr, Xh, nullptr, nullptr,
                                                         n, 256, 1);

    // ---- instance norm stats + merged finalize/pack/corr ----
    k_instats<<<cdiv(n, 128), 256, 0, stream>>>(Xh, insum, insumsq, n);
    k_normprep<<<17, 256, 0, stream>>>(WO1, insum, insumsq, pO1h, pO1l, corr, mu, rstd, n);

    // ---- cluster pooling (poolavg + pooledges merged) ----
    k_poolmerge<<<NCLUST + EB, 256, 0, stream>>>(Xh, crowptr, cdeg, cnodes, mu, rstd, px,
                                                 src, dst, bcarr, bmT, E);
    k_pooldeg<<<NCLUST, 256, 0, stream>>>(bmT, dinvp);

    // ---- local (pooled) GCN stack ----
    k_fc<128, 2><<<cdiv(NCLUST, 16), 256, 0, stream>>>(px, WL1, nullptr, nullptr, nullptr,
                                                       lA, NCLUST, 256, 0);
    k_proppool2<128><<<NCLUST, 1024, 0, stream>>>(lA, dinvp, bmT, bL1, lB);
    k_fc<128, 2><<<cdiv(NCLUST, 16), 256, 0, stream>>>(lB, WfL1, bfL1, nullptr, nullptr,
                                                       lA, NCLUST, 128, 1);
    k_fc<64, 2><<<cdiv(NCLUST, 32), 256, 0, stream>>>(lA, WL2, nullptr, nullptr, nullptr,
                                                      lB, NCLUST, 128, 0);
    k_proppool2<64><<<NCLUST, 1024, 0, stream>>>(lB, dinvp, bmT, bL2, lA);
    // fused: lx = elu(lA @ WfL2 + bfL2) -> lB; compO = lx @ WO1[256:] -> lA
    k_fcl2<<<NCLUST / 32, 256, 0, stream>>>(lA, WfL2, bfL2, WO1 + (size_t)256 * 128,
                                            lB, lA);

    // ---- output GCN stack ----
    // t1 = Xh @ (rstd*WO1) - corr + compO[bc] -> bf16 (Bh)  [FULLW=64: 4 chunks]
    k_gmfma<128, 8, 64><<<cdiv(n, 128), 512, 0, stream>>>(Xh, pO1h, pO1l, nullptr,
                                                          corr, lA, bcarr, nullptr, Bh,
                                                          nullptr, nullptr, n, 256, 0);
    k_prop4sb<128, 1><<<PB, 256, 0, stream>>>(Bh, dinv, rowptr, deg, csr_ev,
                                              bO1, nullptr, Xh, n, 1);
    // o2 = elu(o1 @ WfO1 + bfO1)  (Xh in-place)  [FULLW=64: 2 chunks]
    k_gmfma<128, 8, 64><<<cdiv(n, 128), 512, 0, stream>>>(Xh, pfO1h, pfO1l, bfO1,
                                                          nullptr, nullptr, nullptr,
                                                          nullptr, Xh, nullptr, nullptr,
                                                          n, 128, 1);
    // t2 = o2 @ WO2  -> bf16 (Bh, N x 32)  [register-W, 8-wave]
    k_gmfma<32, 8, 0><<<cdiv(n, 256), 512, 0, stream>>>(Xh, pO2h, pO2l, nullptr,
                                                        nullptr, nullptr, nullptr,
                                                        nullptr, Bh, nullptr, nullptr,
                                                        n, 128, 0);
    k_prop4sb<32, 1><<<PB, 256, 0, stream>>>(Bh, dinv, rowptr, deg, csr_ev,
                                             bO2, nullptr, Xh, n, 1);
    // o4 = elu(o3 @ WfO2 + bfO2); t3 = o4 @ WO3 fused -> B (N x 3 f32)
    k_gmfma<32, 8, 0><<<cdiv(n, 256), 512, 0, stream>>>(Xh, pfO2h, pfO2l, bfO2,
                                                        nullptr, nullptr, nullptr,
                                                        nullptr, nullptr, WO3, B,
                                                        n, 32, 1);
    // o5 = elu(S t3 + bO3); out = elu(o5 @ WfO3 + bfO3)  (fused)
    k_prop3out<<<cdiv(n, 256), 256, 0, stream>>>(B, dinv, rowptr, deg, csr_ev,
                                                 bO3, WfO3, bfO3, out, n);
}

// Round 32
// 1045.316 us; speedup vs baseline: 1.0853x; 1.0008x over previous
//
#include <hip/hip_runtime.h>

// ---------------------------------------------------------------------------
// GCN3D. R9: split-bf16 MFMA GEMMs. R13: prop4s+norm-fold. R14/15/17/23: bf16
// activations everywhere. R17/R20/R21/R22: launch merging, int2 edges.
// R24: LDS-W staging. R26/R27: FULLW chunked k-loops. R29/R30: FULLW=32
//   (4 blk/CU) + gather unroll (1046us best). R31: unroll x4 marginal.
// R32: FULLW A-register prefetch pipeline: loadA(gs+1) issued BEFORE the
//   ds_read+MFMA of kstep gs (A is registers -- no LDS hazard, compiler
//   can't hoist across __syncthreads itself). A-latency now spans the
//   MFMA block + trailing barrier + next stage instead of serializing
//   after each barrier. Applies to h3/h4/t1/o2.
// ---------------------------------------------------------------------------

#define NCLUST 1024

typedef short bf16x8 __attribute__((ext_vector_type(8)));
typedef float f32x4 __attribute__((ext_vector_type(4)));

__device__ __forceinline__ float elu1(float x) { return x > 0.f ? x : expm1f(x); }

__device__ __forceinline__ unsigned f2bf(float f) {
    union { float f; unsigned u; } c; c.f = f;
    unsigned u = c.u;
    return (u + 0x7fffu + ((u >> 16) & 1u)) >> 16;
}
__device__ __forceinline__ float bf2f(unsigned h) {
    union { unsigned u; float f; } c; c.u = h << 16; return c.f;
}

union U8 { unsigned u[4]; bf16x8 v; };

// ---- W pre-pack body ----
__device__ __forceinline__ void wpack_body(const float* W, unsigned* Phi, unsigned* Plo,
                                           int K, int BN, int t) {
    int NT = BN / 16;
    int lane = t & 63;
    int rest = t >> 6;
    int ct = rest % NT;
    int s = rest / NT;
    int col = ct * 16 + (lane & 15);
    int g = lane >> 4;
    int k0 = s * 32;
    float e[8];
#pragma unroll
    for (int j = 0; j < 4; j++) {
        e[j]     = W[(size_t)(k0 + 4 * g + j) * BN + col];
        e[4 + j] = W[(size_t)(k0 + 16 + 4 * g + j) * BN + col];
    }
#pragma unroll
    for (int j = 0; j < 4; j++) {
        unsigned h0 = f2bf(e[2 * j]), h1 = f2bf(e[2 * j + 1]);
        Phi[(size_t)t * 4 + j] = h0 | (h1 << 16);
        unsigned l0 = f2bf(e[2 * j] - bf2f(h0));
        unsigned l1 = f2bf(e[2 * j + 1] - bf2f(h1));
        Plo[(size_t)t * 4 + j] = l0 | (l1 << 16);
    }
}

struct PackDesc { const float* W; unsigned* Ph; unsigned* Pl; int K, BN, tbase; };
struct InitArgs {
    PackDesc d[6]; int tot;
    int4* z1; int nz1; int4* z2; int nz2;
};

__global__ void k_init(InitArgs a) {
    int t = blockIdx.x * 256 + threadIdx.x;
    if (t < a.nz1) a.z1[t] = make_int4(0, 0, 0, 0);
    else if (t - a.nz1 < a.nz2) a.z2[t - a.nz1] = make_int4(0, 0, 0, 0);
    if (t < a.tot) {
        int i = 0;
#pragma unroll
        for (int j = 1; j < 6; j++) if (t >= a.d[j].tbase) i = j;
        wpack_body(a.d[i].W, a.d[i].Ph, a.d[i].Pl, a.d[i].K, a.d[i].BN,
                   t - a.d[i].tbase);
    }
}

// ---------------- CSR build ----------------
__global__ void k_hist(const int* __restrict__ key, int* __restrict__ deg, int E) {
    int e = blockIdx.x * 256 + threadIdx.x;
    if (e < E) atomicAdd(&deg[key[e]], 1);
}

__global__ void k_scan_block(const int* __restrict__ deg, int* __restrict__ rowptr,
                             int* __restrict__ bsum, int n) {
    __shared__ int lds[256];
    int tid = threadIdx.x;
    int base = blockIdx.x * 1024 + tid * 4;
    int v0 = base + 0 < n ? deg[base + 0] : 0;
    int v1 = base + 1 < n ? deg[base + 1] : 0;
    int v2 = base + 2 < n ? deg[base + 2] : 0;
    int v3 = base + 3 < n ? deg[base + 3] : 0;
    int tsum = v0 + v1 + v2 + v3;
    lds[tid] = tsum; __syncthreads();
    for (int off = 1; off < 256; off <<= 1) {
        int t = (tid >= off) ? lds[tid - off] : 0;
        __syncthreads();
        lds[tid] += t;
        __syncthreads();
    }
    int run = lds[tid] - tsum;
    if (base + 0 < n) rowptr[base + 0] = run; run += v0;
    if (base + 1 < n) rowptr[base + 1] = run; run += v1;
    if (base + 2 < n) rowptr[base + 2] = run; run += v2;
    if (base + 3 < n) rowptr[base + 3] = run;
    if (tid == 255) bsum[blockIdx.x] = lds[255];
}

// merged: bsum scan + rowptr finalize + dinv + bc + cluster hist
__global__ void k_nodeinit(int* __restrict__ rowptr, const int* __restrict__ bsum,
                           const int* __restrict__ deg, const int* __restrict__ cluster,
                           const int* __restrict__ inb, float* __restrict__ dinv,
                           int* __restrict__ bc, int* __restrict__ cdeg, int n, int nb) {
    __shared__ int pfx[128];
    int tid = threadIdx.x;
    if (tid < 128) pfx[tid] = (tid < nb) ? bsum[tid] : 0;
    __syncthreads();
    for (int off = 1; off < 128; off <<= 1) {
        int v = 0;
        if (tid < 128 && tid >= off) v = pfx[tid - off];
        __syncthreads();
        if (tid < 128) pfx[tid] += v;
        __syncthreads();
    }
    int i = blockIdx.x * 256 + tid;
    if (i >= n) return;
    int j = i >> 10;
    int base = (j == 0) ? 0 : pfx[j - 1];
    rowptr[i] += base;
    dinv[i] = rsqrtf((float)deg[i] + 1.0f);
    int c = cluster[i] + inb[i] * NCLUST;
    bc[i] = c;
    atomicAdd(&cdeg[c], 1);
}

// merged: edge CSR fill (packed int2) + cluster member fill
__global__ void k_fillc(const int* __restrict__ src, const int* __restrict__ dst,
                        const float* __restrict__ dinv, const int* __restrict__ rowptr,
                        int* __restrict__ fill, int2* __restrict__ csr_ev, int E,
                        const int* __restrict__ bc, const int* __restrict__ crowptr,
                        int* __restrict__ cfill, int* __restrict__ cnodes, int n) {
    int e = blockIdx.x * 256 + threadIdx.x;
    if (e < E) {
        int d = dst[e];
        int pos = rowptr[d] + atomicAdd(&fill[d], 1);
        int s = src[e];
        csr_ev[pos] = make_int2(s, __float_as_int(dinv[s]));
    }
    if (e < n) {
        int c = bc[e];
        int pos = crowptr[c] + atomicAdd(&cfill[c], 1);
        cnodes[pos] = e;
    }
}

// ------ GCN propagation, bf16 input; OB=0 f32 out, OB=1 bf16 out ------
// Edge loop unrolled x4: four independent row-gathers in flight per iter.
template <int F, int OB>
__global__ __launch_bounds__(256) void k_prop4sb(
        const unsigned short* __restrict__ hbf, const float* __restrict__ dinv,
        const int* __restrict__ rowptr, const int* __restrict__ deg,
        const int2* __restrict__ csr_ev,
        const float* __restrict__ bias, float* __restrict__ outf,
        unsigned short* __restrict__ outb, int n, int flags) {
    constexpr int FS = F / 4;
    constexpr int ES = 64 / FS;
    const int node = (blockIdx.x * 256 + threadIdx.x) >> 6;
    if (node >= n) return;
    const int l = threadIdx.x & 63;
    const int fs = l & (FS - 1);
    const int ep = l / FS;
    const int fi = fs * 4;
    const int start = rowptr[node];
    const int cnt = deg[node];
    float ax = 0.f, ay = 0.f, az = 0.f, aw = 0.f;
    int j = ep;
    for (; j + 3 * ES < cnt; j += 4 * ES) {
        const int2 ev0 = csr_ev[start + j];
        const int2 ev1 = csr_ev[start + j + ES];
        const int2 ev2 = csr_ev[start + j + 2 * ES];
        const int2 ev3 = csr_ev[start + j + 3 * ES];
        float w0 = __int_as_float(ev0.y);
        float w1 = __int_as_float(ev1.y);
        float w2 = __int_as_float(ev2.y);
        float w3 = __int_as_float(ev3.y);
        const ushort4 v0 = *reinterpret_cast<const ushort4*>(&hbf[(size_t)ev0.x * F + fi]);
        const ushort4 v1 = *reinterpret_cast<const ushort4*>(&hbf[(size_t)ev1.x * F + fi]);
        const ushort4 v2 = *reinterpret_cast<const ushort4*>(&hbf[(size_t)ev2.x * F + fi]);
        const ushort4 v3 = *reinterpret_cast<const ushort4*>(&hbf[(size_t)ev3.x * F + fi]);
        ax += (w0 * bf2f(v0.x) + w1 * bf2f(v1.x)) + (w2 * bf2f(v2.x) + w3 * bf2f(v3.x));
        ay += (w0 * bf2f(v0.y) + w1 * bf2f(v1.y)) + (w2 * bf2f(v2.y) + w3 * bf2f(v3.y));
        az += (w0 * bf2f(v0.z) + w1 * bf2f(v1.z)) + (w2 * bf2f(v2.z) + w3 * bf2f(v3.z));
        aw += (w0 * bf2f(v0.w) + w1 * bf2f(v1.w)) + (w2 * bf2f(v2.w) + w3 * bf2f(v3.w));
    }
    for (; j < cnt; j += ES) {
        const int2 ev = csr_ev[start + j];
        float w = __int_as_float(ev.y);
        const ushort4 v = *reinterpret_cast<const ushort4*>(&hbf[(size_t)ev.x * F + fi]);
        ax += w * bf2f(v.x); ay += w * bf2f(v.y);
        az += w * bf2f(v.z); aw += w * bf2f(v.w);
    }
#pragma unroll
    for (int off = FS; off < 64; off <<= 1) {
        ax += __shfl_xor(ax, off);
        ay += __shfl_xor(ay, off);
        az += __shfl_xor(az, off);
        aw += __shfl_xor(aw, off);
    }
    if (ep == 0) {
        float di = dinv[node];
        const ushort4 sv = *reinterpret_cast<const ushort4*>(&hbf[(size_t)node * F + fi]);
        float4 o;
        o.x = di * ax + di * di * bf2f(sv.x);
        o.y = di * ay + di * di * bf2f(sv.y);
        o.z = di * az + di * di * bf2f(sv.z);
        o.w = di * aw + di * di * bf2f(sv.w);
        if (flags) {
            const float4 b = *reinterpret_cast<const float4*>(&bias[fi]);
            o.x = elu1(o.x + b.x); o.y = elu1(o.y + b.y);
            o.z = elu1(o.z + b.z); o.w = elu1(o.w + b.w);
        }
        if constexpr (OB) {
            ushort4 ob;
            ob.x = (unsigned short)f2bf(o.x); ob.y = (unsigned short)f2bf(o.y);
            ob.z = (unsigned short)f2bf(o.z); ob.w = (unsigned short)f2bf(o.w);
            *reinterpret_cast<ushort4*>(&outb[(size_t)node * F + fi]) = ob;
        } else {
            *reinterpret_cast<float4*>(&outf[(size_t)node * F + fi]) = o;
        }
    }
}

// prop3 on x + fused fc<64> -> bf16 out (N x 64); edge loop unrolled x2
__global__ void k_prop3f1(const float* __restrict__ h, const float* __restrict__ dinv,
                          const int* __restrict__ rowptr, const int* __restrict__ deg,
                          const int2* __restrict__ csr_ev,
                          const float* __restrict__ WG1, const float* __restrict__ bG1,
                          unsigned short* __restrict__ outb, int n) {
    int node = blockIdx.x * 256 + threadIdx.x;
    if (node >= n) return;
    int start = rowptr[node], cnt = deg[node];
    float a0 = 0.f, a1 = 0.f, a2 = 0.f;
    int j = 0;
    for (; j + 1 < cnt; j += 2) {
        const int2 ev0 = csr_ev[start + j];
        const int2 ev1 = csr_ev[start + j + 1];
        float w0 = __int_as_float(ev0.y);
        float w1 = __int_as_float(ev1.y);
        const float* r0 = h + (size_t)ev0.x * 3;
        const float* r1 = h + (size_t)ev1.x * 3;
        a0 += w0 * r0[0] + w1 * r1[0];
        a1 += w0 * r0[1] + w1 * r1[1];
        a2 += w0 * r0[2] + w1 * r1[2];
    }
    if (j < cnt) {
        const int2 ev = csr_ev[start + j];
        float w = __int_as_float(ev.y);
        const float* r = h + (size_t)ev.x * 3;
        a0 += w * r[0]; a1 += w * r[1]; a2 += w * r[2];
    }
    float di = dinv[node];
    float p0 = di * a0 + di * di * h[(size_t)node * 3 + 0];
    float p1 = di * a1 + di * di * h[(size_t)node * 3 + 1];
    float p2 = di * a2 + di * di * h[(size_t)node * 3 + 2];
    unsigned short* op = outb + (size_t)node * 64;
#pragma unroll 4
    for (int c = 0; c < 64; c += 4) {
        ushort4 ob;
        ob.x = (unsigned short)f2bf(elu1(p0 * WG1[c + 0] + p1 * WG1[64 + c + 0] + p2 * WG1[128 + c + 0] + bG1[c + 0]));
        ob.y = (unsigned short)f2bf(elu1(p0 * WG1[c + 1] + p1 * WG1[64 + c + 1] + p2 * WG1[128 + c + 1] + bG1[c + 1]));
        ob.z = (unsigned short)f2bf(elu1(p0 * WG1[c + 2] + p1 * WG1[64 + c + 2] + p2 * WG1[128 + c + 2] + bG1[c + 2]));
        ob.w = (unsigned short)f2bf(elu1(p0 * WG1[c + 3] + p1 * WG1[64 + c + 3] + p2 * WG1[128 + c + 3] + bG1[c + 3]));
        *reinterpret_cast<ushort4*>(op + c) = ob;
    }
}

// prop3 on t3 (+bO3, elu) + fused final fc3; edge loop unrolled x2
__global__ void k_prop3out(const float* __restrict__ h, const float* __restrict__ dinv,
                           const int* __restrict__ rowptr, const int* __restrict__ deg,
                           const int2* __restrict__ csr_ev,
                           const float* __restrict__ bO3, const float* __restrict__ WfO3,
                           const float* __restrict__ bfO3, float* __restrict__ out, int n) {
    int node = blockIdx.x * 256 + threadIdx.x;
    if (node >= n) return;
    int start = rowptr[node], cnt = deg[node];
    float a0 = 0.f, a1 = 0.f, a2 = 0.f;
    int j = 0;
    for (; j + 1 < cnt; j += 2) {
        const int2 ev0 = csr_ev[start + j];
        const int2 ev1 = csr_ev[start + j + 1];
        float w0 = __int_as_float(ev0.y);
        float w1 = __int_as_float(ev1.y);
        const float* r0 = h + (size_t)ev0.x * 3;
        const float* r1 = h + (size_t)ev1.x * 3;
        a0 += w0 * r0[0] + w1 * r1[0];
        a1 += w0 * r0[1] + w1 * r1[1];
        a2 += w0 * r0[2] + w1 * r1[2];
    }
    if (j < cnt) {
        const int2 ev = csr_ev[start + j];
        float w = __int_as_float(ev.y);
        const float* r = h + (size_t)ev.x * 3;
        a0 += w * r[0]; a1 += w * r[1]; a2 += w * r[2];
    }
    float di = dinv[node];
    float o0 = elu1(di * a0 + di * di * h[(size_t)node * 3 + 0] + bO3[0]);
    float o1 = elu1(di * a1 + di * di * h[(size_t)node * 3 + 1] + bO3[1]);
    float o2 = elu1(di * a2 + di * di * h[(size_t)node * 3 + 2] + bO3[2]);
#pragma unroll
    for (int c = 0; c < 3; c++) {
        out[(size_t)node * 3 + c] =
            elu1(o0 * WfO3[c] + o1 * WfO3[3 + c] + o2 * WfO3[6 + c] + bfO3[c]);
    }
}

// ---- merged: infinal + rstd-scaled WO1 pack + corr (17 blocks x 256) ----
__global__ void k_normprep(const float* __restrict__ W, const float* __restrict__ insum,
                           const float* __restrict__ insumsq, unsigned* __restrict__ Phi,
                           unsigned* __restrict__ Plo, float* __restrict__ corr,
                           float* __restrict__ mu, float* __restrict__ rstd, int n) {
    const float fn = (float)n;
    const int bid = blockIdx.x, tid = threadIdx.x;
    if (bid == 16) {
        float m = insum[tid] / fn;
        float var = insumsq[tid] / fn - m * m;
        mu[tid] = m;
        rstd[tid] = rsqrtf(var + 1e-5f);
        return;
    }
    {
        int t = bid * 256 + tid;
        int lane = t & 63, rest = t >> 6;
        int ct = rest % 8, s = rest / 8;
        int col = ct * 16 + (lane & 15);
        int g = lane >> 4;
        int k0 = s * 32;
        float e[8];
#pragma unroll
        for (int j = 0; j < 4; j++) {
            int ka = k0 + 4 * g + j;
            int kb = k0 + 16 + 4 * g + j;
            float ma = insum[ka] / fn;
            float sa = rsqrtf(insumsq[ka] / fn - ma * ma + 1e-5f);
            float mb = insum[kb] / fn;
            float sb = rsqrtf(insumsq[kb] / fn - mb * mb + 1e-5f);
            e[j]     = W[(size_t)ka * 128 + col] * sa;
            e[4 + j] = W[(size_t)kb * 128 + col] * sb;
        }
#pragma unroll
        for (int j = 0; j < 4; j++) {
            unsigned h0 = f2bf(e[2 * j]), h1 = f2bf(e[2 * j + 1]);
            Phi[(size_t)t * 4 + j] = h0 | (h1 << 16);
            unsigned l0 = f2bf(e[2 * j] - bf2f(h0));
            unsigned l1 = f2bf(e[2 * j + 1] - bf2f(h1));
            Plo[(size_t)t * 4 + j] = l0 | (l1 << 16);
        }
    }
    if (tid < 128) {
        int k0 = bid * 16;
        float s = 0.f;
        for (int k = k0; k < k0 + 16; k++) {
            float m = insum[k] / fn;
            float r = rsqrtf(insumsq[k] / fn - m * m + 1e-5f);
            s += m * r * W[(size_t)k * 128 + tid];
        }
        atomicAdd(&corr[tid], s);
    }
}

// ---- split-bf16 MFMA GEMM (bf16-A only). Three W paths:
//   FULLW>0: loop K in FULLW chunks {stage, barrier, compute, barrier};
//     32KB chunks -> 4 blocks/CU. A-register prefetch pipeline: next
//     kstep's A issued before current MFMAs (no LDS hazard).
//   else BN>=128: double-buffered global_load_lds W, barrier per kstep.
//   else: register W.
// Optional fused second GEMM (W3: BN x 3) via 16-lane shfl -> C3 (BN<=32).
template <int BN, int WAVES, int FULLW>
__global__ __launch_bounds__(WAVES * 64) void k_gmfma(
        const unsigned short* __restrict__ Abf,
        const unsigned* __restrict__ Phi, const unsigned* __restrict__ Plo,
        const float* __restrict__ bias, const float* __restrict__ sub,
        const float* __restrict__ add, const int* __restrict__ addidx,
        float* __restrict__ C, unsigned short* __restrict__ Cbf,
        const float* __restrict__ W3, float* __restrict__ C3,
        int N, int K, int flags) {
    constexpr int NT = BN / 16;
    constexpr int WCOL = (BN == 256) ? 4 : (BN == 128 ? 2 : 1);
    constexpr int WROW = WAVES / WCOL;
    constexpr int NTW = NT / WCOL;
    constexpr int BR = 32 * WROW;
    constexpr bool LDSW = (BN >= 128);
    constexpr int LDSU = (FULLW > 0) ? 2 * NT * (FULLW / 32) * 256
                                     : (LDSW ? 2 * 2 * NT * 256 : 1);
    __shared__ unsigned lds_w[LDSU];
    const int t = threadIdx.x;
    const int w = t >> 6, l = t & 63;
    const int wr = w / WCOL, wc = w % WCOL;
    const int l15 = l & 15, g = l >> 4;
    const int row0 = blockIdx.x * BR + wr * 32;
    const int ctbase = wc * NTW;
    int ar0 = row0 + l15;      ar0 = ar0 < N ? ar0 : N - 1;
    int ar1 = row0 + 16 + l15; ar1 = ar1 < N ? ar1 : N - 1;
    const unsigned short* ab0 = Abf + (size_t)ar0 * K;
    const unsigned short* ab1 = Abf + (size_t)ar1 * K;

    f32x4 acc[2][NTW];
#pragma unroll
    for (int f = 0; f < 2; f++)
#pragma unroll
        for (int ct = 0; ct < NTW; ct++) acc[f][ct] = (f32x4){0.f, 0.f, 0.f, 0.f};

    auto loadA = [&](int s, U8* ahi) {
        const int k0 = s * 32;
#pragma unroll
        for (int f = 0; f < 2; f++) {
            const unsigned short* ab = f ? ab1 : ab0;
            const uint2 hA = *reinterpret_cast<const uint2*>(ab + k0 + 4 * g);
            const uint2 hB = *reinterpret_cast<const uint2*>(ab + k0 + 16 + 4 * g);
            ahi[f].u[0] = hA.x; ahi[f].u[1] = hA.y;
            ahi[f].u[2] = hB.x; ahi[f].u[3] = hB.y;
        }
    };
    auto domfma = [&](U8* wh, U8* wl, U8* ahi) {
#pragma unroll
        for (int ct = 0; ct < NTW; ct++) {
            acc[0][ct] = __builtin_amdgcn_mfma_f32_16x16x32_bf16(ahi[0].v, wh[ct].v, acc[0][ct], 0, 0, 0);
            acc[0][ct] = __builtin_amdgcn_mfma_f32_16x16x32_bf16(ahi[0].v, wl[ct].v, acc[0][ct], 0, 0, 0);
            acc[1][ct] = __builtin_amdgcn_mfma_f32_16x16x32_bf16(ahi[1].v, wh[ct].v, acc[1][ct], 0, 0, 0);
            acc[1][ct] = __builtin_amdgcn_mfma_f32_16x16x32_bf16(ahi[1].v, wl[ct].v, acc[1][ct], 0, 0, 0);
        }
    };

    const int nk = K / 32;

    if constexpr (FULLW > 0) {
        constexpr int NKT = FULLW / 32;     // ksteps per chunk
        const int nchunk = K / FULLW;
        U8 wh[NTW], wl[NTW], ahiC[2], ahiN[2];
        loadA(0, ahiC);                     // prologue prefetch
        for (int c = 0; c < nchunk; c++) {
            for (int i = w; i < 2 * NT * NKT; i += WAVES) {
                int s = i / (2 * NT);
                int j = i - s * 2 * NT;
                int gs = c * NKT + s;
                const unsigned* gsrc = (j < NT)
                    ? Phi + (size_t)(gs * NT + j) * 256 + l * 4
                    : Plo + (size_t)(gs * NT + (j - NT)) * 256 + l * 4;
                __builtin_amdgcn_global_load_lds(
                    (const __attribute__((address_space(1))) unsigned*)gsrc,
                    (__attribute__((address_space(3))) unsigned*)(lds_w + (size_t)i * 256),
                    16, 0, 0);
            }
            __syncthreads();                // chunk staged + visible
#pragma unroll
            for (int s = 0; s < NKT; s++) {
                const int gs = c * NKT + s;
                if (gs + 1 < nk) loadA(gs + 1, ahiN);   // prefetch next kstep
                const unsigned* base = lds_w + (size_t)s * (2 * NT * 256);
#pragma unroll
                for (int ct = 0; ct < NTW; ct++) {
                    wh[ct] = *reinterpret_cast<const U8*>(base + (ctbase + ct) * 256 + l * 4);
                    wl[ct] = *reinterpret_cast<const U8*>(base + (NT + ctbase + ct) * 256 + l * 4);
                }
                domfma(wh, wl, ahiC);
#pragma unroll
                for (int q = 0; q < 4; q++) {
                    ahiC[0].u[q] = ahiN[0].u[q];
                    ahiC[1].u[q] = ahiN[1].u[q];
                }
            }
            __syncthreads();   // reads done before restage / stores (in-place)
        }
    } else if constexpr (LDSW) {
        auto stage = [&](int s, int b) {
            unsigned* base = lds_w + (size_t)b * (2 * NT * 256);
            for (int i = w; i < 2 * NT; i += WAVES) {
                const unsigned* gsrc = (i < NT)
                    ? Phi + (size_t)(s * NT + i) * 256 + l * 4
                    : Plo + (size_t)(s * NT + (i - NT)) * 256 + l * 4;
                __builtin_amdgcn_global_load_lds(
                    (const __attribute__((address_space(1))) unsigned*)gsrc,
                    (__attribute__((address_space(3))) unsigned*)(base + i * 256),
                    16, 0, 0);
            }
        };
        auto loadWlds = [&](int b, U8* wh, U8* wl) {
            const unsigned* base = lds_w + (size_t)b * (2 * NT * 256);
#pragma unroll
            for (int ct = 0; ct < NTW; ct++) {
                wh[ct] = *reinterpret_cast<const U8*>(base + (ctbase + ct) * 256 + l * 4);
                wl[ct] = *reinterpret_cast<const U8*>(base + (NT + ctbase + ct) * 256 + l * 4);
            }
        };

        U8 wh[NTW], wl[NTW], ahiA[2], ahiB[2];
        stage(0, 0);
        loadA(0, ahiA);
        __syncthreads();                    // W(0) staged + visible
        int s = 0;
        while (true) {
            const bool hasB = (s + 1 < nk);
            if (hasB) { stage(s + 1, (s + 1) & 1); loadA(s + 1, ahiB); }
            loadWlds(s & 1, wh, wl);
            domfma(wh, wl, ahiA);
            __syncthreads();                // drain stage(s+1); protect buf reuse
            if (!hasB) break;
            s++;
            const bool hasA2 = (s + 1 < nk);
            if (hasA2) { stage(s + 1, (s + 1) & 1); loadA(s + 1, ahiA); }
            loadWlds(s & 1, wh, wl);
            domfma(wh, wl, ahiB);
            __syncthreads();
            if (!hasA2) break;
            s++;
        }
        // loop's trailing barrier = all A reads done before stores (in-place safe)
    } else {
        auto loadW = [&](int s, U8* wh, U8* wl) {
            const unsigned* pb = Phi + ((size_t)(s * NT + ctbase) * 64 + l) * 4;
            const unsigned* pl = Plo + ((size_t)(s * NT + ctbase) * 64 + l) * 4;
#pragma unroll
            for (int ct = 0; ct < NTW; ct++) {
                wh[ct] = *reinterpret_cast<const U8*>(pb + (size_t)ct * 256);
                wl[ct] = *reinterpret_cast<const U8*>(pl + (size_t)ct * 256);
            }
        };
        U8 whA[NTW], wlA[NTW], ahiA[2];
        U8 whB[NTW], wlB[NTW], ahiB[2];
        loadW(0, whA, wlA);
        loadA(0, ahiA);
        int s = 0;
        while (true) {
            const bool hasB = (s + 1 < nk);
            if (hasB) { loadW(s + 1, whB, wlB); loadA(s + 1, ahiB); }
            domfma(whA, wlA, ahiA);
            if (!hasB) break;
            const bool hasA2 = (s + 2 < nk);
            if (hasA2) { loadW(s + 2, whA, wlA); loadA(s + 2, ahiA); }
            domfma(whB, wlB, ahiB);
            if (!hasA2) break;
            s += 2;
        }
        __syncthreads();   // all A reads done before any store (in-place safe)
    }

#pragma unroll
    for (int f = 0; f < 2; f++) {
#pragma unroll
        for (int r = 0; r < 4; r++) {
            int row = row0 + 16 * f + 4 * g + r;
            if (row >= N) continue;   // uniform across l15 group (shfl-safe)
            int gi = (add != nullptr) ? addidx[row] : 0;
            float t0 = 0.f, t1 = 0.f, t2 = 0.f;
#pragma unroll
            for (int ct = 0; ct < NTW; ct++) {
                int col = (ctbase + ct) * 16 + l15;
                float o = acc[f][ct][r];
                if (add != nullptr) o += add[(size_t)gi * BN + col];
                if (sub != nullptr) o -= sub[col];
                if (flags) o = elu1(o + bias[col]);
                if (C != nullptr) C[(size_t)row * BN + col] = o;
                if (Cbf != nullptr) Cbf[(size_t)row * BN + col] = (unsigned short)f2bf(o);
                if (W3 != nullptr) {
                    t0 += o * W3[col * 3 + 0];
                    t1 += o * W3[col * 3 + 1];
                    t2 += o * W3[col * 3 + 2];
                }
            }
            if (W3 != nullptr) {
#pragma unroll
                for (int m = 1; m < 16; m <<= 1) {
                    t0 += __shfl_xor(t0, m);
                    t1 += __shfl_xor(t1, m);
                    t2 += __shfl_xor(t2, m);
                }
                if (l15 == 0) {
                    C3[(size_t)row * 3 + 0] = t0;
                    C3[(size_t)row * 3 + 1] = t1;
                    C3[(size_t)row * 3 + 2] = t2;
                }
            }
        }
    }
}

// ---------------- simple fc (small shapes) ----------------
template <int M, int RPT>
__global__ __launch_bounds__(256) void k_fc(
        const float* __restrict__ A, const float* __restrict__ W,
        const float* __restrict__ bias, const float* __restrict__ add,
        const int* __restrict__ addidx, float* __restrict__ C,
        int N, int K, int flags) {
    constexpr int TX = M / 4;
    constexpr int TY = 256 / TX;
    constexpr int RB = TY * RPT;
    int tx = threadIdx.x % TX;
    int ty = threadIdx.x / TX;
    int row0 = blockIdx.x * RB + ty * RPT;
    float4 acc[RPT];
#pragma unroll
    for (int r = 0; r < RPT; r++) acc[r] = make_float4(0.f, 0.f, 0.f, 0.f);
    for (int k = 0; k < K; k++) {
        float4 w = *reinterpret_cast<const float4*>(&W[(size_t)k * M + tx * 4]);
#pragma unroll
        for (int r = 0; r < RPT; r++) {
            int row = row0 + r;
            row = row < N ? row : N - 1;
            float a = A[(size_t)row * K + k];
            acc[r].x += a * w.x; acc[r].y += a * w.y;
            acc[r].z += a * w.z; acc[r].w += a * w.w;
        }
    }
    if (add != nullptr) {
#pragma unroll
        for (int r = 0; r < RPT; r++) {
            int row = row0 + r;
            if (row < N) {
                int g = addidx[row];
                const float4 v = *reinterpret_cast<const float4*>(&add[(size_t)g * M + tx * 4]);
                acc[r].x += v.x; acc[r].y += v.y; acc[r].z += v.z; acc[r].w += v.w;
            }
        }
    }
    __syncthreads();
    float4 b = make_float4(0.f, 0.f, 0.f, 0.f);
    if (flags) b = *reinterpret_cast<const float4*>(&bias[tx * 4]);
#pragma unroll
    for (int r = 0; r < RPT; r++) {
        int row = row0 + r;
        if (row >= N) break;
        float4 o = acc[r];
        o.x += b.x; o.y += b.y; o.z += b.z; o.w += b.w;
        if (flags) { o.x = elu1(o.x); o.y = elu1(o.y); o.z = elu1(o.z); o.w = elu1(o.w); }
        *reinterpret_cast<float4*>(&C[(size_t)row * M + tx * 4]) = o;
    }
}

// fused: lx = elu(lA @ WfL2 + bfL2) -> lB;  compO = lx @ WO1[256:] -> lA
__global__ __launch_bounds__(256) void k_fcl2(
        const float* __restrict__ A, const float* __restrict__ W1,
        const float* __restrict__ b1, const float* __restrict__ W2,
        float* __restrict__ lxout, float* __restrict__ compO) {
    __shared__ float lx[32][64];
    const int tid = threadIdx.x;
    const int tx = tid % 16, ty = tid / 16;
    const int row0b = blockIdx.x * 32;
    float4 acc[2];
    acc[0] = make_float4(0.f, 0.f, 0.f, 0.f);
    acc[1] = make_float4(0.f, 0.f, 0.f, 0.f);
    for (int k = 0; k < 64; k++) {
        float4 w = *reinterpret_cast<const float4*>(&W1[(size_t)k * 64 + tx * 4]);
#pragma unroll
        for (int r = 0; r < 2; r++) {
            float a = A[(size_t)(row0b + ty * 2 + r) * 64 + k];
            acc[r].x += a * w.x; acc[r].y += a * w.y;
            acc[r].z += a * w.z; acc[r].w += a * w.w;
        }
    }
    float4 b = *reinterpret_cast<const float4*>(&b1[tx * 4]);
#pragma unroll
    for (int r = 0; r < 2; r++) {
        int lr = ty * 2 + r;
        float4 o;
        o.x = elu1(acc[r].x + b.x); o.y = elu1(acc[r].y + b.y);
        o.z = elu1(acc[r].z + b.z); o.w = elu1(acc[r].w + b.w);
        *reinterpret_cast<float4*>(&lxout[(size_t)(row0b + lr) * 64 + tx * 4]) = o;
        lx[lr][tx * 4 + 0] = o.x; lx[lr][tx * 4 + 1] = o.y;
        lx[lr][tx * 4 + 2] = o.z; lx[lr][tx * 4 + 3] = o.w;
    }
    __syncthreads();
    for (int o = tid; o < 32 * 128; o += 256) {
        int r = o >> 7, c = o & 127;
        float s = 0.f;
        for (int k = 0; k < 64; k++) s += lx[r][k] * W2[(size_t)k * 128 + c];
        compO[(size_t)(row0b + r) * 128 + c] = s;
    }
}

// ---------------- instance norm stats (bf16 input) ----------------
__global__ void k_instats(const unsigned short* __restrict__ h, float* __restrict__ sum,
                          float* __restrict__ sumsq, int n) {
    int c = threadIdx.x;
    int r0 = blockIdx.x * 128;
    int r1 = r0 + 128 < n ? r0 + 128 : n;
    float s = 0.f, q = 0.f;
#pragma unroll 4
    for (int r = r0; r < r1; r++) {
        float v = bf2f(h[(size_t)r * 256 + c]);
        s += v; q += v * v;
    }
    atomicAdd(&sum[c], s);
    atomicAdd(&sumsq[c], q);
}

// ---- merged: cluster poolavg + pooledges ----
__global__ __launch_bounds__(256) void k_poolmerge(
        const unsigned short* __restrict__ xh, const int* __restrict__ crowptr,
        const int* __restrict__ cdeg, const int* __restrict__ cnodes,
        const float* __restrict__ mu, const float* __restrict__ rstd,
        float* __restrict__ px,
        const int* __restrict__ src, const int* __restrict__ dst,
        const int* __restrict__ bc, unsigned char* __restrict__ bmT, int E) {
    int bid = blockIdx.x;
    if (bid < NCLUST) {
        int cl = bid;
        int c  = threadIdx.x;
        int start = crowptr[cl];
        int cnt = cdeg[cl];
        float acc = 0.f;
        int j = 0;
        for (; j + 3 < cnt; j += 4) {       // 4 independent gathers (ILP)
            int n0 = cnodes[start + j + 0];
            int n1 = cnodes[start + j + 1];
            int n2 = cnodes[start + j + 2];
            int n3 = cnodes[start + j + 3];
            float v0 = bf2f(xh[(size_t)n0 * 256 + c]);
            float v1 = bf2f(xh[(size_t)n1 * 256 + c]);
            float v2 = bf2f(xh[(size_t)n2 * 256 + c]);
            float v3 = bf2f(xh[(size_t)n3 * 256 + c]);
            acc += (v0 + v1) + (v2 + v3);
        }
        for (; j < cnt; j++) {
            int node = cnodes[start + j];
            acc += bf2f(xh[(size_t)node * 256 + c]);
        }
        float res = acc / fmaxf((float)cnt, 1.0f);
        res = (cnt > 0) ? (res - mu[c]) * rstd[c] : 0.f;
        px[(size_t)cl * 256 + c] = res;
    } else {
        int e = (bid - NCLUST) * 256 + threadIdx.x;
        if (e < E) {
            int ps = bc[src[e]];
            int pd = bc[dst[e]];
            bmT[(size_t)pd * NCLUST + ps] = 1;
        }
    }
}

__global__ __launch_bounds__(256) void k_pooldeg(
        const unsigned char* __restrict__ bmT, float* __restrict__ dinvp) {
    int d = blockIdx.x;
    int t = threadIdx.x;
    const unsigned int v = reinterpret_cast<const unsigned int*>(bmT + (size_t)d * NCLUST)[t];
    int s = (v & 0xff) + ((v >> 8) & 0xff) + ((v >> 16) & 0xff) + ((v >> 24) & 0xff);
    if (t == (d >> 2)) s -= (v >> ((d & 3) * 8)) & 0xff;
    __shared__ int red[256];
    red[t] = s; __syncthreads();
    for (int o = 128; o > 0; o >>= 1) {
        if (t < o) red[t] += red[t + o];
        __syncthreads();
    }
    if (t == 0) dinvp[d] = rsqrtf((float)red[0] + 1.0f);
}

template <int F>
__global__ __launch_bounds__(1024) void k_proppool2(
        const float* __restrict__ h, const float* __restrict__ dinvp,
        const unsigned char* __restrict__ bmT, const float* __restrict__ bias,
        float* __restrict__ out) {
    constexpr int SG = 1024 / F;
    const int d = blockIdx.x;
    const int t = threadIdx.x;
    const int f = t & (F - 1);
    const int sg = t / F;
    const unsigned char* bmrow = bmT + (size_t)d * NCLUST;
    float acc = 0.f;
#pragma unroll 4
    for (int s = sg; s < NCLUST; s += SG) {
        float m = (s != d) ? (float)bmrow[s] : 0.f;
        acc += m * dinvp[s] * h[(size_t)s * F + f];
    }
    __shared__ float red[1024];
    red[t] = acc; __syncthreads();
#pragma unroll
    for (int o = SG / 2; o > 0; o >>= 1) {
        if (sg < o) red[t] += red[t + o * F];
        __syncthreads();
    }
    if (sg == 0) {
        float di = dinvp[d];
        float r = di * red[f] + di * di * h[(size_t)d * F + f] + bias[f];
        out[(size_t)d * F + f] = elu1(r);
    }
}

// ---------------------------------------------------------------------------
extern "C" void kernel_launch(void* const* d_in, const int* in_sizes, int n_in,
                              void* d_out, int out_size, void* d_ws, size_t ws_size,
                              hipStream_t stream) {
    const float* x       = (const float*)d_in[0];
    const int*   adj     = (const int*)d_in[1];
    const int*   inb     = (const int*)d_in[3];
    const int*   cluster = (const int*)d_in[4];
    const float* WG1  = (const float*)d_in[5];   const float* bG1  = (const float*)d_in[6];
    const float* WfG1 = (const float*)d_in[7];   const float* bfG1 = (const float*)d_in[8];
    const float* WG2  = (const float*)d_in[9];   const float* bG2  = (const float*)d_in[10];
    const float* WfG2 = (const float*)d_in[11];  const float* bfG2 = (const float*)d_in[12];
    const float* WL1  = (const float*)d_in[13];  const float* bL1  = (const float*)d_in[14];
    const float* WfL1 = (const float*)d_in[15];  const float* bfL1 = (const float*)d_in[16];
    const float* WL2  = (const float*)d_in[17];  const float* bL2  = (const float*)d_in[18];
    const float* WfL2 = (const float*)d_in[19];  const float* bfL2 = (const float*)d_in[20];
    const float* WO1  = (const float*)d_in[21];  const float* bO1  = (const float*)d_in[22];
    const float* WfO1 = (const float*)d_in[23];  const float* bfO1 = (const float*)d_in[24];
    const float* WO2  = (const float*)d_in[25];  const float* bO2  = (const float*)d_in[26];
    const float* WfO2 = (const float*)d_in[27];  const float* bfO2 = (const float*)d_in[28];
    const float* WO3  = (const float*)d_in[29];  const float* bO3  = (const float*)d_in[30];
    const float* WfO3 = (const float*)d_in[31];  const float* bfO3 = (const float*)d_in[32];
    float* out = (float*)d_out;

    const int n = in_sizes[0] / 3;       // 100000
    const int E = in_sizes[1] / 2;       // 1600000
    const int* src = adj;
    const int* dst = adj + E;

    // ---- workspace carve ----
    char* ws = (char*)d_ws;
    size_t off = 0;
    auto alloc = [&](size_t bytes) -> void* {
        void* p = ws + off;
        off = (off + bytes + 255) & ~(size_t)255;
        return p;
    };
    int*   deg     = (int*)alloc((size_t)n * 4);     // zero span 1 start
    int*   fill    = (int*)alloc((size_t)n * 4);
    int*   cdeg    = (int*)alloc(NCLUST * 4);
    int*   cfill   = (int*)alloc(NCLUST * 4);
    int*   rowptr  = (int*)alloc((size_t)n * 4);     // zero span 1 end (exclusive)
    int*   crowptr = (int*)alloc(NCLUST * 4);
    int*   cnodes  = (int*)alloc((size_t)n * 4);
    int*   bcarr   = (int*)alloc((size_t)n * 4);
    float* dinv    = (float*)alloc((size_t)n * 4);
    int*   bsum    = (int*)alloc(512);
    int2*  csr_ev  = (int2*)alloc((size_t)E * 8);
    float* X       = (float*)alloc((size_t)n * 256 * 4);
    unsigned short* Xh = (unsigned short*)alloc((size_t)n * 256 * 2);
    float* B       = (float*)alloc((size_t)n * 128 * 4);
    unsigned short* Bh = (unsigned short*)alloc((size_t)n * 128 * 2);
    float* insum   = (float*)alloc(256 * 4);         // zero span 2 start
    float* insumsq = (float*)alloc(256 * 4);
    float* px      = (float*)alloc((size_t)NCLUST * 256 * 4);
    unsigned char* bmT = (unsigned char*)alloc((size_t)NCLUST * NCLUST);
    float* corr    = (float*)alloc(128 * 4);
    float* mu      = (float*)alloc(256 * 4);         // zero span 2 end (exclusive)
    float* rstd    = (float*)alloc(256 * 4);
    float* dinvp   = (float*)alloc(NCLUST * 4);
    float* lA      = (float*)alloc((size_t)NCLUST * 128 * 4);
    float* lB      = (float*)alloc((size_t)NCLUST * 128 * 4);
    unsigned* pfG1h = (unsigned*)alloc(2048 * 4);   unsigned* pfG1l = (unsigned*)alloc(2048 * 4);
    unsigned* pG2h  = (unsigned*)alloc(8192 * 4);   unsigned* pG2l  = (unsigned*)alloc(8192 * 4);
    unsigned* pfG2h = (unsigned*)alloc(32768 * 4);  unsigned* pfG2l = (unsigned*)alloc(32768 * 4);
    unsigned* pO1h  = (unsigned*)alloc(16384 * 4);  unsigned* pO1l  = (unsigned*)alloc(16384 * 4);
    unsigned* pfO1h = (unsigned*)alloc(8192 * 4);   unsigned* pfO1l = (unsigned*)alloc(8192 * 4);
    unsigned* pO2h  = (unsigned*)alloc(2048 * 4);   unsigned* pO2l  = (unsigned*)alloc(2048 * 4);
    unsigned* pfO2h = (unsigned*)alloc(512 * 4);    unsigned* pfO2l = (unsigned*)alloc(512 * 4);
    (void)ws_size; (void)n_in; (void)out_size;

    unsigned short* Bh1 = Bh;                        // h1/h2 (n x 64 bf16)
    unsigned short* Bh2 = Bh + (size_t)n * 64;       // p64 (n x 64 bf16)

    auto cdiv = [](int a, int b) { return (a + b - 1) / b; };
    const int EB = cdiv(E, 256);
    const int PB = cdiv(n, 4);

    // ---- init: zero scratch + pack all static weights (ONE launch) ----
    int nz1 = (int)(((char*)rowptr - (char*)deg) / 16);
    int nz2 = (int)(((char*)mu - (char*)insum) / 16);
    InitArgs ia;
    ia.d[0] = {WfG1, pfG1h, pfG1l, 64, 64, 0};
    ia.d[1] = {WG2,  pG2h,  pG2l,  64, 256, 512};
    ia.d[2] = {WfG2, pfG2h, pfG2l, 256, 256, 2560};
    ia.d[3] = {WfO1, pfO1h, pfO1l, 128, 128, 10752};
    ia.d[4] = {WO2,  pO2h,  pO2l,  128, 32, 12800};
    ia.d[5] = {WfO2, pfO2h, pfO2l, 32, 32, 13312};
    ia.tot = 13440;
    ia.z1 = (int4*)deg; ia.nz1 = nz1;
    ia.z2 = (int4*)insum; ia.nz2 = nz2;
    int initN = (nz1 + nz2 > ia.tot) ? (nz1 + nz2) : ia.tot;
    k_init<<<cdiv(initN, 256), 256, 0, stream>>>(ia);

    // ---- CSR build ----
    k_hist<<<EB, 256, 0, stream>>>(dst, deg, E);
    int nb = cdiv(n, 1024);
    k_scan_block<<<nb, 256, 0, stream>>>(deg, rowptr, bsum, n);
    k_nodeinit<<<cdiv(n, 256), 256, 0, stream>>>(rowptr, bsum, deg, cluster, inb,
                                                 dinv, bcarr, cdeg, n, nb);
    k_scan_block<<<1, 256, 0, stream>>>(cdeg, crowptr, bsum, NCLUST);
    k_fillc<<<EB, 256, 0, stream>>>(src, dst, dinv, rowptr, fill, csr_ev, E,
                                    bcarr, crowptr, cfill, cnodes, n);

    // ---- global GCN stack (all bf16 activations) ----
    // p3 + fused fc<64>: h1 -> bf16 Bh1
    k_prop3f1<<<cdiv(n, 256), 256, 0, stream>>>(x, dinv, rowptr, deg, csr_ev,
                                                WG1, bG1, Bh1, n);
    // h2 = elu(h1 @ WfG1 + bfG1)  (Bh1 in-place, register-W)  [8-wave]
    k_gmfma<64, 8, 0><<<cdiv(n, 256), 512, 0, stream>>>(Bh1, pfG1h, pfG1l, bfG1,
                                                        nullptr, nullptr, nullptr,
                                                        nullptr, Bh1, nullptr, nullptr,
                                                        n, 64, 1);
    // p64 = S h2  (bf16 gather -> bf16 Bh2)
    k_prop4sb<64, 1><<<PB, 256, 0, stream>>>(Bh1, dinv, rowptr, deg, csr_ev,
                                             nullptr, nullptr, Bh2, n, 0);
    // h3 = elu(p64 @ WG2 + bG2) -> bf16 (Xh)  [FULLW=32 + A-prefetch]
    k_gmfma<256, 8, 32><<<cdiv(n, 64), 512, 0, stream>>>(Bh2, pG2h, pG2l, bG2,
                                                         nullptr, nullptr, nullptr,
                                                         nullptr, Xh, nullptr, nullptr,
                                                         n, 64, 1);
    // h4 = elu(h3 @ WfG2 + bfG2)  (Xh in-place)  [FULLW=32 + A-prefetch]
    k_gmfma<256, 8, 32><<<cdiv(n, 64), 512, 0, stream>>>(Xh, pfG2h, pfG2l, bfG2,
                                                         nullptr, nullptr, nullptr,
                                                         nullptr, Xh, nullptr, nullptr,
                                                         n, 256, 1);

    // ---- instance norm stats + merged finalize/pack/corr ----
    k_instats<<<cdiv(n, 128), 256, 0, stream>>>(Xh, insum, insumsq, n);
    k_normprep<<<17, 256, 0, stream>>>(WO1, insum, insumsq, pO1h, pO1l, corr, mu, rstd, n);

    // ---- cluster pooling (poolavg + pooledges merged) ----
    k_poolmerge<<<NCLUST + EB, 256, 0, stream>>>(Xh, crowptr, cdeg, cnodes, mu, rstd, px,
                                                 src, dst, bcarr, bmT, E);
    k_pooldeg<<<NCLUST, 256, 0, stream>>>(bmT, dinvp);

    // ---- local (pooled) GCN stack ----
    k_fc<128, 2><<<cdiv(NCLUST, 16), 256, 0, stream>>>(px, WL1, nullptr, nullptr, nullptr,
                                                       lA, NCLUST, 256, 0);
    k_proppool2<128><<<NCLUST, 1024, 0, stream>>>(lA, dinvp, bmT, bL1, lB);
    k_fc<128, 2><<<cdiv(NCLUST, 16), 256, 0, stream>>>(lB, WfL1, bfL1, nullptr, nullptr,
                                                       lA, NCLUST, 128, 1);
    k_fc<64, 2><<<cdiv(NCLUST, 32), 256, 0, stream>>>(lA, WL2, nullptr, nullptr, nullptr,
                                                      lB, NCLUST, 128, 0);
    k_proppool2<64><<<NCLUST, 1024, 0, stream>>>(lB, dinvp, bmT, bL2, lA);
    // fused: lx = elu(lA @ WfL2 + bfL2) -> lB; compO = lx @ WO1[256:] -> lA
    k_fcl2<<<NCLUST / 32, 256, 0, stream>>>(lA, WfL2, bfL2, WO1 + (size_t)256 * 128,
                                            lB, lA);

    // ---- output GCN stack ----
    // t1 = Xh @ (rstd*WO1) - corr + compO[bc] -> bf16 (Bh)  [FULLW=64 + A-prefetch]
    k_gmfma<128, 8, 64><<<cdiv(n, 128), 512, 0, stream>>>(Xh, pO1h, pO1l, nullptr,
                                                          corr, lA, bcarr, nullptr, Bh,
                                                          nullptr, nullptr, n, 256, 0);
    k_prop4sb<128, 1><<<PB, 256, 0, stream>>>(Bh, dinv, rowptr, deg, csr_ev,
                                              bO1, nullptr, Xh, n, 1);
    // o2 = elu(o1 @ WfO1 + bfO1)  (Xh in-place)  [FULLW=64 + A-prefetch]
    k_gmfma<128, 8, 64><<<cdiv(n, 128), 512, 0, stream>>>(Xh, pfO1h, pfO1l, bfO1,
                                                          nullptr, nullptr, nullptr,
                                                          nullptr, Xh, nullptr, nullptr,
                                                          n, 128, 1);
    // t2 = o2 @ WO2  -> bf16 (Bh, N x 32)  [register-W, 8-wave]
    k_gmfma<32, 8, 0><<<cdiv(n, 256), 512, 0, stream>>>(Xh, pO2h, pO2l, nullptr,
                                                        nullptr, nullptr, nullptr,
                                                        nullptr, Bh, nullptr, nullptr,
                                                        n, 128, 0);
    k_prop4sb<32, 1><<<PB, 256, 0, stream>>>(Bh, dinv, rowptr, deg, csr_ev,
                                             bO2, nullptr, Xh, n, 1);
    // o4 = elu(o3 @ WfO2 + bfO2); t3 = o4 @ WO3 fused -> B (N x 3 f32)
    k_gmfma<32, 8, 0><<<cdiv(n, 256), 512, 0, stream>>>(Xh, pfO2h, pfO2l, bfO2,
                                                        nullptr, nullptr, nullptr,
                                                        nullptr, nullptr, WO3, B,
                                                        n, 32, 1);
    // o5 = elu(S t3 + bO3); out = elu(o5 @ WfO3 + bfO3)  (fused)
    k_prop3out<<<cdiv(n, 256), 256, 0, stream>>>(B, dinv, rowptr, deg, csr_ev,
                                                 bO3, WfO3, bfO3, out, n);
}

// Round 33
// 991.892 us; speedup vs baseline: 1.1437x; 1.0539x over previous
//
#include <hip/hip_runtime.h>

// ---------------------------------------------------------------------------
// GCN3D. R9: split-bf16 MFMA GEMMs. R13: prop4s+norm-fold. R14/15/17/23: bf16
// activations everywhere. R17/R20/R21/R22: launch merging, int2 edges.
// R24: LDS-W staging. R26-R32: FULLW chunks (32KB, 4 blk/CU), A-prefetch,
//   gather unrolls (1045us best). h4 plateaued (9 attacks) -- attack tail.
// R33: k_proppool2 read h (512KB) fully PER BLOCK: 1024 blocks = 512MB L2
//   traffic for 268 MFLOP. D-tile DT=4: block produces 4 dest rows, bm rows
//   diag-zeroed in LDS, h read once per block -> traffic /4. 2-barrier
//   reduction via red[4][1024]. Also instats unroll 4->8.
// ---------------------------------------------------------------------------

#define NCLUST 1024

typedef short bf16x8 __attribute__((ext_vector_type(8)));
typedef float f32x4 __attribute__((ext_vector_type(4)));

__device__ __forceinline__ float elu1(float x) { return x > 0.f ? x : expm1f(x); }

__device__ __forceinline__ unsigned f2bf(float f) {
    union { float f; unsigned u; } c; c.f = f;
    unsigned u = c.u;
    return (u + 0x7fffu + ((u >> 16) & 1u)) >> 16;
}
__device__ __forceinline__ float bf2f(unsigned h) {
    union { unsigned u; float f; } c; c.u = h << 16; return c.f;
}

union U8 { unsigned u[4]; bf16x8 v; };

// ---- W pre-pack body ----
__device__ __forceinline__ void wpack_body(const float* W, unsigned* Phi, unsigned* Plo,
                                           int K, int BN, int t) {
    int NT = BN / 16;
    int lane = t & 63;
    int rest = t >> 6;
    int ct = rest % NT;
    int s = rest / NT;
    int col = ct * 16 + (lane & 15);
    int g = lane >> 4;
    int k0 = s * 32;
    float e[8];
#pragma unroll
    for (int j = 0; j < 4; j++) {
        e[j]     = W[(size_t)(k0 + 4 * g + j) * BN + col];
        e[4 + j] = W[(size_t)(k0 + 16 + 4 * g + j) * BN + col];
    }
#pragma unroll
    for (int j = 0; j < 4; j++) {
        unsigned h0 = f2bf(e[2 * j]), h1 = f2bf(e[2 * j + 1]);
        Phi[(size_t)t * 4 + j] = h0 | (h1 << 16);
        unsigned l0 = f2bf(e[2 * j] - bf2f(h0));
        unsigned l1 = f2bf(e[2 * j + 1] - bf2f(h1));
        Plo[(size_t)t * 4 + j] = l0 | (l1 << 16);
    }
}

struct PackDesc { const float* W; unsigned* Ph; unsigned* Pl; int K, BN, tbase; };
struct InitArgs {
    PackDesc d[6]; int tot;
    int4* z1; int nz1; int4* z2; int nz2;
};

__global__ void k_init(InitArgs a) {
    int t = blockIdx.x * 256 + threadIdx.x;
    if (t < a.nz1) a.z1[t] = make_int4(0, 0, 0, 0);
    else if (t - a.nz1 < a.nz2) a.z2[t - a.nz1] = make_int4(0, 0, 0, 0);
    if (t < a.tot) {
        int i = 0;
#pragma unroll
        for (int j = 1; j < 6; j++) if (t >= a.d[j].tbase) i = j;
        wpack_body(a.d[i].W, a.d[i].Ph, a.d[i].Pl, a.d[i].K, a.d[i].BN,
                   t - a.d[i].tbase);
    }
}

// ---------------- CSR build ----------------
__global__ void k_hist(const int* __restrict__ key, int* __restrict__ deg, int E) {
    int e = blockIdx.x * 256 + threadIdx.x;
    if (e < E) atomicAdd(&deg[key[e]], 1);
}

__global__ void k_scan_block(const int* __restrict__ deg, int* __restrict__ rowptr,
                             int* __restrict__ bsum, int n) {
    __shared__ int lds[256];
    int tid = threadIdx.x;
    int base = blockIdx.x * 1024 + tid * 4;
    int v0 = base + 0 < n ? deg[base + 0] : 0;
    int v1 = base + 1 < n ? deg[base + 1] : 0;
    int v2 = base + 2 < n ? deg[base + 2] : 0;
    int v3 = base + 3 < n ? deg[base + 3] : 0;
    int tsum = v0 + v1 + v2 + v3;
    lds[tid] = tsum; __syncthreads();
    for (int off = 1; off < 256; off <<= 1) {
        int t = (tid >= off) ? lds[tid - off] : 0;
        __syncthreads();
        lds[tid] += t;
        __syncthreads();
    }
    int run = lds[tid] - tsum;
    if (base + 0 < n) rowptr[base + 0] = run; run += v0;
    if (base + 1 < n) rowptr[base + 1] = run; run += v1;
    if (base + 2 < n) rowptr[base + 2] = run; run += v2;
    if (base + 3 < n) rowptr[base + 3] = run;
    if (tid == 255) bsum[blockIdx.x] = lds[255];
}

// merged: bsum scan + rowptr finalize + dinv + bc + cluster hist
__global__ void k_nodeinit(int* __restrict__ rowptr, const int* __restrict__ bsum,
                           const int* __restrict__ deg, const int* __restrict__ cluster,
                           const int* __restrict__ inb, float* __restrict__ dinv,
                           int* __restrict__ bc, int* __restrict__ cdeg, int n, int nb) {
    __shared__ int pfx[128];
    int tid = threadIdx.x;
    if (tid < 128) pfx[tid] = (tid < nb) ? bsum[tid] : 0;
    __syncthreads();
    for (int off = 1; off < 128; off <<= 1) {
        int v = 0;
        if (tid < 128 && tid >= off) v = pfx[tid - off];
        __syncthreads();
        if (tid < 128) pfx[tid] += v;
        __syncthreads();
    }
    int i = blockIdx.x * 256 + tid;
    if (i >= n) return;
    int j = i >> 10;
    int base = (j == 0) ? 0 : pfx[j - 1];
    rowptr[i] += base;
    dinv[i] = rsqrtf((float)deg[i] + 1.0f);
    int c = cluster[i] + inb[i] * NCLUST;
    bc[i] = c;
    atomicAdd(&cdeg[c], 1);
}

// merged: edge CSR fill (packed int2) + cluster member fill
__global__ void k_fillc(const int* __restrict__ src, const int* __restrict__ dst,
                        const float* __restrict__ dinv, const int* __restrict__ rowptr,
                        int* __restrict__ fill, int2* __restrict__ csr_ev, int E,
                        const int* __restrict__ bc, const int* __restrict__ crowptr,
                        int* __restrict__ cfill, int* __restrict__ cnodes, int n) {
    int e = blockIdx.x * 256 + threadIdx.x;
    if (e < E) {
        int d = dst[e];
        int pos = rowptr[d] + atomicAdd(&fill[d], 1);
        int s = src[e];
        csr_ev[pos] = make_int2(s, __float_as_int(dinv[s]));
    }
    if (e < n) {
        int c = bc[e];
        int pos = crowptr[c] + atomicAdd(&cfill[c], 1);
        cnodes[pos] = e;
    }
}

// ------ GCN propagation, bf16 input; OB=0 f32 out, OB=1 bf16 out ------
// Edge loop unrolled x4: four independent row-gathers in flight per iter.
template <int F, int OB>
__global__ __launch_bounds__(256) void k_prop4sb(
        const unsigned short* __restrict__ hbf, const float* __restrict__ dinv,
        const int* __restrict__ rowptr, const int* __restrict__ deg,
        const int2* __restrict__ csr_ev,
        const float* __restrict__ bias, float* __restrict__ outf,
        unsigned short* __restrict__ outb, int n, int flags) {
    constexpr int FS = F / 4;
    constexpr int ES = 64 / FS;
    const int node = (blockIdx.x * 256 + threadIdx.x) >> 6;
    if (node >= n) return;
    const int l = threadIdx.x & 63;
    const int fs = l & (FS - 1);
    const int ep = l / FS;
    const int fi = fs * 4;
    const int start = rowptr[node];
    const int cnt = deg[node];
    float ax = 0.f, ay = 0.f, az = 0.f, aw = 0.f;
    int j = ep;
    for (; j + 3 * ES < cnt; j += 4 * ES) {
        const int2 ev0 = csr_ev[start + j];
        const int2 ev1 = csr_ev[start + j + ES];
        const int2 ev2 = csr_ev[start + j + 2 * ES];
        const int2 ev3 = csr_ev[start + j + 3 * ES];
        float w0 = __int_as_float(ev0.y);
        float w1 = __int_as_float(ev1.y);
        float w2 = __int_as_float(ev2.y);
        float w3 = __int_as_float(ev3.y);
        const ushort4 v0 = *reinterpret_cast<const ushort4*>(&hbf[(size_t)ev0.x * F + fi]);
        const ushort4 v1 = *reinterpret_cast<const ushort4*>(&hbf[(size_t)ev1.x * F + fi]);
        const ushort4 v2 = *reinterpret_cast<const ushort4*>(&hbf[(size_t)ev2.x * F + fi]);
        const ushort4 v3 = *reinterpret_cast<const ushort4*>(&hbf[(size_t)ev3.x * F + fi]);
        ax += (w0 * bf2f(v0.x) + w1 * bf2f(v1.x)) + (w2 * bf2f(v2.x) + w3 * bf2f(v3.x));
        ay += (w0 * bf2f(v0.y) + w1 * bf2f(v1.y)) + (w2 * bf2f(v2.y) + w3 * bf2f(v3.y));
        az += (w0 * bf2f(v0.z) + w1 * bf2f(v1.z)) + (w2 * bf2f(v2.z) + w3 * bf2f(v3.z));
        aw += (w0 * bf2f(v0.w) + w1 * bf2f(v1.w)) + (w2 * bf2f(v2.w) + w3 * bf2f(v3.w));
    }
    for (; j < cnt; j += ES) {
        const int2 ev = csr_ev[start + j];
        float w = __int_as_float(ev.y);
        const ushort4 v = *reinterpret_cast<const ushort4*>(&hbf[(size_t)ev.x * F + fi]);
        ax += w * bf2f(v.x); ay += w * bf2f(v.y);
        az += w * bf2f(v.z); aw += w * bf2f(v.w);
    }
#pragma unroll
    for (int off = FS; off < 64; off <<= 1) {
        ax += __shfl_xor(ax, off);
        ay += __shfl_xor(ay, off);
        az += __shfl_xor(az, off);
        aw += __shfl_xor(aw, off);
    }
    if (ep == 0) {
        float di = dinv[node];
        const ushort4 sv = *reinterpret_cast<const ushort4*>(&hbf[(size_t)node * F + fi]);
        float4 o;
        o.x = di * ax + di * di * bf2f(sv.x);
        o.y = di * ay + di * di * bf2f(sv.y);
        o.z = di * az + di * di * bf2f(sv.z);
        o.w = di * aw + di * di * bf2f(sv.w);
        if (flags) {
            const float4 b = *reinterpret_cast<const float4*>(&bias[fi]);
            o.x = elu1(o.x + b.x); o.y = elu1(o.y + b.y);
            o.z = elu1(o.z + b.z); o.w = elu1(o.w + b.w);
        }
        if constexpr (OB) {
            ushort4 ob;
            ob.x = (unsigned short)f2bf(o.x); ob.y = (unsigned short)f2bf(o.y);
            ob.z = (unsigned short)f2bf(o.z); ob.w = (unsigned short)f2bf(o.w);
            *reinterpret_cast<ushort4*>(&outb[(size_t)node * F + fi]) = ob;
        } else {
            *reinterpret_cast<float4*>(&outf[(size_t)node * F + fi]) = o;
        }
    }
}

// prop3 on x + fused fc<64> -> bf16 out (N x 64); edge loop unrolled x2
__global__ void k_prop3f1(const float* __restrict__ h, const float* __restrict__ dinv,
                          const int* __restrict__ rowptr, const int* __restrict__ deg,
                          const int2* __restrict__ csr_ev,
                          const float* __restrict__ WG1, const float* __restrict__ bG1,
                          unsigned short* __restrict__ outb, int n) {
    int node = blockIdx.x * 256 + threadIdx.x;
    if (node >= n) return;
    int start = rowptr[node], cnt = deg[node];
    float a0 = 0.f, a1 = 0.f, a2 = 0.f;
    int j = 0;
    for (; j + 1 < cnt; j += 2) {
        const int2 ev0 = csr_ev[start + j];
        const int2 ev1 = csr_ev[start + j + 1];
        float w0 = __int_as_float(ev0.y);
        float w1 = __int_as_float(ev1.y);
        const float* r0 = h + (size_t)ev0.x * 3;
        const float* r1 = h + (size_t)ev1.x * 3;
        a0 += w0 * r0[0] + w1 * r1[0];
        a1 += w0 * r0[1] + w1 * r1[1];
        a2 += w0 * r0[2] + w1 * r1[2];
    }
    if (j < cnt) {
        const int2 ev = csr_ev[start + j];
        float w = __int_as_float(ev.y);
        const float* r = h + (size_t)ev.x * 3;
        a0 += w * r[0]; a1 += w * r[1]; a2 += w * r[2];
    }
    float di = dinv[node];
    float p0 = di * a0 + di * di * h[(size_t)node * 3 + 0];
    float p1 = di * a1 + di * di * h[(size_t)node * 3 + 1];
    float p2 = di * a2 + di * di * h[(size_t)node * 3 + 2];
    unsigned short* op = outb + (size_t)node * 64;
#pragma unroll 4
    for (int c = 0; c < 64; c += 4) {
        ushort4 ob;
        ob.x = (unsigned short)f2bf(elu1(p0 * WG1[c + 0] + p1 * WG1[64 + c + 0] + p2 * WG1[128 + c + 0] + bG1[c + 0]));
        ob.y = (unsigned short)f2bf(elu1(p0 * WG1[c + 1] + p1 * WG1[64 + c + 1] + p2 * WG1[128 + c + 1] + bG1[c + 1]));
        ob.z = (unsigned short)f2bf(elu1(p0 * WG1[c + 2] + p1 * WG1[64 + c + 2] + p2 * WG1[128 + c + 2] + bG1[c + 2]));
        ob.w = (unsigned short)f2bf(elu1(p0 * WG1[c + 3] + p1 * WG1[64 + c + 3] + p2 * WG1[128 + c + 3] + bG1[c + 3]));
        *reinterpret_cast<ushort4*>(op + c) = ob;
    }
}

// prop3 on t3 (+bO3, elu) + fused final fc3; edge loop unrolled x2
__global__ void k_prop3out(const float* __restrict__ h, const float* __restrict__ dinv,
                           const int* __restrict__ rowptr, const int* __restrict__ deg,
                           const int2* __restrict__ csr_ev,
                           const float* __restrict__ bO3, const float* __restrict__ WfO3,
                           const float* __restrict__ bfO3, float* __restrict__ out, int n) {
    int node = blockIdx.x * 256 + threadIdx.x;
    if (node >= n) return;
    int start = rowptr[node], cnt = deg[node];
    float a0 = 0.f, a1 = 0.f, a2 = 0.f;
    int j = 0;
    for (; j + 1 < cnt; j += 2) {
        const int2 ev0 = csr_ev[start + j];
        const int2 ev1 = csr_ev[start + j + 1];
        float w0 = __int_as_float(ev0.y);
        float w1 = __int_as_float(ev1.y);
        const float* r0 = h + (size_t)ev0.x * 3;
        const float* r1 = h + (size_t)ev1.x * 3;
        a0 += w0 * r0[0] + w1 * r1[0];
        a1 += w0 * r0[1] + w1 * r1[1];
        a2 += w0 * r0[2] + w1 * r1[2];
    }
    if (j < cnt) {
        const int2 ev = csr_ev[start + j];
        float w = __int_as_float(ev.y);
        const float* r = h + (size_t)ev.x * 3;
        a0 += w * r[0]; a1 += w * r[1]; a2 += w * r[2];
    }
    float di = dinv[node];
    float o0 = elu1(di * a0 + di * di * h[(size_t)node * 3 + 0] + bO3[0]);
    float o1 = elu1(di * a1 + di * di * h[(size_t)node * 3 + 1] + bO3[1]);
    float o2 = elu1(di * a2 + di * di * h[(size_t)node * 3 + 2] + bO3[2]);
#pragma unroll
    for (int c = 0; c < 3; c++) {
        out[(size_t)node * 3 + c] =
            elu1(o0 * WfO3[c] + o1 * WfO3[3 + c] + o2 * WfO3[6 + c] + bfO3[c]);
    }
}

// ---- merged: infinal + rstd-scaled WO1 pack + corr (17 blocks x 256) ----
__global__ void k_normprep(const float* __restrict__ W, const float* __restrict__ insum,
                           const float* __restrict__ insumsq, unsigned* __restrict__ Phi,
                           unsigned* __restrict__ Plo, float* __restrict__ corr,
                           float* __restrict__ mu, float* __restrict__ rstd, int n) {
    const float fn = (float)n;
    const int bid = blockIdx.x, tid = threadIdx.x;
    if (bid == 16) {
        float m = insum[tid] / fn;
        float var = insumsq[tid] / fn - m * m;
        mu[tid] = m;
        rstd[tid] = rsqrtf(var + 1e-5f);
        return;
    }
    {
        int t = bid * 256 + tid;
        int lane = t & 63, rest = t >> 6;
        int ct = rest % 8, s = rest / 8;
        int col = ct * 16 + (lane & 15);
        int g = lane >> 4;
        int k0 = s * 32;
        float e[8];
#pragma unroll
        for (int j = 0; j < 4; j++) {
            int ka = k0 + 4 * g + j;
            int kb = k0 + 16 + 4 * g + j;
            float ma = insum[ka] / fn;
            float sa = rsqrtf(insumsq[ka] / fn - ma * ma + 1e-5f);
            float mb = insum[kb] / fn;
            float sb = rsqrtf(insumsq[kb] / fn - mb * mb + 1e-5f);
            e[j]     = W[(size_t)ka * 128 + col] * sa;
            e[4 + j] = W[(size_t)kb * 128 + col] * sb;
        }
#pragma unroll
        for (int j = 0; j < 4; j++) {
            unsigned h0 = f2bf(e[2 * j]), h1 = f2bf(e[2 * j + 1]);
            Phi[(size_t)t * 4 + j] = h0 | (h1 << 16);
            unsigned l0 = f2bf(e[2 * j] - bf2f(h0));
            unsigned l1 = f2bf(e[2 * j + 1] - bf2f(h1));
            Plo[(size_t)t * 4 + j] = l0 | (l1 << 16);
        }
    }
    if (tid < 128) {
        int k0 = bid * 16;
        float s = 0.f;
        for (int k = k0; k < k0 + 16; k++) {
            float m = insum[k] / fn;
            float r = rsqrtf(insumsq[k] / fn - m * m + 1e-5f);
            s += m * r * W[(size_t)k * 128 + tid];
        }
        atomicAdd(&corr[tid], s);
    }
}

// ---- split-bf16 MFMA GEMM (bf16-A only). Three W paths:
//   FULLW>0: loop K in FULLW chunks {stage, barrier, compute, barrier};
//     32KB chunks -> 4 blocks/CU. A-register prefetch pipeline.
//   else BN>=128: double-buffered global_load_lds W, barrier per kstep.
//   else: register W.
// Optional fused second GEMM (W3: BN x 3) via 16-lane shfl -> C3 (BN<=32).
template <int BN, int WAVES, int FULLW>
__global__ __launch_bounds__(WAVES * 64) void k_gmfma(
        const unsigned short* __restrict__ Abf,
        const unsigned* __restrict__ Phi, const unsigned* __restrict__ Plo,
        const float* __restrict__ bias, const float* __restrict__ sub,
        const float* __restrict__ add, const int* __restrict__ addidx,
        float* __restrict__ C, unsigned short* __restrict__ Cbf,
        const float* __restrict__ W3, float* __restrict__ C3,
        int N, int K, int flags) {
    constexpr int NT = BN / 16;
    constexpr int WCOL = (BN == 256) ? 4 : (BN == 128 ? 2 : 1);
    constexpr int WROW = WAVES / WCOL;
    constexpr int NTW = NT / WCOL;
    constexpr int BR = 32 * WROW;
    constexpr bool LDSW = (BN >= 128);
    constexpr int LDSU = (FULLW > 0) ? 2 * NT * (FULLW / 32) * 256
                                     : (LDSW ? 2 * 2 * NT * 256 : 1);
    __shared__ unsigned lds_w[LDSU];
    const int t = threadIdx.x;
    const int w = t >> 6, l = t & 63;
    const int wr = w / WCOL, wc = w % WCOL;
    const int l15 = l & 15, g = l >> 4;
    const int row0 = blockIdx.x * BR + wr * 32;
    const int ctbase = wc * NTW;
    int ar0 = row0 + l15;      ar0 = ar0 < N ? ar0 : N - 1;
    int ar1 = row0 + 16 + l15; ar1 = ar1 < N ? ar1 : N - 1;
    const unsigned short* ab0 = Abf + (size_t)ar0 * K;
    const unsigned short* ab1 = Abf + (size_t)ar1 * K;

    f32x4 acc[2][NTW];
#pragma unroll
    for (int f = 0; f < 2; f++)
#pragma unroll
        for (int ct = 0; ct < NTW; ct++) acc[f][ct] = (f32x4){0.f, 0.f, 0.f, 0.f};

    auto loadA = [&](int s, U8* ahi) {
        const int k0 = s * 32;
#pragma unroll
        for (int f = 0; f < 2; f++) {
            const unsigned short* ab = f ? ab1 : ab0;
            const uint2 hA = *reinterpret_cast<const uint2*>(ab + k0 + 4 * g);
            const uint2 hB = *reinterpret_cast<const uint2*>(ab + k0 + 16 + 4 * g);
            ahi[f].u[0] = hA.x; ahi[f].u[1] = hA.y;
            ahi[f].u[2] = hB.x; ahi[f].u[3] = hB.y;
        }
    };
    auto domfma = [&](U8* wh, U8* wl, U8* ahi) {
#pragma unroll
        for (int ct = 0; ct < NTW; ct++) {
            acc[0][ct] = __builtin_amdgcn_mfma_f32_16x16x32_bf16(ahi[0].v, wh[ct].v, acc[0][ct], 0, 0, 0);
            acc[0][ct] = __builtin_amdgcn_mfma_f32_16x16x32_bf16(ahi[0].v, wl[ct].v, acc[0][ct], 0, 0, 0);
            acc[1][ct] = __builtin_amdgcn_mfma_f32_16x16x32_bf16(ahi[1].v, wh[ct].v, acc[1][ct], 0, 0, 0);
            acc[1][ct] = __builtin_amdgcn_mfma_f32_16x16x32_bf16(ahi[1].v, wl[ct].v, acc[1][ct], 0, 0, 0);
        }
    };

    const int nk = K / 32;

    if constexpr (FULLW > 0) {
        constexpr int NKT = FULLW / 32;     // ksteps per chunk
        const int nchunk = K / FULLW;
        U8 wh[NTW], wl[NTW], ahiC[2], ahiN[2];
        loadA(0, ahiC);                     // prologue prefetch
        for (int c = 0; c < nchunk; c++) {
            for (int i = w; i < 2 * NT * NKT; i += WAVES) {
                int s = i / (2 * NT);
                int j = i - s * 2 * NT;
                int gs = c * NKT + s;
                const unsigned* gsrc = (j < NT)
                    ? Phi + (size_t)(gs * NT + j) * 256 + l * 4
                    : Plo + (size_t)(gs * NT + (j - NT)) * 256 + l * 4;
                __builtin_amdgcn_global_load_lds(
                    (const __attribute__((address_space(1))) unsigned*)gsrc,
                    (__attribute__((address_space(3))) unsigned*)(lds_w + (size_t)i * 256),
                    16, 0, 0);
            }
            __syncthreads();                // chunk staged + visible
#pragma unroll
            for (int s = 0; s < NKT; s++) {
                const int gs = c * NKT + s;
                if (gs + 1 < nk) loadA(gs + 1, ahiN);   // prefetch next kstep
                const unsigned* base = lds_w + (size_t)s * (2 * NT * 256);
#pragma unroll
                for (int ct = 0; ct < NTW; ct++) {
                    wh[ct] = *reinterpret_cast<const U8*>(base + (ctbase + ct) * 256 + l * 4);
                    wl[ct] = *reinterpret_cast<const U8*>(base + (NT + ctbase + ct) * 256 + l * 4);
                }
                domfma(wh, wl, ahiC);
#pragma unroll
                for (int q = 0; q < 4; q++) {
                    ahiC[0].u[q] = ahiN[0].u[q];
                    ahiC[1].u[q] = ahiN[1].u[q];
                }
            }
            __syncthreads();   // reads done before restage / stores (in-place)
        }
    } else if constexpr (LDSW) {
        auto stage = [&](int s, int b) {
            unsigned* base = lds_w + (size_t)b * (2 * NT * 256);
            for (int i = w; i < 2 * NT; i += WAVES) {
                const unsigned* gsrc = (i < NT)
                    ? Phi + (size_t)(s * NT + i) * 256 + l * 4
                    : Plo + (size_t)(s * NT + (i - NT)) * 256 + l * 4;
                __builtin_amdgcn_global_load_lds(
                    (const __attribute__((address_space(1))) unsigned*)gsrc,
                    (__attribute__((address_space(3))) unsigned*)(base + i * 256),
                    16, 0, 0);
            }
        };
        auto loadWlds = [&](int b, U8* wh, U8* wl) {
            const unsigned* base = lds_w + (size_t)b * (2 * NT * 256);
#pragma unroll
            for (int ct = 0; ct < NTW; ct++) {
                wh[ct] = *reinterpret_cast<const U8*>(base + (ctbase + ct) * 256 + l * 4);
                wl[ct] = *reinterpret_cast<const U8*>(base + (NT + ctbase + ct) * 256 + l * 4);
            }
        };

        U8 wh[NTW], wl[NTW], ahiA[2], ahiB[2];
        stage(0, 0);
        loadA(0, ahiA);
        __syncthreads();                    // W(0) staged + visible
        int s = 0;
        while (true) {
            const bool hasB = (s + 1 < nk);
            if (hasB) { stage(s + 1, (s + 1) & 1); loadA(s + 1, ahiB); }
            loadWlds(s & 1, wh, wl);
            domfma(wh, wl, ahiA);
            __syncthreads();                // drain stage(s+1); protect buf reuse
            if (!hasB) break;
            s++;
            const bool hasA2 = (s + 1 < nk);
            if (hasA2) { stage(s + 1, (s + 1) & 1); loadA(s + 1, ahiA); }
            loadWlds(s & 1, wh, wl);
            domfma(wh, wl, ahiB);
            __syncthreads();
            if (!hasA2) break;
            s++;
        }
        // loop's trailing barrier = all A reads done before stores (in-place safe)
    } else {
        auto loadW = [&](int s, U8* wh, U8* wl) {
            const unsigned* pb = Phi + ((size_t)(s * NT + ctbase) * 64 + l) * 4;
            const unsigned* pl = Plo + ((size_t)(s * NT + ctbase) * 64 + l) * 4;
#pragma unroll
            for (int ct = 0; ct < NTW; ct++) {
                wh[ct] = *reinterpret_cast<const U8*>(pb + (size_t)ct * 256);
                wl[ct] = *reinterpret_cast<const U8*>(pl + (size_t)ct * 256);
            }
        };
        U8 whA[NTW], wlA[NTW], ahiA[2];
        U8 whB[NTW], wlB[NTW], ahiB[2];
        loadW(0, whA, wlA);
        loadA(0, ahiA);
        int s = 0;
        while (true) {
            const bool hasB = (s + 1 < nk);
            if (hasB) { loadW(s + 1, whB, wlB); loadA(s + 1, ahiB); }
            domfma(whA, wlA, ahiA);
            if (!hasB) break;
            const bool hasA2 = (s + 2 < nk);
            if (hasA2) { loadW(s + 2, whA, wlA); loadA(s + 2, ahiA); }
            domfma(whB, wlB, ahiB);
            if (!hasA2) break;
            s += 2;
        }
        __syncthreads();   // all A reads done before any store (in-place safe)
    }

#pragma unroll
    for (int f = 0; f < 2; f++) {
#pragma unroll
        for (int r = 0; r < 4; r++) {
            int row = row0 + 16 * f + 4 * g + r;
            if (row >= N) continue;   // uniform across l15 group (shfl-safe)
            int gi = (add != nullptr) ? addidx[row] : 0;
            float t0 = 0.f, t1 = 0.f, t2 = 0.f;
#pragma unroll
            for (int ct = 0; ct < NTW; ct++) {
                int col = (ctbase + ct) * 16 + l15;
                float o = acc[f][ct][r];
                if (add != nullptr) o += add[(size_t)gi * BN + col];
                if (sub != nullptr) o -= sub[col];
                if (flags) o = elu1(o + bias[col]);
                if (C != nullptr) C[(size_t)row * BN + col] = o;
                if (Cbf != nullptr) Cbf[(size_t)row * BN + col] = (unsigned short)f2bf(o);
                if (W3 != nullptr) {
                    t0 += o * W3[col * 3 + 0];
                    t1 += o * W3[col * 3 + 1];
                    t2 += o * W3[col * 3 + 2];
                }
            }
            if (W3 != nullptr) {
#pragma unroll
                for (int m = 1; m < 16; m <<= 1) {
                    t0 += __shfl_xor(t0, m);
                    t1 += __shfl_xor(t1, m);
                    t2 += __shfl_xor(t2, m);
                }
                if (l15 == 0) {
                    C3[(size_t)row * 3 + 0] = t0;
                    C3[(size_t)row * 3 + 1] = t1;
                    C3[(size_t)row * 3 + 2] = t2;
                }
            }
        }
    }
}

// ---------------- simple fc (small shapes) ----------------
template <int M, int RPT>
__global__ __launch_bounds__(256) void k_fc(
        const float* __restrict__ A, const float* __restrict__ W,
        const float* __restrict__ bias, const float* __restrict__ add,
        const int* __restrict__ addidx, float* __restrict__ C,
        int N, int K, int flags) {
    constexpr int TX = M / 4;
    constexpr int TY = 256 / TX;
    constexpr int RB = TY * RPT;
    int tx = threadIdx.x % TX;
    int ty = threadIdx.x / TX;
    int row0 = blockIdx.x * RB + ty * RPT;
    float4 acc[RPT];
#pragma unroll
    for (int r = 0; r < RPT; r++) acc[r] = make_float4(0.f, 0.f, 0.f, 0.f);
    for (int k = 0; k < K; k++) {
        float4 w = *reinterpret_cast<const float4*>(&W[(size_t)k * M + tx * 4]);
#pragma unroll
        for (int r = 0; r < RPT; r++) {
            int row = row0 + r;
            row = row < N ? row : N - 1;
            float a = A[(size_t)row * K + k];
            acc[r].x += a * w.x; acc[r].y += a * w.y;
            acc[r].z += a * w.z; acc[r].w += a * w.w;
        }
    }
    if (add != nullptr) {
#pragma unroll
        for (int r = 0; r < RPT; r++) {
            int row = row0 + r;
            if (row < N) {
                int g = addidx[row];
                const float4 v = *reinterpret_cast<const float4*>(&add[(size_t)g * M + tx * 4]);
                acc[r].x += v.x; acc[r].y += v.y; acc[r].z += v.z; acc[r].w += v.w;
            }
        }
    }
    __syncthreads();
    float4 b = make_float4(0.f, 0.f, 0.f, 0.f);
    if (flags) b = *reinterpret_cast<const float4*>(&bias[tx * 4]);
#pragma unroll
    for (int r = 0; r < RPT; r++) {
        int row = row0 + r;
        if (row >= N) break;
        float4 o = acc[r];
        o.x += b.x; o.y += b.y; o.z += b.z; o.w += b.w;
        if (flags) { o.x = elu1(o.x); o.y = elu1(o.y); o.z = elu1(o.z); o.w = elu1(o.w); }
        *reinterpret_cast<float4*>(&C[(size_t)row * M + tx * 4]) = o;
    }
}

// fused: lx = elu(lA @ WfL2 + bfL2) -> lB;  compO = lx @ WO1[256:] -> lA
__global__ __launch_bounds__(256) void k_fcl2(
        const float* __restrict__ A, const float* __restrict__ W1,
        const float* __restrict__ b1, const float* __restrict__ W2,
        float* __restrict__ lxout, float* __restrict__ compO) {
    __shared__ float lx[32][64];
    const int tid = threadIdx.x;
    const int tx = tid % 16, ty = tid / 16;
    const int row0b = blockIdx.x * 32;
    float4 acc[2];
    acc[0] = make_float4(0.f, 0.f, 0.f, 0.f);
    acc[1] = make_float4(0.f, 0.f, 0.f, 0.f);
    for (int k = 0; k < 64; k++) {
        float4 w = *reinterpret_cast<const float4*>(&W1[(size_t)k * 64 + tx * 4]);
#pragma unroll
        for (int r = 0; r < 2; r++) {
            float a = A[(size_t)(row0b + ty * 2 + r) * 64 + k];
            acc[r].x += a * w.x; acc[r].y += a * w.y;
            acc[r].z += a * w.z; acc[r].w += a * w.w;
        }
    }
    float4 b = *reinterpret_cast<const float4*>(&b1[tx * 4]);
#pragma unroll
    for (int r = 0; r < 2; r++) {
        int lr = ty * 2 + r;
        float4 o;
        o.x = elu1(acc[r].x + b.x); o.y = elu1(acc[r].y + b.y);
        o.z = elu1(acc[r].z + b.z); o.w = elu1(acc[r].w + b.w);
        *reinterpret_cast<float4*>(&lxout[(size_t)(row0b + lr) * 64 + tx * 4]) = o;
        lx[lr][tx * 4 + 0] = o.x; lx[lr][tx * 4 + 1] = o.y;
        lx[lr][tx * 4 + 2] = o.z; lx[lr][tx * 4 + 3] = o.w;
    }
    __syncthreads();
    for (int o = tid; o < 32 * 128; o += 256) {
        int r = o >> 7, c = o & 127;
        float s = 0.f;
        for (int k = 0; k < 64; k++) s += lx[r][k] * W2[(size_t)k * 128 + c];
        compO[(size_t)(row0b + r) * 128 + c] = s;
    }
}

// ---------------- instance norm stats (bf16 input) ----------------
__global__ void k_instats(const unsigned short* __restrict__ h, float* __restrict__ sum,
                          float* __restrict__ sumsq, int n) {
    int c = threadIdx.x;
    int r0 = blockIdx.x * 128;
    int r1 = r0 + 128 < n ? r0 + 128 : n;
    float s = 0.f, q = 0.f;
#pragma unroll 8
    for (int r = r0; r < r1; r++) {
        float v = bf2f(h[(size_t)r * 256 + c]);
        s += v; q += v * v;
    }
    atomicAdd(&sum[c], s);
    atomicAdd(&sumsq[c], q);
}

// ---- merged: cluster poolavg + pooledges ----
__global__ __launch_bounds__(256) void k_poolmerge(
        const unsigned short* __restrict__ xh, const int* __restrict__ crowptr,
        const int* __restrict__ cdeg, const int* __restrict__ cnodes,
        const float* __restrict__ mu, const float* __restrict__ rstd,
        float* __restrict__ px,
        const int* __restrict__ src, const int* __restrict__ dst,
        const int* __restrict__ bc, unsigned char* __restrict__ bmT, int E) {
    int bid = blockIdx.x;
    if (bid < NCLUST) {
        int cl = bid;
        int c  = threadIdx.x;
        int start = crowptr[cl];
        int cnt = cdeg[cl];
        float acc = 0.f;
        int j = 0;
        for (; j + 3 < cnt; j += 4) {       // 4 independent gathers (ILP)
            int n0 = cnodes[start + j + 0];
            int n1 = cnodes[start + j + 1];
            int n2 = cnodes[start + j + 2];
            int n3 = cnodes[start + j + 3];
            float v0 = bf2f(xh[(size_t)n0 * 256 + c]);
            float v1 = bf2f(xh[(size_t)n1 * 256 + c]);
            float v2 = bf2f(xh[(size_t)n2 * 256 + c]);
            float v3 = bf2f(xh[(size_t)n3 * 256 + c]);
            acc += (v0 + v1) + (v2 + v3);
        }
        for (; j < cnt; j++) {
            int node = cnodes[start + j];
            acc += bf2f(xh[(size_t)node * 256 + c]);
        }
        float res = acc / fmaxf((float)cnt, 1.0f);
        res = (cnt > 0) ? (res - mu[c]) * rstd[c] : 0.f;
        px[(size_t)cl * 256 + c] = res;
    } else {
        int e = (bid - NCLUST) * 256 + threadIdx.x;
        if (e < E) {
            int ps = bc[src[e]];
            int pd = bc[dst[e]];
            bmT[(size_t)pd * NCLUST + ps] = 1;
        }
    }
}

__global__ __launch_bounds__(256) void k_pooldeg(
        const unsigned char* __restrict__ bmT, float* __restrict__ dinvp) {
    int d = blockIdx.x;
    int t = threadIdx.x;
    const unsigned int v = reinterpret_cast<const unsigned int*>(bmT + (size_t)d * NCLUST)[t];
    int s = (v & 0xff) + ((v >> 8) & 0xff) + ((v >> 16) & 0xff) + ((v >> 24) & 0xff);
    if (t == (d >> 2)) s -= (v >> ((d & 3) * 8)) & 0xff;
    __shared__ int red[256];
    red[t] = s; __syncthreads();
    for (int o = 128; o > 0; o >>= 1) {
        if (t < o) red[t] += red[t + o];
        __syncthreads();
    }
    if (t == 0) dinvp[d] = rsqrtf((float)red[0] + 1.0f);
}

// ---- pooled propagation, D-tiled: block computes DT=4 dest rows, reads h
// ONCE for all 4 (was: once per dest row => 4x L2 traffic). 2 barriers.
template <int F>
__global__ __launch_bounds__(1024) void k_proppool2(
        const float* __restrict__ h, const float* __restrict__ dinvp,
        const unsigned char* __restrict__ bmT, const float* __restrict__ bias,
        float* __restrict__ out) {
    constexpr int DT = 4;
    constexpr int SG = 1024 / F;
    __shared__ unsigned char lbm[DT][NCLUST];   // diag-zeroed mask rows (4KB)
    __shared__ float red[DT][1024];             // partials (16KB)
    const int d0 = blockIdx.x * DT;
    const int t = threadIdx.x;
    const int f = t & (F - 1);
    const int sg = t / F;
    // stage mask rows, zeroing the diagonal
    for (int idx = t; idx < DT * NCLUST; idx += 1024) {
        int dt = idx >> 10;
        int s = idx & (NCLUST - 1);
        lbm[dt][s] = (s == d0 + dt) ? 0 : bmT[(size_t)(d0 + dt) * NCLUST + s];
    }
    __syncthreads();
    float acc[DT];
#pragma unroll
    for (int dt = 0; dt < DT; dt++) acc[dt] = 0.f;
    for (int s = sg; s < NCLUST; s += SG) {
        float hv = dinvp[s] * h[(size_t)s * F + f];
#pragma unroll
        for (int dt = 0; dt < DT; dt++)
            acc[dt] += (float)lbm[dt][s] * hv;
    }
#pragma unroll
    for (int dt = 0; dt < DT; dt++) red[dt][t] = acc[dt];
    __syncthreads();
    if (t < DT * F) {
        int dt = t / F;
        int f2 = t % F;
        float s = 0.f;
#pragma unroll
        for (int gsg = 0; gsg < SG; gsg++) s += red[dt][gsg * F + f2];
        int d = d0 + dt;
        float di = dinvp[d];
        float r = di * s + di * di * h[(size_t)d * F + f2] + bias[f2];
        out[(size_t)d * F + f2] = elu1(r);
    }
}

// ---------------------------------------------------------------------------
extern "C" void kernel_launch(void* const* d_in, const int* in_sizes, int n_in,
                              void* d_out, int out_size, void* d_ws, size_t ws_size,
                              hipStream_t stream) {
    const float* x       = (const float*)d_in[0];
    const int*   adj     = (const int*)d_in[1];
    const int*   inb     = (const int*)d_in[3];
    const int*   cluster = (const int*)d_in[4];
    const float* WG1  = (const float*)d_in[5];   const float* bG1  = (const float*)d_in[6];
    const float* WfG1 = (const float*)d_in[7];   const float* bfG1 = (const float*)d_in[8];
    const float* WG2  = (const float*)d_in[9];   const float* bG2  = (const float*)d_in[10];
    const float* WfG2 = (const float*)d_in[11];  const float* bfG2 = (const float*)d_in[12];
    const float* WL1  = (const float*)d_in[13];  const float* bL1  = (const float*)d_in[14];
    const float* WfL1 = (const float*)d_in[15];  const float* bfL1 = (const float*)d_in[16];
    const float* WL2  = (const float*)d_in[17];  const float* bL2  = (const float*)d_in[18];
    const float* WfL2 = (const float*)d_in[19];  const float* bfL2 = (const float*)d_in[20];
    const float* WO1  = (const float*)d_in[21];  const float* bO1  = (const float*)d_in[22];
    const float* WfO1 = (const float*)d_in[23];  const float* bfO1 = (const float*)d_in[24];
    const float* WO2  = (const float*)d_in[25];  const float* bO2  = (const float*)d_in[26];
    const float* WfO2 = (const float*)d_in[27];  const float* bfO2 = (const float*)d_in[28];
    const float* WO3  = (const float*)d_in[29];  const float* bO3  = (const float*)d_in[30];
    const float* WfO3 = (const float*)d_in[31];  const float* bfO3 = (const float*)d_in[32];
    float* out = (float*)d_out;

    const int n = in_sizes[0] / 3;       // 100000
    const int E = in_sizes[1] / 2;       // 1600000
    const int* src = adj;
    const int* dst = adj + E;

    // ---- workspace carve ----
    char* ws = (char*)d_ws;
    size_t off = 0;
    auto alloc = [&](size_t bytes) -> void* {
        void* p = ws + off;
        off = (off + bytes + 255) & ~(size_t)255;
        return p;
    };
    int*   deg     = (int*)alloc((size_t)n * 4);     // zero span 1 start
    int*   fill    = (int*)alloc((size_t)n * 4);
    int*   cdeg    = (int*)alloc(NCLUST * 4);
    int*   cfill   = (int*)alloc(NCLUST * 4);
    int*   rowptr  = (int*)alloc((size_t)n * 4);     // zero span 1 end (exclusive)
    int*   crowptr = (int*)alloc(NCLUST * 4);
    int*   cnodes  = (int*)alloc((size_t)n * 4);
    int*   bcarr   = (int*)alloc((size_t)n * 4);
    float* dinv    = (float*)alloc((size_t)n * 4);
    int*   bsum    = (int*)alloc(512);
    int2*  csr_ev  = (int2*)alloc((size_t)E * 8);
    float* X       = (float*)alloc((size_t)n * 256 * 4);
    unsigned short* Xh = (unsigned short*)alloc((size_t)n * 256 * 2);
    float* B       = (float*)alloc((size_t)n * 128 * 4);
    unsigned short* Bh = (unsigned short*)alloc((size_t)n * 128 * 2);
    float* insum   = (float*)alloc(256 * 4);         // zero span 2 start
    float* insumsq = (float*)alloc(256 * 4);
    float* px      = (float*)alloc((size_t)NCLUST * 256 * 4);
    unsigned char* bmT = (unsigned char*)alloc((size_t)NCLUST * NCLUST);
    float* corr    = (float*)alloc(128 * 4);
    float* mu      = (float*)alloc(256 * 4);         // zero span 2 end (exclusive)
    float* rstd    = (float*)alloc(256 * 4);
    float* dinvp   = (float*)alloc(NCLUST * 4);
    float* lA      = (float*)alloc((size_t)NCLUST * 128 * 4);
    float* lB      = (float*)alloc((size_t)NCLUST * 128 * 4);
    unsigned* pfG1h = (unsigned*)alloc(2048 * 4);   unsigned* pfG1l = (unsigned*)alloc(2048 * 4);
    unsigned* pG2h  = (unsigned*)alloc(8192 * 4);   unsigned* pG2l  = (unsigned*)alloc(8192 * 4);
    unsigned* pfG2h = (unsigned*)alloc(32768 * 4);  unsigned* pfG2l = (unsigned*)alloc(32768 * 4);
    unsigned* pO1h  = (unsigned*)alloc(16384 * 4);  unsigned* pO1l  = (unsigned*)alloc(16384 * 4);
    unsigned* pfO1h = (unsigned*)alloc(8192 * 4);   unsigned* pfO1l = (unsigned*)alloc(8192 * 4);
    unsigned* pO2h  = (unsigned*)alloc(2048 * 4);   unsigned* pO2l  = (unsigned*)alloc(2048 * 4);
    unsigned* pfO2h = (unsigned*)alloc(512 * 4);    unsigned* pfO2l = (unsigned*)alloc(512 * 4);
    (void)ws_size; (void)n_in; (void)out_size;

    unsigned short* Bh1 = Bh;                        // h1/h2 (n x 64 bf16)
    unsigned short* Bh2 = Bh + (size_t)n * 64;       // p64 (n x 64 bf16)

    auto cdiv = [](int a, int b) { return (a + b - 1) / b; };
    const int EB = cdiv(E, 256);
    const int PB = cdiv(n, 4);

    // ---- init: zero scratch + pack all static weights (ONE launch) ----
    int nz1 = (int)(((char*)rowptr - (char*)deg) / 16);
    int nz2 = (int)(((char*)mu - (char*)insum) / 16);
    InitArgs ia;
    ia.d[0] = {WfG1, pfG1h, pfG1l, 64, 64, 0};
    ia.d[1] = {WG2,  pG2h,  pG2l,  64, 256, 512};
    ia.d[2] = {WfG2, pfG2h, pfG2l, 256, 256, 2560};
    ia.d[3] = {WfO1, pfO1h, pfO1l, 128, 128, 10752};
    ia.d[4] = {WO2,  pO2h,  pO2l,  128, 32, 12800};
    ia.d[5] = {WfO2, pfO2h, pfO2l, 32, 32, 13312};
    ia.tot = 13440;
    ia.z1 = (int4*)deg; ia.nz1 = nz1;
    ia.z2 = (int4*)insum; ia.nz2 = nz2;
    int initN = (nz1 + nz2 > ia.tot) ? (nz1 + nz2) : ia.tot;
    k_init<<<cdiv(initN, 256), 256, 0, stream>>>(ia);

    // ---- CSR build ----
    k_hist<<<EB, 256, 0, stream>>>(dst, deg, E);
    int nb = cdiv(n, 1024);
    k_scan_block<<<nb, 256, 0, stream>>>(deg, rowptr, bsum, n);
    k_nodeinit<<<cdiv(n, 256), 256, 0, stream>>>(rowptr, bsum, deg, cluster, inb,
                                                 dinv, bcarr, cdeg, n, nb);
    k_scan_block<<<1, 256, 0, stream>>>(cdeg, crowptr, bsum, NCLUST);
    k_fillc<<<EB, 256, 0, stream>>>(src, dst, dinv, rowptr, fill, csr_ev, E,
                                    bcarr, crowptr, cfill, cnodes, n);

    // ---- global GCN stack (all bf16 activations) ----
    // p3 + fused fc<64>: h1 -> bf16 Bh1
    k_prop3f1<<<cdiv(n, 256), 256, 0, stream>>>(x, dinv, rowptr, deg, csr_ev,
                                                WG1, bG1, Bh1, n);
    // h2 = elu(h1 @ WfG1 + bfG1)  (Bh1 in-place, register-W)  [8-wave]
    k_gmfma<64, 8, 0><<<cdiv(n, 256), 512, 0, stream>>>(Bh1, pfG1h, pfG1l, bfG1,
                                                        nullptr, nullptr, nullptr,
                                                        nullptr, Bh1, nullptr, nullptr,
                                                        n, 64, 1);
    // p64 = S h2  (bf16 gather -> bf16 Bh2)
    k_prop4sb<64, 1><<<PB, 256, 0, stream>>>(Bh1, dinv, rowptr, deg, csr_ev,
                                             nullptr, nullptr, Bh2, n, 0);
    // h3 = elu(p64 @ WG2 + bG2) -> bf16 (Xh)  [FULLW=32 + A-prefetch]
    k_gmfma<256, 8, 32><<<cdiv(n, 64), 512, 0, stream>>>(Bh2, pG2h, pG2l, bG2,
                                                         nullptr, nullptr, nullptr,
                                                         nullptr, Xh, nullptr, nullptr,
                                                         n, 64, 1);
    // h4 = elu(h3 @ WfG2 + bfG2)  (Xh in-place)  [FULLW=32 + A-prefetch]
    k_gmfma<256, 8, 32><<<cdiv(n, 64), 512, 0, stream>>>(Xh, pfG2h, pfG2l, bfG2,
                                                         nullptr, nullptr, nullptr,
                                                         nullptr, Xh, nullptr, nullptr,
                                                         n, 256, 1);

    // ---- instance norm stats + merged finalize/pack/corr ----
    k_instats<<<cdiv(n, 128), 256, 0, stream>>>(Xh, insum, insumsq, n);
    k_normprep<<<17, 256, 0, stream>>>(WO1, insum, insumsq, pO1h, pO1l, corr, mu, rstd, n);

    // ---- cluster pooling (poolavg + pooledges merged) ----
    k_poolmerge<<<NCLUST + EB, 256, 0, stream>>>(Xh, crowptr, cdeg, cnodes, mu, rstd, px,
                                                 src, dst, bcarr, bmT, E);
    k_pooldeg<<<NCLUST, 256, 0, stream>>>(bmT, dinvp);

    // ---- local (pooled) GCN stack ----
    k_fc<128, 2><<<cdiv(NCLUST, 16), 256, 0, stream>>>(px, WL1, nullptr, nullptr, nullptr,
                                                       lA, NCLUST, 256, 0);
    k_proppool2<128><<<NCLUST / 4, 1024, 0, stream>>>(lA, dinvp, bmT, bL1, lB);
    k_fc<128, 2><<<cdiv(NCLUST, 16), 256, 0, stream>>>(lB, WfL1, bfL1, nullptr, nullptr,
                                                       lA, NCLUST, 128, 1);
    k_fc<64, 2><<<cdiv(NCLUST, 32), 256, 0, stream>>>(lA, WL2, nullptr, nullptr, nullptr,
                                                      lB, NCLUST, 128, 0);
    k_proppool2<64><<<NCLUST / 4, 1024, 0, stream>>>(lB, dinvp, bmT, bL2, lA);
    // fused: lx = elu(lA @ WfL2 + bfL2) -> lB; compO = lx @ WO1[256:] -> lA
    k_fcl2<<<NCLUST / 32, 256, 0, stream>>>(lA, WfL2, bfL2, WO1 + (size_t)256 * 128,
                                            lB, lA);

    // ---- output GCN stack ----
    // t1 = Xh @ (rstd*WO1) - corr + compO[bc] -> bf16 (Bh)  [FULLW=64 + A-prefetch]
    k_gmfma<128, 8, 64><<<cdiv(n, 128), 512, 0, stream>>>(Xh, pO1h, pO1l, nullptr,
                                                          corr, lA, bcarr, nullptr, Bh,
                                                          nullptr, nullptr, n, 256, 0);
    k_prop4sb<128, 1><<<PB, 256, 0, stream>>>(Bh, dinv, rowptr, deg, csr_ev,
                                              bO1, nullptr, Xh, n, 1);
    // o2 = elu(o1 @ WfO1 + bfO1)  (Xh in-place)  [FULLW=64 + A-prefetch]
    k_gmfma<128, 8, 64><<<cdiv(n, 128), 512, 0, stream>>>(Xh, pfO1h, pfO1l, bfO1,
                                                          nullptr, nullptr, nullptr,
                                                          nullptr, Xh, nullptr, nullptr,
                                                          n, 128, 1);
    // t2 = o2 @ WO2  -> bf16 (Bh, N x 32)  [register-W, 8-wave]
    k_gmfma<32, 8, 0><<<cdiv(n, 256), 512, 0, stream>>>(Xh, pO2h, pO2l, nullptr,
                                                        nullptr, nullptr, nullptr,
                                                        nullptr, Bh, nullptr, nullptr,
                                                        n, 128, 0);
    k_prop4sb<32, 1><<<PB, 256, 0, stream>>>(Bh, dinv, rowptr, deg, csr_ev,
                                             bO2, nullptr, Xh, n, 1);
    // o4 = elu(o3 @ WfO2 + bfO2); t3 = o4 @ WO3 fused -> B (N x 3 f32)
    k_gmfma<32, 8, 0><<<cdiv(n, 256), 512, 0, stream>>>(Xh, pfO2h, pfO2l, bfO2,
                                                        nullptr, nullptr, nullptr,
                                                        nullptr, nullptr, WO3, B,
                                                        n, 32, 1);
    // o5 = elu(S t3 + bO3); out = elu(o5 @ WfO3 + bfO3)  (fused)
    k_prop3out<<<cdiv(n, 256), 256, 0, stream>>>(B, dinv, rowptr, deg, csr_ev,
                                                 bO3, WfO3, bfO3, out, n);
}